// Round 1
// 485.154 us; speedup vs baseline: 1.1872x; 1.1872x over previous
//
#include <hip/hip_runtime.h>
#include <hip/hip_bf16.h>
#include <cstddef>

// Problem constants
#define BB 4
#define TT 2048
#define CC 2048
#define HH 16
#define DD 128
#define LL 512

typedef _Float16 f16;
typedef f16 f16x2 __attribute__((ext_vector_type(2)));
typedef f16 f16x4 __attribute__((ext_vector_type(4)));
typedef f16 f16x8 __attribute__((ext_vector_type(8)));
typedef float f32x4 __attribute__((ext_vector_type(4)));

// ---------------------------------------------------------------------------
// async global->LDS, 16 B per lane (global_load_lds_dwordx4).
// LDS dest = wave-uniform base + lane*16 (fixed); global side is a per-lane
// gather -> swizzles go into the GLOBAL address, LDS stays lane-contiguous.
// ---------------------------------------------------------------------------
__device__ __forceinline__ void async_load16(void* lptr, const void* gptr) {
  __builtin_amdgcn_global_load_lds(
      (const __attribute__((address_space(1))) unsigned int*)gptr,
      (__attribute__((address_space(3))) unsigned int*)lptr, 16, 0, 0);
}

// ---------------------------------------------------------------------------
// 256x256 8-phase MFMA NT GEMM (f16 in, fp32 out): C[m,n] = sum_k A[m,k]B[n,k]
// m201-style template: BK=64, 8 waves (2M x 4N), 128 KiB double-buffered LDS,
// counted vmcnt (never 0 in main loop), per-phase barriers + setprio around
// the MFMA cluster, XOR chunk swizzle via pre-swizzled GLOBAL gather address.
// Requires M%256==0, N%256==0, K%64==0, K>=128.
//
// Staging schedule (4 phases per K-tile t, buffer bi = t&1):
//   phase t.1 -> (t+1) A-hi   into buf[bi^1]
//   phase t.2 -> (t+1) B-lo   into buf[bi^1]
//   phase t.3 -> (t+1) B-hi   into buf[bi^1]
//   phase t.4 -> (t+2) A-lo   into buf[bi]   (A region of buf[bi] has no
//                                             reader after t.3's drain;
//                                             t.4 only re-reads B region)
// vmcnt(2) at end of t.4 allows only t.4's own 2 loads outstanding ->
// everything tile t+1 needs has landed before its phase-1 ds_reads.
// ---------------------------------------------------------------------------
__global__ __launch_bounds__(512, 2) void mla_gemm_256(
    const f16* __restrict__ A, const f16* __restrict__ B,
    float* __restrict__ C, int M, int N, int K) {
  // [buf][0=A,1=B][256 rows][64 f16]; row r chunk ch (16B units) stored at
  // ch' = ch ^ (r&7)  (pre-swizzled on the global side).
  __shared__ __align__(16) f16 smem[2][2][256 * 64];

  const int tid = threadIdx.x;       // 0..511
  const int lane = tid & 63;
  const int w = tid >> 6;            // 0..7
  const int lnm = lane & 15, quad = lane >> 4;
  const int wm = w >> 2, wn = w & 3; // 2 x 4 wave grid; wave tile 128x64

  // Bijective XCD-aware block swizzle (m204 variant).
  const int nwg = gridDim.x;
  const int bid0 = blockIdx.x;
  const int q8 = nwg >> 3, r8 = nwg & 7;
  const int xcd = bid0 & 7, lid = bid0 >> 3;
  const int wg =
      (xcd < r8 ? xcd * (q8 + 1) : r8 * (q8 + 1) + (xcd - r8) * q8) + lid;
  const int ntc = N >> 8;
  const int m0 = (wg / ntc) * 256;
  const int n0 = (wg % ntc) * 256;

  // Staging geometry: issue j covers LDS slot idx=j*512+tid -> local row
  // r = j*64 + (tid>>3), stored chunk ch' = tid&7; global chunk
  // ch = ch' ^ (r&7) = (tid&7) ^ ((tid>>3)&7)  (j*64 is 0 mod 8).
  const int srow = tid >> 3;
  const int sch = (tid & 7) ^ ((tid >> 3) & 7);
  const f16* Ag = A + (size_t)(m0 + srow) * K + sch * 8;
  const f16* Bg = B + (size_t)(n0 + srow) * K + sch * 8;

  // half h: 0=A-lo 1=A-hi 2=B-lo 3=B-hi; each = 2 global_load_lds / thread
  auto stage = [&](int bi, int k0, int h) {
    const int mat = h >> 1;
    const int rb = (h & 1) * 128;
    const f16* g = (mat ? Bg : Ag) + (size_t)rb * K + k0;
    f16* l = &smem[bi][mat][rb * 64 + tid * 8];
    async_load16(l, g);
    async_load16(l + 4096, g + (size_t)64 * K);
  };

  const int rx8 = lnm & 7;  // (row & 7) for all fragment rows below
  auto rdA = [&](const f16* Ab, int i, int ks) -> f16x8 {
    return *(const f16x8*)&Ab[(wm * 128 + i * 16 + lnm) * 64 +
                              (((ks * 4 + quad) ^ rx8) * 8)];
  };
  auto rdB = [&](const f16* Bb, int j, int ks) -> f16x8 {
    return *(const f16x8*)&Bb[(wn * 64 + j * 16 + lnm) * 64 +
                              (((ks * 4 + quad) ^ rx8) * 8)];
  };

  f32x4 acc[8][4] = {};

  const int NT = K >> 6;

  // Prologue: tile0 fully + tile1 A-lo (the (t-1).4-equivalent stage).
  stage(0, 0, 0);
  stage(0, 0, 1);
  stage(0, 0, 2);
  stage(0, 0, 3);
  stage(1, 64, 0);
  asm volatile("s_waitcnt vmcnt(2)" ::: "memory");  // tile0 landed
  __builtin_amdgcn_s_barrier();

  for (int t = 0; t < NT; ++t) {
    const int bi = t & 1;
    const f16* Ab = smem[bi][0];
    const f16* Bb = smem[bi][1];
    // Clamped k-offsets for tail staging (writes valid-but-dead data into a
    // buffer region that is never read again; keeps vmcnt counts uniform).
    const int k1 = (t + 1 < NT ? t + 1 : t) << 6;
    const int k2 = (t + 2 < NT ? t + 2 : t) << 6;

    f16x8 Ar[4][2], Br[2][2];

    // -------- phase 1: quadrant (mq0, nq0) -- 12 ds_reads --------
#pragma unroll
    for (int i = 0; i < 4; i++)
#pragma unroll
      for (int ks = 0; ks < 2; ks++) Ar[i][ks] = rdA(Ab, i, ks);
#pragma unroll
    for (int j = 0; j < 2; j++)
#pragma unroll
      for (int ks = 0; ks < 2; ks++) Br[j][ks] = rdB(Bb, j, ks);
    stage(bi ^ 1, k1, 1);
    __builtin_amdgcn_s_barrier();
    asm volatile("s_waitcnt lgkmcnt(0)" ::: "memory");
    __builtin_amdgcn_s_setprio(1);
#pragma unroll
    for (int i = 0; i < 4; i++)
#pragma unroll
      for (int j = 0; j < 2; j++)
#pragma unroll
        for (int ks = 0; ks < 2; ks++)
          acc[i][j] = __builtin_amdgcn_mfma_f32_16x16x32_f16(
              Ar[i][ks], Br[j][ks], acc[i][j], 0, 0, 0);
    __builtin_amdgcn_s_setprio(0);
    __builtin_amdgcn_s_barrier();

    // -------- phase 2: quadrant (mq0, nq1) -- 4 ds_reads --------
#pragma unroll
    for (int j = 0; j < 2; j++)
#pragma unroll
      for (int ks = 0; ks < 2; ks++) Br[j][ks] = rdB(Bb, 2 + j, ks);
    stage(bi ^ 1, k1, 2);
    __builtin_amdgcn_s_barrier();
    asm volatile("s_waitcnt lgkmcnt(0)" ::: "memory");
    __builtin_amdgcn_s_setprio(1);
#pragma unroll
    for (int i = 0; i < 4; i++)
#pragma unroll
      for (int j = 0; j < 2; j++)
#pragma unroll
        for (int ks = 0; ks < 2; ks++)
          acc[i][2 + j] = __builtin_amdgcn_mfma_f32_16x16x32_f16(
              Ar[i][ks], Br[j][ks], acc[i][2 + j], 0, 0, 0);
    __builtin_amdgcn_s_setprio(0);
    __builtin_amdgcn_s_barrier();

    // -------- phase 3: quadrant (mq1, nq1) -- 8 ds_reads --------
#pragma unroll
    for (int i = 0; i < 4; i++)
#pragma unroll
      for (int ks = 0; ks < 2; ks++) Ar[i][ks] = rdA(Ab, 4 + i, ks);
    stage(bi ^ 1, k1, 3);
    __builtin_amdgcn_s_barrier();
    asm volatile("s_waitcnt lgkmcnt(0)" ::: "memory");
    __builtin_amdgcn_s_setprio(1);
#pragma unroll
    for (int i = 0; i < 4; i++)
#pragma unroll
      for (int j = 0; j < 2; j++)
#pragma unroll
        for (int ks = 0; ks < 2; ks++)
          acc[4 + i][2 + j] = __builtin_amdgcn_mfma_f32_16x16x32_f16(
              Ar[i][ks], Br[j][ks], acc[4 + i][2 + j], 0, 0, 0);
    __builtin_amdgcn_s_setprio(0);
    __builtin_amdgcn_s_barrier();

    // -------- phase 4: quadrant (mq1, nq0) -- 4 ds_reads (B re-read) ------
    // Stage targets buf[bi] A-lo; this phase only reads buf[bi] B region.
#pragma unroll
    for (int j = 0; j < 2; j++)
#pragma unroll
      for (int ks = 0; ks < 2; ks++) Br[j][ks] = rdB(Bb, j, ks);
    stage(bi, k2, 0);
    __builtin_amdgcn_s_barrier();
    asm volatile("s_waitcnt lgkmcnt(0)" ::: "memory");
    __builtin_amdgcn_s_setprio(1);
#pragma unroll
    for (int i = 0; i < 4; i++)
#pragma unroll
      for (int j = 0; j < 2; j++)
#pragma unroll
        for (int ks = 0; ks < 2; ks++)
          acc[4 + i][j] = __builtin_amdgcn_mfma_f32_16x16x32_f16(
              Ar[i][ks], Br[j][ks], acc[4 + i][j], 0, 0, 0);
    __builtin_amdgcn_s_setprio(0);
    // Counted wait: allow only this phase's 2 loads outstanding -> tile t+1
    // (h0 from (t-1).4, h1..h3 from t.1-3) is fully landed after barrier.
    asm volatile("s_waitcnt vmcnt(2)" ::: "memory");
    __builtin_amdgcn_s_barrier();
  }

  // Drain remaining DMA before LDS teardown / epilogue.
  asm volatile("s_waitcnt vmcnt(0)" ::: "memory");

#pragma unroll
  for (int i = 0; i < 8; i++)
#pragma unroll
    for (int r = 0; r < 4; r++) {
      float* crow = C + (size_t)(m0 + wm * 128 + i * 16 + quad * 4 + r) * N +
                    n0 + wn * 64 + lnm;
#pragma unroll
      for (int j = 0; j < 4; j++) crow[j * 16] = acc[i][j][r];
    }
}

// ---------------------------------------------------------------------------
// MFMA NT GEMM (f16 in, fp32 out): C[m,n] = sum_k A[m*K+k] * B[n*K+k]
// 128x128 tile, BK=32 (m97 recipe). Kept for N<2048 shapes (kv/up-projs).
// ---------------------------------------------------------------------------
__global__ __launch_bounds__(256) void mla_gemm_mfma(
    const f16* __restrict__ A, const f16* __restrict__ B,
    float* __restrict__ C, int M, int N, int K) {
  __shared__ f16 As[128 * 32];
  __shared__ f16 Bs[128 * 32];

  const int tid = threadIdx.x;
  const int lane = tid & 63;
  const int w = tid >> 6;
  const int lnm = lane & 15, quad = lane >> 4;
  const int wm = w >> 1, wn = w & 1;
  const int m0 = blockIdx.y * 128;
  const int n0 = blockIdx.x * 128;

  const int srow = tid >> 2;
  const int skoff = (tid & 3) * 8;

  f32x4 acc[4][4] = {};

  for (int k0 = 0; k0 < K; k0 += 32) {
    const f16* ag = A + (size_t)(m0 + srow) * K + k0 + skoff;
    const f16* bg = B + (size_t)(n0 + srow) * K + k0 + skoff;
    async_load16(&As[(size_t)tid * 8], ag);
    async_load16(&As[(size_t)(256 + tid) * 8], ag + (size_t)64 * K);
    async_load16(&Bs[(size_t)tid * 8], bg);
    async_load16(&Bs[(size_t)(256 + tid) * 8], bg + (size_t)64 * K);
    __syncthreads();

    f16x8 af[4], bf[4];
#pragma unroll
    for (int i = 0; i < 4; i++)
      af[i] = *(const f16x8*)&As[(wm * 64 + i * 16 + lnm) * 32 + quad * 8];
#pragma unroll
    for (int j = 0; j < 4; j++)
      bf[j] = *(const f16x8*)&Bs[(wn * 64 + j * 16 + lnm) * 32 + quad * 8];
#pragma unroll
    for (int i = 0; i < 4; i++)
#pragma unroll
      for (int j = 0; j < 4; j++)
        acc[i][j] = __builtin_amdgcn_mfma_f32_16x16x32_f16(af[i], bf[j],
                                                           acc[i][j], 0, 0, 0);
    __syncthreads();
  }

#pragma unroll
  for (int i = 0; i < 4; i++)
#pragma unroll
    for (int r = 0; r < 4; r++) {
      float* crow = C + (size_t)(m0 + wm * 64 + i * 16 + quad * 4 + r) * N +
                    n0 + wn * 64 + lnm;
#pragma unroll
      for (int j = 0; j < 4; j++) crow[j * 16] = acc[i][j][r];
    }
}

// ---------------------------------------------------------------------------
// fp32 -> f16 convert (vectorized, n % 4 == 0)
// ---------------------------------------------------------------------------
__global__ __launch_bounds__(256) void mla_cvt_f16(
    const float4* __restrict__ in, f16* __restrict__ out, int n4) {
  int i = blockIdx.x * 256 + threadIdx.x;
  if (i >= n4) return;
  float4 v = in[i];
  f16x4 r = {(f16)v.x, (f16)v.y, (f16)v.z, (f16)v.w};
  *(f16x4*)(out + (size_t)i * 4) = r;
}

// ---------------------------------------------------------------------------
// Fused RoPE (interleaved pairs) + scale + fp32 -> f16 conversion.
// ---------------------------------------------------------------------------
__global__ __launch_bounds__(256) void mla_rope_cvt(
    const float2* __restrict__ x, f16* __restrict__ o,
    const float* __restrict__ cosb, const float* __restrict__ sinb,
    int Hh, float scale, int total) {
  int idx = blockIdx.x * blockDim.x + threadIdx.x;
  if (idx >= total) return;
  const int Dh = DD / 2;
  int i = idx % Dh;
  int t = (idx / (Dh * Hh)) % TT;
  float c = cosb[t * Dh + i];
  float s = sinb[t * Dh + i];
  float2 v = x[idx];
  f16x2 r;
  r.x = (f16)((v.x * c - v.y * s) * scale);
  r.y = (f16)((v.x * s + v.y * c) * scale);
  *(f16x2*)(o + (size_t)idx * 2) = r;
}

// ---------------------------------------------------------------------------
// v fp32 [B,T,D] -> vt f16 [B,D,T]
// ---------------------------------------------------------------------------
__global__ __launch_bounds__(256) void mla_transpose_v(
    const float* __restrict__ v, f16* __restrict__ vt) {
  __shared__ float tl[32][33];
  const int b = blockIdx.z;
  const int t0 = blockIdx.x * 32;
  const int d0 = blockIdx.y * 32;
  const int tx = threadIdx.x & 31;
  const int ty = threadIdx.x >> 5;
#pragma unroll
  for (int k = 0; k < 4; k++)
    tl[ty + 8 * k][tx] = v[((size_t)(b * TT + t0 + ty + 8 * k)) * DD + d0 + tx];
  __syncthreads();
#pragma unroll
  for (int k = 0; k < 4; k++)
    vt[((size_t)(b * DD + d0 + ty + 8 * k)) * TT + t0 + tx] =
        (f16)tl[tx][ty + 8 * k];
}

// ---------------------------------------------------------------------------
// Block-cooperative MFMA flash attention v2 (unchanged this round).
// ---------------------------------------------------------------------------
__global__ __launch_bounds__(256, 2) void mla_flash2(
    const f16* __restrict__ qh, const f16* __restrict__ kh,
    const f16* __restrict__ vth, f16* __restrict__ y) {
  __shared__ f16 Ks[64 * 128];   // (s, ch16B): stored at ch' = ch ^ (s&15)
  __shared__ f16 Vs[128 * 64];   // (d, ch8f16): stored at ch' = ch ^ (d&7)

  const int tid = threadIdx.x;
  const int lane = tid & 63;
  const int w = tid >> 6;
  const int lnm = lane & 15, quad = lane >> 4;

  const int bid = blockIdx.x;
  const int qt = (TT / 128 - 1) - (bid >> 6);  // LPT: longest q-tiles first
  const int bh = bid & 63;
  const int b = bh >> 4, h = bh & 15;
  const int q0b = qt * 128;
  const int q0 = q0b + w * 32;  // this wave's 32 q-rows

  // Q B-frags (global, once per block)
  f16x8 qf[2][4];
#pragma unroll
  for (int qnb = 0; qnb < 2; qnb++) {
    const f16* qrow =
        qh + ((size_t)(b * TT + q0 + qnb * 16 + lnm) * HH + h) * DD;
#pragma unroll
    for (int c = 0; c < 4; c++)
      qf[qnb][c] = *(const f16x8*)(qrow + c * 32 + quad * 8);
  }

  f32x4 O[2][8] = {};
  float l_acc[2] = {0.f, 0.f};

  const int nst = (q0b + 128) / 64;  // 2*qt + 2
  const int wmax = q0 + 31;
  const f16* kbase = kh + (size_t)b * TT * DD;
  const f16* vbase = vth + (size_t)b * DD * TT;

  const int ks_row = tid >> 4;
  const int ks_col = ((tid & 15) ^ (tid >> 4)) * 8;
  const int vs_row = tid >> 3;
  const int vs_col = ((tid & 7) ^ ((tid >> 3) & 7)) * 8;

  for (int st = 0; st < nst; st++) {
    const int s0 = st * 64;
#pragma unroll
    for (int i = 0; i < 4; i++)
      async_load16(&Ks[(size_t)(i * 256 + tid) * 8],
                   kbase + (size_t)(s0 + i * 16 + ks_row) * DD + ks_col);
#pragma unroll
    for (int i = 0; i < 4; i++)
      async_load16(&Vs[(size_t)(i * 256 + tid) * 8],
                   vbase + (size_t)(i * 32 + vs_row) * TT + s0 + vs_col);
    __syncthreads();

    if (s0 <= wmax) {  // wave-uniform: skip fully-masked tiles
      // QK: S^T = K . Q^T
      f32x4 S[2][4] = {};
#pragma unroll
      for (int sb = 0; sb < 4; sb++) {
        const int sl = sb * 16 + lnm;
#pragma unroll
        for (int c = 0; c < 4; c++) {
          f16x8 ka =
              *(const f16x8*)&Ks[sl * 128 + ((c * 4 + quad) ^ lnm) * 8];
          S[0][sb] = __builtin_amdgcn_mfma_f32_16x16x32_f16(ka, qf[0][c],
                                                            S[0][sb], 0, 0, 0);
          S[1][sb] = __builtin_amdgcn_mfma_f32_16x16x32_f16(ka, qf[1][c],
                                                            S[1][sb], 0, 0, 0);
        }
      }

      // P = exp(S) + causal mask, cvt f16, accumulate row-sums
      f16x4 P[2][4];
      const bool domask = (s0 + 63 > q0);
#pragma unroll
      for (int qnb = 0; qnb < 2; qnb++) {
        const int m_abs = q0 + qnb * 16 + lnm;
        float lp = 0.f;
#pragma unroll
        for (int sb = 0; sb < 4; sb++) {
          const int srow = s0 + sb * 16 + quad * 4;
          f16x4 ph;
#pragma unroll
          for (int j = 0; j < 4; j++) {
            float p = __expf(S[qnb][sb][j]);
            if (domask && (srow + j > m_abs)) p = 0.f;
            lp += p;
            ph[j] = (f16)p;
          }
          P[qnb][sb] = ph;
        }
        l_acc[qnb] += lp;
      }

      // PV: O += P . V  (P in-register A-frags; V from LDS)
#pragma unroll
      for (int sb = 0; sb < 4; sb++) {
        const int chb = sb * 2 + (quad >> 1);
        const int soff = (quad & 1) * 4;
#pragma unroll
        for (int db = 0; db < 8; db++) {
          const int d = db * 16 + lnm;
          f16x4 vb =
              *(const f16x4*)&Vs[d * 64 + ((chb ^ (d & 7)) * 8) + soff];
          O[0][db] = __builtin_amdgcn_mfma_f32_16x16x16f16(P[0][sb], vb,
                                                           O[0][db], 0, 0, 0);
          O[1][db] = __builtin_amdgcn_mfma_f32_16x16x16f16(P[1][sb], vb,
                                                           O[1][db], 0, 0, 0);
        }
      }
    }
    __syncthreads();
  }

  // Row-sums across quads
#pragma unroll
  for (int qnb = 0; qnb < 2; qnb++) {
    float l = l_acc[qnb];
    l += __shfl_xor(l, 16, 64);
    l += __shfl_xor(l, 32, 64);
    l_acc[qnb] = l;
  }

  // Epilogue: y = O / l (f16)
#pragma unroll
  for (int qnb = 0; qnb < 2; qnb++) {
    float linv[4];
#pragma unroll
    for (int r = 0; r < 4; r++)
      linv[r] = 1.f / __shfl(l_acc[qnb], quad * 4 + r, 64);
#pragma unroll
    for (int db = 0; db < 8; db++)
#pragma unroll
      for (int r = 0; r < 4; r++) {
        size_t off =
            ((size_t)(b * TT + q0 + qnb * 16 + quad * 4 + r) * HH + h) * DD +
            db * 16 + lnm;
        y[off] = (f16)(O[qnb][db][r] * linv[r]);
      }
  }
}

// ---------------------------------------------------------------------------
extern "C" void kernel_launch(void* const* d_in, const int* in_sizes, int n_in,
                              void* d_out, int out_size, void* d_ws,
                              size_t ws_size, hipStream_t stream) {
  const float* x      = (const float*)d_in[0];
  const float* fcos   = (const float*)d_in[1];
  const float* fsin   = (const float*)d_in[2];
  const float* wq     = (const float*)d_in[3];
  const float* wdown  = (const float*)d_in[4];
  const float* wk_up  = (const float*)d_in[5];
  const float* wv_up  = (const float*)d_in[6];
  const float* wo     = (const float*)d_in[7];
  float* out = (float*)d_out;

  const int M = BB * TT;  // 8192

  // Workspace layout. Aliases: qh <- xh (xh dead after down-proj GEMM),
  // yh <- q (q fp32 dead after rope_cvt_q).
  float* ws = (float*)d_ws;
  float* q      = ws;                              // 16.7M f32 (64 MB)
  float* kv     = q + (size_t)M * CC;              // 4.2M f32 (16 MB)
  float* kk     = kv + (size_t)M * LL;             // 1M f32 (4 MB)
  float* vv     = kk + (size_t)M * DD;             // 1M f32 (4 MB)
  f16*   xh     = (f16*)(vv + (size_t)M * DD);     // 16.7M f16 (32 MB)
  f16*   wqh    = xh + (size_t)M * CC;             // 4.2M f16 (8 MB)
  f16*   wdownh = wqh + (size_t)CC * CC;           // 1M f16 (2 MB)
  f16*   wkuph  = wdownh + (size_t)LL * CC;        // 64K f16
  f16*   wvuph  = wkuph + (size_t)DD * LL;         // 64K f16
  f16*   woh    = wvuph + (size_t)DD * LL;         // 4.2M f16 (8 MB)
  f16*   kvh    = woh + (size_t)CC * CC;           // 4.2M f16 (8 MB)
  f16*   khb    = kvh + (size_t)M * LL;            // 1M f16 (2 MB)
  f16*   vth    = khb + (size_t)M * DD;            // 1M f16 (2 MB)
  f16*   qh     = xh;                              // alias
  f16*   yh     = (f16*)q;                         // alias

  dim3 blk(256);

  // fp32 -> f16 conversions
  mla_cvt_f16<<<(M * CC / 4 + 255) / 256, blk, 0, stream>>>(
      (const float4*)x, xh, M * CC / 4);
  mla_cvt_f16<<<(CC * CC / 4 + 255) / 256, blk, 0, stream>>>(
      (const float4*)wq, wqh, CC * CC / 4);
  mla_cvt_f16<<<(LL * CC / 4 + 255) / 256, blk, 0, stream>>>(
      (const float4*)wdown, wdownh, LL * CC / 4);
  mla_cvt_f16<<<(DD * LL / 4 + 255) / 256, blk, 0, stream>>>(
      (const float4*)wk_up, wkuph, DD * LL / 4);
  mla_cvt_f16<<<(DD * LL / 4 + 255) / 256, blk, 0, stream>>>(
      (const float4*)wv_up, wvuph, DD * LL / 4);
  mla_cvt_f16<<<(CC * CC / 4 + 255) / 256, blk, 0, stream>>>(
      (const float4*)wo, woh, CC * CC / 4);

  // q = x @ wq^T (8-phase 256^2) ; kv = x @ wdown^T (128^2: N=512 -> 256 wgs)
  mla_gemm_256<<<dim3((M / 256) * (CC / 256)), dim3(512), 0, stream>>>(
      xh, wqh, q, M, CC, CC);
  mla_gemm_mfma<<<dim3(LL / 128, M / 128), blk, 0, stream>>>(
      xh, wdownh, kv, M, LL, CC);

  // kv -> f16, then k/v up-projections
  mla_cvt_f16<<<(M * LL / 4 + 255) / 256, blk, 0, stream>>>(
      (const float4*)kv, kvh, M * LL / 4);
  mla_gemm_mfma<<<dim3(DD / 128, M / 128), blk, 0, stream>>>(
      kvh, wkuph, kk, M, DD, LL);
  mla_gemm_mfma<<<dim3(DD / 128, M / 128), blk, 0, stream>>>(
      kvh, wvuph, vv, M, DD, LL);

  // RoPE + f16 conversion (1/sqrt(128) folded into q)
  {
    const float SCL = 0.08838834764831845f;
    int total_q = BB * TT * HH * (DD / 2);
    mla_rope_cvt<<<(total_q + 255) / 256, blk, 0, stream>>>(
        (const float2*)q, qh, fcos, fsin, HH, SCL, total_q);
    int total_k = BB * TT * (DD / 2);
    mla_rope_cvt<<<(total_k + 255) / 256, blk, 0, stream>>>(
        (const float2*)kk, khb, fcos, fsin, 1, 1.0f, total_k);
  }

  // v -> vt (transposed f16)
  mla_transpose_v<<<dim3(TT / 32, DD / 32, BB), blk, 0, stream>>>(vv, vth);

  // Flash attention v2 -> yh (f16). 1024 blocks, LPT order.
  mla_flash2<<<dim3(BB * HH * (TT / 128)), blk, 0, stream>>>(qh, khb, vth, yh);

  // out = y @ wo^T (8-phase 256^2)
  mla_gemm_256<<<dim3((M / 256) * (CC / 256)), dim3(512), 0, stream>>>(
      yh, woh, out, M, CC, CC);
}

// Round 3
// 469.722 us; speedup vs baseline: 1.2262x; 1.0329x over previous
//
#include <hip/hip_runtime.h>
#include <hip/hip_bf16.h>
#include <cstddef>

// Problem constants
#define BB 4
#define TT 2048
#define CC 2048
#define HH 16
#define DD 128
#define LL 512

typedef _Float16 f16;
typedef f16 f16x2 __attribute__((ext_vector_type(2)));
typedef f16 f16x4 __attribute__((ext_vector_type(4)));
typedef f16 f16x8 __attribute__((ext_vector_type(8)));
typedef float f32x4 __attribute__((ext_vector_type(4)));

// ---------------------------------------------------------------------------
// async global->LDS, 16 B per lane (global_load_lds_dwordx4).
// LDS dest = wave-uniform base + lane*16 (fixed); global side is a per-lane
// gather -> swizzles go into the GLOBAL address, LDS stays lane-contiguous.
// ---------------------------------------------------------------------------
__device__ __forceinline__ void async_load16(void* lptr, const void* gptr) {
  __builtin_amdgcn_global_load_lds(
      (const __attribute__((address_space(1))) unsigned int*)gptr,
      (__attribute__((address_space(3))) unsigned int*)lptr, 16, 0, 0);
}

// ---------------------------------------------------------------------------
// 256x256 8-phase MFMA NT GEMM (f16 in): C[m,n] = sum_k A[m,k]B[n,k]
// m201-style template: BK=64, 8 waves (2M x 4N), 128 KiB double-buffered LDS,
// counted vmcnt (never 0 in main loop), per-phase barriers + setprio around
// the MFMA cluster, XOR chunk swizzle via pre-swizzled GLOBAL gather address.
// EPI=0: fp32 store. EPI=1: fused RoPE(interleaved)+scale+f16 store (q path;
// requires cols to be h*DD+d layout, N==CC).
// ---------------------------------------------------------------------------
template <int EPI>
__global__ __launch_bounds__(512, 2) void mla_gemm_256(
    const f16* __restrict__ A, const f16* __restrict__ B,
    void* __restrict__ Cv, int M, int N, int K,
    const float* __restrict__ cosb, const float* __restrict__ sinb) {
  // [buf][0=A,1=B][256 rows][64 f16]; row r chunk ch (16B units) stored at
  // ch' = ch ^ (r&7)  (pre-swizzled on the global side).
  __shared__ __align__(16) f16 smem[2][2][256 * 64];

  const int tid = threadIdx.x;       // 0..511
  const int lane = tid & 63;
  const int w = tid >> 6;            // 0..7
  const int lnm = lane & 15, quad = lane >> 4;
  const int wm = w >> 2, wn = w & 3; // 2 x 4 wave grid; wave tile 128x64

  // Bijective XCD-aware block swizzle (m204 variant).
  const int nwg = gridDim.x;
  const int bid0 = blockIdx.x;
  const int q8 = nwg >> 3, r8 = nwg & 7;
  const int xcd = bid0 & 7, lid = bid0 >> 3;
  const int wg =
      (xcd < r8 ? xcd * (q8 + 1) : r8 * (q8 + 1) + (xcd - r8) * q8) + lid;
  const int ntc = N >> 8;
  const int m0 = (wg / ntc) * 256;
  const int n0 = (wg % ntc) * 256;

  // Staging geometry: issue j covers LDS slot idx=j*512+tid -> local row
  // r = j*64 + (tid>>3), stored chunk ch' = tid&7; global chunk
  // ch = ch' ^ (r&7) = (tid&7) ^ ((tid>>3)&7)  (j*64 is 0 mod 8).
  const int srow = tid >> 3;
  const int sch = (tid & 7) ^ ((tid >> 3) & 7);
  const f16* Ag = A + (size_t)(m0 + srow) * K + sch * 8;
  const f16* Bg = B + (size_t)(n0 + srow) * K + sch * 8;

  // half h: 0=A-lo 1=A-hi 2=B-lo 3=B-hi; each = 2 global_load_lds / thread
  auto stage = [&](int bi, int k0, int h) {
    const int mat = h >> 1;
    const int rb = (h & 1) * 128;
    const f16* g = (mat ? Bg : Ag) + (size_t)rb * K + k0;
    f16* l = &smem[bi][mat][rb * 64 + tid * 8];
    async_load16(l, g);
    async_load16(l + 4096, g + (size_t)64 * K);
  };

  const int rx8 = lnm & 7;  // (row & 7) for all fragment rows below
  auto rdA = [&](const f16* Ab, int i, int ks) -> f16x8 {
    return *(const f16x8*)&Ab[(wm * 128 + i * 16 + lnm) * 64 +
                              (((ks * 4 + quad) ^ rx8) * 8)];
  };
  auto rdB = [&](const f16* Bb, int j, int ks) -> f16x8 {
    return *(const f16x8*)&Bb[(wn * 64 + j * 16 + lnm) * 64 +
                              (((ks * 4 + quad) ^ rx8) * 8)];
  };

  f32x4 acc[8][4] = {};

  const int NT = K >> 6;

  // Prologue: tile0 fully + tile1 A-lo (the (t-1).4-equivalent stage).
  stage(0, 0, 0);
  stage(0, 0, 1);
  stage(0, 0, 2);
  stage(0, 0, 3);
  stage(1, 64, 0);
  asm volatile("s_waitcnt vmcnt(2)" ::: "memory");  // tile0 landed
  __builtin_amdgcn_s_barrier();

  for (int t = 0; t < NT; ++t) {
    const int bi = t & 1;
    const f16* Ab = smem[bi][0];
    const f16* Bb = smem[bi][1];
    // Clamped k-offsets for tail staging (writes valid-but-dead data into a
    // buffer region that is never read again; keeps vmcnt counts uniform).
    const int k1 = (t + 1 < NT ? t + 1 : t) << 6;
    const int k2 = (t + 2 < NT ? t + 2 : t) << 6;

    f16x8 Ar[4][2], Br[2][2];

    // -------- phase 1: quadrant (mq0, nq0) -- 12 ds_reads --------
#pragma unroll
    for (int i = 0; i < 4; i++)
#pragma unroll
      for (int ks = 0; ks < 2; ks++) Ar[i][ks] = rdA(Ab, i, ks);
#pragma unroll
    for (int j = 0; j < 2; j++)
#pragma unroll
      for (int ks = 0; ks < 2; ks++) Br[j][ks] = rdB(Bb, j, ks);
    stage(bi ^ 1, k1, 1);
    __builtin_amdgcn_s_barrier();
    asm volatile("s_waitcnt lgkmcnt(0)" ::: "memory");
    __builtin_amdgcn_s_setprio(1);
#pragma unroll
    for (int i = 0; i < 4; i++)
#pragma unroll
      for (int j = 0; j < 2; j++)
#pragma unroll
        for (int ks = 0; ks < 2; ks++)
          acc[i][j] = __builtin_amdgcn_mfma_f32_16x16x32_f16(
              Ar[i][ks], Br[j][ks], acc[i][j], 0, 0, 0);
    __builtin_amdgcn_s_setprio(0);
    __builtin_amdgcn_s_barrier();

    // -------- phase 2: quadrant (mq0, nq1) -- 4 ds_reads --------
#pragma unroll
    for (int j = 0; j < 2; j++)
#pragma unroll
      for (int ks = 0; ks < 2; ks++) Br[j][ks] = rdB(Bb, 2 + j, ks);
    stage(bi ^ 1, k1, 2);
    __builtin_amdgcn_s_barrier();
    asm volatile("s_waitcnt lgkmcnt(0)" ::: "memory");
    __builtin_amdgcn_s_setprio(1);
#pragma unroll
    for (int i = 0; i < 4; i++)
#pragma unroll
      for (int j = 0; j < 2; j++)
#pragma unroll
        for (int ks = 0; ks < 2; ks++)
          acc[i][2 + j] = __builtin_amdgcn_mfma_f32_16x16x32_f16(
              Ar[i][ks], Br[j][ks], acc[i][2 + j], 0, 0, 0);
    __builtin_amdgcn_s_setprio(0);
    __builtin_amdgcn_s_barrier();

    // -------- phase 3: quadrant (mq1, nq1) -- 8 ds_reads --------
#pragma unroll
    for (int i = 0; i < 4; i++)
#pragma unroll
      for (int ks = 0; ks < 2; ks++) Ar[i][ks] = rdA(Ab, 4 + i, ks);
    stage(bi ^ 1, k1, 3);
    __builtin_amdgcn_s_barrier();
    asm volatile("s_waitcnt lgkmcnt(0)" ::: "memory");
    __builtin_amdgcn_s_setprio(1);
#pragma unroll
    for (int i = 0; i < 4; i++)
#pragma unroll
      for (int j = 0; j < 2; j++)
#pragma unroll
        for (int ks = 0; ks < 2; ks++)
          acc[4 + i][2 + j] = __builtin_amdgcn_mfma_f32_16x16x32_f16(
              Ar[i][ks], Br[j][ks], acc[4 + i][2 + j], 0, 0, 0);
    __builtin_amdgcn_s_setprio(0);
    __builtin_amdgcn_s_barrier();

    // -------- phase 4: quadrant (mq1, nq0) -- 4 ds_reads (B re-read) ------
    // Stage targets buf[bi] A-lo; this phase only reads buf[bi] B region.
#pragma unroll
    for (int j = 0; j < 2; j++)
#pragma unroll
      for (int ks = 0; ks < 2; ks++) Br[j][ks] = rdB(Bb, j, ks);
    stage(bi, k2, 0);
    __builtin_amdgcn_s_barrier();
    asm volatile("s_waitcnt lgkmcnt(0)" ::: "memory");
    __builtin_amdgcn_s_setprio(1);
#pragma unroll
    for (int i = 0; i < 4; i++)
#pragma unroll
      for (int j = 0; j < 2; j++)
#pragma unroll
        for (int ks = 0; ks < 2; ks++)
          acc[4 + i][j] = __builtin_amdgcn_mfma_f32_16x16x32_f16(
              Ar[i][ks], Br[j][ks], acc[4 + i][j], 0, 0, 0);
    __builtin_amdgcn_s_setprio(0);
    // Counted wait: allow only this phase's 2 loads outstanding -> tile t+1
    // (h0 from (t-1).4, h1..h3 from t.1-3) is fully landed after barrier.
    asm volatile("s_waitcnt vmcnt(2)" ::: "memory");
    __builtin_amdgcn_s_barrier();
  }

  // Drain remaining DMA before LDS teardown / epilogue.
  asm volatile("s_waitcnt vmcnt(0)" ::: "memory");

  if constexpr (EPI == 0) {
    float* C = (float*)Cv;
#pragma unroll
    for (int i = 0; i < 8; i++)
#pragma unroll
      for (int r = 0; r < 4; r++) {
        float* crow = C + (size_t)(m0 + wm * 128 + i * 16 + quad * 4 + r) * N +
                      n0 + wn * 64 + lnm;
#pragma unroll
        for (int j = 0; j < 4; j++) crow[j * 16] = acc[i][j][r];
      }
  } else {
    // Fused RoPE + 1/sqrt(D) scale + f16 store. Pair (2i,2i+1) along cols:
    // partner value lives on the lnm^1 lane -> shfl_xor(.,1).
    f16* C = (f16*)Cv;
    const float SCL = 0.08838834764831845f;
#pragma unroll
    for (int i = 0; i < 8; i++)
#pragma unroll
      for (int r = 0; r < 4; r++) {
        const int m = m0 + wm * 128 + i * 16 + quad * 4 + r;
        const int t = m & (TT - 1);
#pragma unroll
        for (int j = 0; j < 4; j++) {
          const int col = n0 + wn * 64 + j * 16 + lnm;
          float v = acc[i][j][r];
          float u = __shfl_xor(v, 1, 64);
          const int fi = (col & (DD - 1)) >> 1;
          const float ct = cosb[t * (DD / 2) + fi];
          const float st2 = sinb[t * (DD / 2) + fi];
          const float o =
              (lnm & 1) ? (u * st2 + v * ct) : (v * ct - u * st2);
          C[(size_t)m * N + col] = (f16)(o * SCL);
        }
      }
  }
}

// ---------------------------------------------------------------------------
// MFMA NT GEMM (f16 in, fp32 out): C[m,n] = sum_k A[m*K+k] * B[n*K+k]
// 128x128 tile, BK=32 (m97 recipe). Kept for N<2048 shapes (kv/up-projs).
// ---------------------------------------------------------------------------
__global__ __launch_bounds__(256) void mla_gemm_mfma(
    const f16* __restrict__ A, const f16* __restrict__ B,
    float* __restrict__ C, int M, int N, int K) {
  __shared__ f16 As[128 * 32];
  __shared__ f16 Bs[128 * 32];

  const int tid = threadIdx.x;
  const int lane = tid & 63;
  const int w = tid >> 6;
  const int lnm = lane & 15, quad = lane >> 4;
  const int wm = w >> 1, wn = w & 1;
  const int m0 = blockIdx.y * 128;
  const int n0 = blockIdx.x * 128;

  const int srow = tid >> 2;
  const int skoff = (tid & 3) * 8;

  f32x4 acc[4][4] = {};

  for (int k0 = 0; k0 < K; k0 += 32) {
    const f16* ag = A + (size_t)(m0 + srow) * K + k0 + skoff;
    const f16* bg = B + (size_t)(n0 + srow) * K + k0 + skoff;
    async_load16(&As[(size_t)tid * 8], ag);
    async_load16(&As[(size_t)(256 + tid) * 8], ag + (size_t)64 * K);
    async_load16(&Bs[(size_t)tid * 8], bg);
    async_load16(&Bs[(size_t)(256 + tid) * 8], bg + (size_t)64 * K);
    __syncthreads();

    f16x8 af[4], bf[4];
#pragma unroll
    for (int i = 0; i < 4; i++)
      af[i] = *(const f16x8*)&As[(wm * 64 + i * 16 + lnm) * 32 + quad * 8];
#pragma unroll
    for (int j = 0; j < 4; j++)
      bf[j] = *(const f16x8*)&Bs[(wn * 64 + j * 16 + lnm) * 32 + quad * 8];
#pragma unroll
    for (int i = 0; i < 4; i++)
#pragma unroll
      for (int j = 0; j < 4; j++)
        acc[i][j] = __builtin_amdgcn_mfma_f32_16x16x32_f16(af[i], bf[j],
                                                           acc[i][j], 0, 0, 0);
    __syncthreads();
  }

#pragma unroll
  for (int i = 0; i < 4; i++)
#pragma unroll
    for (int r = 0; r < 4; r++) {
      float* crow = C + (size_t)(m0 + wm * 64 + i * 16 + quad * 4 + r) * N +
                    n0 + wn * 64 + lnm;
#pragma unroll
      for (int j = 0; j < 4; j++) crow[j * 16] = acc[i][j][r];
    }
}

// ---------------------------------------------------------------------------
// fp32 -> f16 convert (vectorized, n % 4 == 0)
// ---------------------------------------------------------------------------
__global__ __launch_bounds__(256) void mla_cvt_f16(
    const float4* __restrict__ in, f16* __restrict__ out, int n4) {
  int i = blockIdx.x * 256 + threadIdx.x;
  if (i >= n4) return;
  float4 v = in[i];
  f16x4 r = {(f16)v.x, (f16)v.y, (f16)v.z, (f16)v.w};
  *(f16x4*)(out + (size_t)i * 4) = r;
}

// ---------------------------------------------------------------------------
// Fused RoPE (interleaved pairs) + scale + fp32 -> f16 conversion (k path).
// ---------------------------------------------------------------------------
__global__ __launch_bounds__(256) void mla_rope_cvt(
    const float2* __restrict__ x, f16* __restrict__ o,
    const float* __restrict__ cosb, const float* __restrict__ sinb,
    int Hh, float scale, int total) {
  int idx = blockIdx.x * blockDim.x + threadIdx.x;
  if (idx >= total) return;
  const int Dh = DD / 2;
  int i = idx % Dh;
  int t = (idx / (Dh * Hh)) % TT;
  float c = cosb[t * Dh + i];
  float s = sinb[t * Dh + i];
  float2 v = x[idx];
  f16x2 r;
  r.x = (f16)((v.x * c - v.y * s) * scale);
  r.y = (f16)((v.x * s + v.y * c) * scale);
  *(f16x2*)(o + (size_t)idx * 2) = r;
}

// ---------------------------------------------------------------------------
// v fp32 [B,T,D] -> vt f16 [B,D,T]
// ---------------------------------------------------------------------------
__global__ __launch_bounds__(256) void mla_transpose_v(
    const float* __restrict__ v, f16* __restrict__ vt) {
  __shared__ float tl[32][33];
  const int b = blockIdx.z;
  const int t0 = blockIdx.x * 32;
  const int d0 = blockIdx.y * 32;
  const int tx = threadIdx.x & 31;
  const int ty = threadIdx.x >> 5;
#pragma unroll
  for (int k = 0; k < 4; k++)
    tl[ty + 8 * k][tx] = v[((size_t)(b * TT + t0 + ty + 8 * k)) * DD + d0 + tx];
  __syncthreads();
#pragma unroll
  for (int k = 0; k < 4; k++)
    vt[((size_t)(b * DD + d0 + ty + 8 * k)) * TT + t0 + tx] =
        (f16)tl[tx][ty + 8 * k];
}

// ---------------------------------------------------------------------------
// Block-cooperative MFMA flash attention v3.
// (a) double-buffered K/V LDS tiles (64 KiB) with stage-before-compute and
// ONE drain+barrier per s-tile (T3-minimum recipe);
// (b) PV at 16x16x32 via a per-lane k->s permutation shared by the P (A) and
// V (B) fragments -- exact since MFMA sums over the shared k index;
// (c) s_setprio(1) around the MFMA clusters.
// ---------------------------------------------------------------------------
__global__ __launch_bounds__(256, 2) void mla_flash2(
    const f16* __restrict__ qh, const f16* __restrict__ kh,
    const f16* __restrict__ vth, f16* __restrict__ y) {
  __shared__ f16 Ks[2][64 * 128];  // (s, ch16B): stored at ch' = ch ^ (s&15)
  __shared__ f16 Vs[2][128 * 64];  // (d, ch8f16): stored at ch' = ch ^ (d&7)

  const int tid = threadIdx.x;
  const int lane = tid & 63;
  const int w = tid >> 6;
  const int lnm = lane & 15, quad = lane >> 4;

  const int bid = blockIdx.x;
  const int qt = (TT / 128 - 1) - (bid >> 6);  // LPT: longest q-tiles first
  const int bh = bid & 63;
  const int b = bh >> 4, h = bh & 15;
  const int q0b = qt * 128;
  const int q0 = q0b + w * 32;  // this wave's 32 q-rows

  // Q B-frags (global, once per block)
  f16x8 qf[2][4];
#pragma unroll
  for (int qnb = 0; qnb < 2; qnb++) {
    const f16* qrow =
        qh + ((size_t)(b * TT + q0 + qnb * 16 + lnm) * HH + h) * DD;
#pragma unroll
    for (int c = 0; c < 4; c++)
      qf[qnb][c] = *(const f16x8*)(qrow + c * 32 + quad * 8);
  }

  f32x4 O[2][8] = {};
  float l_acc[2] = {0.f, 0.f};

  const int nst = (q0b + 128) / 64;  // 2*qt + 2
  const int wmax = q0 + 31;
  const f16* kbase = kh + (size_t)b * TT * DD;
  const f16* vbase = vth + (size_t)b * DD * TT;

  const int ks_row = tid >> 4;
  const int ks_col = ((tid & 15) ^ (tid >> 4)) * 8;
  const int vs_row = tid >> 3;
  const int vs_col = ((tid & 7) ^ ((tid >> 3) & 7)) * 8;

  auto stage = [&](int buf, int st) {
    const int s0 = st * 64;
#pragma unroll
    for (int i = 0; i < 4; i++)
      async_load16(&Ks[buf][(size_t)(i * 256 + tid) * 8],
                   kbase + (size_t)(s0 + i * 16 + ks_row) * DD + ks_col);
#pragma unroll
    for (int i = 0; i < 4; i++)
      async_load16(&Vs[buf][(size_t)(i * 256 + tid) * 8],
                   vbase + (size_t)(i * 32 + vs_row) * TT + s0 + vs_col);
  };

  stage(0, 0);
  __syncthreads();  // drains vmcnt(0): tile 0 landed

  for (int st = 0; st < nst; st++) {
    const int cur = st & 1;
    const int s0 = st * 64;
    // Issue next tile's DMA first; its latency hides under this tile's
    // compute, so the end-of-tile drain is cheap.
    if (st + 1 < nst) stage(cur ^ 1, st + 1);

    if (s0 <= wmax) {  // wave-uniform: skip fully-masked tiles
      const f16* Kc = Ks[cur];
      const f16* Vc = Vs[cur];

      // QK: S^T = K . Q^T
      f32x4 S[2][4] = {};
      __builtin_amdgcn_s_setprio(1);
#pragma unroll
      for (int sb = 0; sb < 4; sb++) {
        const int sl = sb * 16 + lnm;
#pragma unroll
        for (int c = 0; c < 4; c++) {
          f16x8 ka =
              *(const f16x8*)&Kc[sl * 128 + ((c * 4 + quad) ^ lnm) * 8];
          S[0][sb] = __builtin_amdgcn_mfma_f32_16x16x32_f16(ka, qf[0][c],
                                                            S[0][sb], 0, 0, 0);
          S[1][sb] = __builtin_amdgcn_mfma_f32_16x16x32_f16(ka, qf[1][c],
                                                            S[1][sb], 0, 0, 0);
        }
      }
      __builtin_amdgcn_s_setprio(0);

      // P = exp(S) + causal mask, packed directly as K=32 A-frags:
      // P8[qnb][c][e]: e<4 -> s=c*32+quad*4+e (sb=2c),
      //                e>=4 -> s=c*32+16+quad*4+(e-4) (sb=2c+1).
      f16x8 P8[2][2];
      const bool domask = (s0 + 63 > q0);
#pragma unroll
      for (int qnb = 0; qnb < 2; qnb++) {
        const int m_abs = q0 + qnb * 16 + lnm;
        float lp = 0.f;
#pragma unroll
        for (int sb = 0; sb < 4; sb++) {
          const int srow = s0 + sb * 16 + quad * 4;
#pragma unroll
          for (int j = 0; j < 4; j++) {
            float p = __expf(S[qnb][sb][j]);
            if (domask && (srow + j > m_abs)) p = 0.f;
            lp += p;
            P8[qnb][sb >> 1][(sb & 1) * 4 + j] = (f16)p;
          }
        }
        l_acc[qnb] += lp;
      }

      // PV at K=32: V frag uses the SAME k->s permutation as P8.
      __builtin_amdgcn_s_setprio(1);
#pragma unroll
      for (int c = 0; c < 2; c++) {
        const int chlo = c * 4 + (quad >> 1);
        const int soff = (quad & 1) * 4;
#pragma unroll
        for (int db = 0; db < 8; db++) {
          const int d = db * 16 + lnm;
          const f16* vrow = &Vc[d * 64];
          f16x4 vlo = *(const f16x4*)&vrow[((chlo ^ (d & 7)) * 8) + soff];
          f16x4 vhi =
              *(const f16x4*)&vrow[(((chlo + 2) ^ (d & 7)) * 8) + soff];
          f16x8 vb;
#pragma unroll
          for (int j = 0; j < 4; j++) {
            vb[j] = vlo[j];
            vb[4 + j] = vhi[j];
          }
          O[0][db] = __builtin_amdgcn_mfma_f32_16x16x32_f16(P8[0][c], vb,
                                                            O[0][db], 0, 0, 0);
          O[1][db] = __builtin_amdgcn_mfma_f32_16x16x32_f16(P8[1][c], vb,
                                                            O[1][db], 0, 0, 0);
        }
      }
      __builtin_amdgcn_s_setprio(0);
    }
    __syncthreads();  // drains next-tile DMA (already landed) + buffer swap
  }

  // Row-sums across quads
#pragma unroll
  for (int qnb = 0; qnb < 2; qnb++) {
    float l = l_acc[qnb];
    l += __shfl_xor(l, 16, 64);
    l += __shfl_xor(l, 32, 64);
    l_acc[qnb] = l;
  }

  // Epilogue: y = O / l (f16)
#pragma unroll
  for (int qnb = 0; qnb < 2; qnb++) {
    float linv[4];
#pragma unroll
    for (int r = 0; r < 4; r++)
      linv[r] = 1.f / __shfl(l_acc[qnb], quad * 4 + r, 64);
#pragma unroll
    for (int db = 0; db < 8; db++)
#pragma unroll
      for (int r = 0; r < 4; r++) {
        size_t off =
            ((size_t)(b * TT + q0 + qnb * 16 + quad * 4 + r) * HH + h) * DD +
            db * 16 + lnm;
        y[off] = (f16)(O[qnb][db][r] * linv[r]);
      }
  }
}

// ---------------------------------------------------------------------------
extern "C" void kernel_launch(void* const* d_in, const int* in_sizes, int n_in,
                              void* d_out, int out_size, void* d_ws,
                              size_t ws_size, hipStream_t stream) {
  const float* x      = (const float*)d_in[0];
  const float* fcos   = (const float*)d_in[1];
  const float* fsin   = (const float*)d_in[2];
  const float* wq     = (const float*)d_in[3];
  const float* wkv_dn = (const float*)d_in[4];
  const float* wk_up  = (const float*)d_in[5];
  const float* wv_up  = (const float*)d_in[6];
  const float* wo     = (const float*)d_in[7];
  float* out = (float*)d_out;

  const int M = BB * TT;  // 8192

  // Workspace layout. q-GEMM writes qh (f16, roped) directly, so the old
  // fp32 q buffer is repurposed: [qh | yh] (each M*CC f16 = 32 MB).
  float* ws = (float*)d_ws;
  float* qbuf   = ws;                              // 64 MB slot: qh + yh
  float* kv     = qbuf + (size_t)M * CC;           // 4.2M f32 (16 MB)
  float* kk     = kv + (size_t)M * LL;             // 1M f32 (4 MB)
  float* vv     = kk + (size_t)M * DD;             // 1M f32 (4 MB)
  f16*   xh     = (f16*)(vv + (size_t)M * DD);     // 16.7M f16 (32 MB)
  f16*   wqh    = xh + (size_t)M * CC;             // 4.2M f16 (8 MB)
  f16*   wdownh = wqh + (size_t)CC * CC;           // 1M f16 (2 MB)
  f16*   wkuph  = wdownh + (size_t)LL * CC;        // 64K f16
  f16*   wvuph  = wkuph + (size_t)DD * LL;         // 64K f16
  f16*   woh    = wvuph + (size_t)DD * LL;         // 4.2M f16 (8 MB)
  f16*   kvh    = woh + (size_t)CC * CC;           // 4.2M f16 (8 MB)
  f16*   khb    = kvh + (size_t)M * LL;             // 1M f16 (2 MB)
  f16*   vth    = khb + (size_t)M * DD;            // 1M f16 (2 MB)
  f16*   qh     = (f16*)qbuf;                      // 32 MB
  f16*   yh     = qh + (size_t)M * CC;             // 32 MB

  dim3 blk(256);

  // fp32 -> f16 conversions
  mla_cvt_f16<<<(M * CC / 4 + 255) / 256, blk, 0, stream>>>(
      (const float4*)x, xh, M * CC / 4);
  mla_cvt_f16<<<(CC * CC / 4 + 255) / 256, blk, 0, stream>>>(
      (const float4*)wq, wqh, CC * CC / 4);
  mla_cvt_f16<<<(LL * CC / 4 + 255) / 256, blk, 0, stream>>>(
      (const float4*)wkv_dn, wdownh, LL * CC / 4);
  mla_cvt_f16<<<(DD * LL / 4 + 255) / 256, blk, 0, stream>>>(
      (const float4*)wk_up, wkuph, DD * LL / 4);
  mla_cvt_f16<<<(DD * LL / 4 + 255) / 256, blk, 0, stream>>>(
      (const float4*)wv_up, wvuph, DD * LL / 4);
  mla_cvt_f16<<<(CC * CC / 4 + 255) / 256, blk, 0, stream>>>(
      (const float4*)wo, woh, CC * CC / 4);

  // q = rope(x @ wq^T) (8-phase 256^2, fused epilogue -> f16 qh)
  mla_gemm_256<1><<<dim3((M / 256) * (CC / 256)), dim3(512), 0, stream>>>(
      xh, wqh, qh, M, CC, CC, fcos, fsin);
  // kv = x @ wdown^T (128^2: N=512 -> 256 wgs)
  mla_gemm_mfma<<<dim3(LL / 128, M / 128), blk, 0, stream>>>(
      xh, wdownh, kv, M, LL, CC);

  // kv -> f16, then k/v up-projections
  mla_cvt_f16<<<(M * LL / 4 + 255) / 256, blk, 0, stream>>>(
      (const float4*)kv, kvh, M * LL / 4);
  mla_gemm_mfma<<<dim3(DD / 128, M / 128), blk, 0, stream>>>(
      kvh, wkuph, kk, M, DD, LL);
  mla_gemm_mfma<<<dim3(DD / 128, M / 128), blk, 0, stream>>>(
      kvh, wvuph, vv, M, DD, LL);

  // k RoPE + f16 conversion
  {
    int total_k = BB * TT * (DD / 2);
    mla_rope_cvt<<<(total_k + 255) / 256, blk, 0, stream>>>(
        (const float2*)kk, khb, fcos, fsin, 1, 1.0f, total_k);
  }

  // v -> vt (transposed f16)
  mla_transpose_v<<<dim3(TT / 32, DD / 32, BB), blk, 0, stream>>>(vv, vth);

  // Flash attention v3 -> yh (f16). 1024 blocks, LPT order.
  mla_flash2<<<dim3(BB * HH * (TT / 128)), blk, 0, stream>>>(qh, khb, vth, yh);

  // out = y @ wo^T (8-phase 256^2)
  mla_gemm_256<0><<<dim3((M / 256) * (CC / 256)), dim3(512), 0, stream>>>(
      yh, woh, out, M, CC, CC, nullptr, nullptr);
}

// Round 5
// 465.919 us; speedup vs baseline: 1.2363x; 1.0082x over previous
//
#include <hip/hip_runtime.h>
#include <hip/hip_bf16.h>
#include <cstddef>

// Problem constants
#define BB 4
#define TT 2048
#define CC 2048
#define HH 16
#define DD 128
#define LL 512

typedef _Float16 f16;
typedef f16 f16x2 __attribute__((ext_vector_type(2)));
typedef f16 f16x4 __attribute__((ext_vector_type(4)));
typedef f16 f16x8 __attribute__((ext_vector_type(8)));
typedef float f32x4 __attribute__((ext_vector_type(4)));

// ---------------------------------------------------------------------------
// async global->LDS, 16 B per lane (global_load_lds_dwordx4).
// LDS dest = wave-uniform base + lane*16 (fixed); global side is a per-lane
// gather -> swizzles go into the GLOBAL address, LDS stays lane-contiguous.
// ---------------------------------------------------------------------------
__device__ __forceinline__ void async_load16(void* lptr, const void* gptr) {
  __builtin_amdgcn_global_load_lds(
      (const __attribute__((address_space(1))) unsigned int*)gptr,
      (__attribute__((address_space(3))) unsigned int*)lptr, 16, 0, 0);
}

// ---------------------------------------------------------------------------
// 256x256 8-phase MFMA NT GEMM (f16 in): C[m,n] = sum_k A[m,k]B[n,k]
// m201-style template: BK=64, 8 waves (2M x 4N), 128 KiB double-buffered LDS,
// counted vmcnt (never 0 in main loop), per-phase barriers + setprio around
// the MFMA cluster, XOR chunk swizzle via pre-swizzled GLOBAL gather address.
// EPI=0: fp32 store. EPI=1: fused RoPE(interleaved)+scale+f16 store (q path;
// scale includes log2(e) -- flash uses exp2).
// ---------------------------------------------------------------------------
template <int EPI>
__global__ __launch_bounds__(512, 2) void mla_gemm_256(
    const f16* __restrict__ A, const f16* __restrict__ B,
    void* __restrict__ Cv, int M, int N, int K,
    const float* __restrict__ cosb, const float* __restrict__ sinb) {
  // [buf][0=A,1=B][256 rows][64 f16]; row r chunk ch (16B units) stored at
  // ch' = ch ^ (r&7)  (pre-swizzled on the global side).
  __shared__ __align__(16) f16 smem[2][2][256 * 64];

  const int tid = threadIdx.x;       // 0..511
  const int lane = tid & 63;
  const int w = tid >> 6;            // 0..7
  const int lnm = lane & 15, quad = lane >> 4;
  const int wm = w >> 2, wn = w & 3; // 2 x 4 wave grid; wave tile 128x64

  // Bijective XCD-aware block swizzle (m204 variant).
  const int nwg = gridDim.x;
  const int bid0 = blockIdx.x;
  const int q8 = nwg >> 3, r8 = nwg & 7;
  const int xcd = bid0 & 7, lid = bid0 >> 3;
  const int wg =
      (xcd < r8 ? xcd * (q8 + 1) : r8 * (q8 + 1) + (xcd - r8) * q8) + lid;
  const int ntc = N >> 8;
  const int m0 = (wg / ntc) * 256;
  const int n0 = (wg % ntc) * 256;

  // Staging geometry: issue j covers LDS slot idx=j*512+tid -> local row
  // r = j*64 + (tid>>3), stored chunk ch' = tid&7; global chunk
  // ch = ch' ^ (r&7) = (tid&7) ^ ((tid>>3)&7)  (j*64 is 0 mod 8).
  const int srow = tid >> 3;
  const int sch = (tid & 7) ^ ((tid >> 3) & 7);
  const f16* Ag = A + (size_t)(m0 + srow) * K + sch * 8;
  const f16* Bg = B + (size_t)(n0 + srow) * K + sch * 8;

  // half h: 0=A-lo 1=A-hi 2=B-lo 3=B-hi; each = 2 global_load_lds / thread
  auto stage = [&](int bi, int k0, int h) {
    const int mat = h >> 1;
    const int rb = (h & 1) * 128;
    const f16* g = (mat ? Bg : Ag) + (size_t)rb * K + k0;
    f16* l = &smem[bi][mat][rb * 64 + tid * 8];
    async_load16(l, g);
    async_load16(l + 4096, g + (size_t)64 * K);
  };

  const int rx8 = lnm & 7;  // (row & 7) for all fragment rows below
  auto rdA = [&](const f16* Ab, int i, int ks) -> f16x8 {
    return *(const f16x8*)&Ab[(wm * 128 + i * 16 + lnm) * 64 +
                              (((ks * 4 + quad) ^ rx8) * 8)];
  };
  auto rdB = [&](const f16* Bb, int j, int ks) -> f16x8 {
    return *(const f16x8*)&Bb[(wn * 64 + j * 16 + lnm) * 64 +
                              (((ks * 4 + quad) ^ rx8) * 8)];
  };

  f32x4 acc[8][4] = {};

  const int NT = K >> 6;

  // Prologue: tile0 fully + tile1 A-lo (the (t-1).4-equivalent stage).
  stage(0, 0, 0);
  stage(0, 0, 1);
  stage(0, 0, 2);
  stage(0, 0, 3);
  stage(1, 64, 0);
  asm volatile("s_waitcnt vmcnt(2)" ::: "memory");  // tile0 landed
  __builtin_amdgcn_s_barrier();

  for (int t = 0; t < NT; ++t) {
    const int bi = t & 1;
    const f16* Ab = smem[bi][0];
    const f16* Bb = smem[bi][1];
    // Clamped k-offsets for tail staging (writes valid-but-dead data into a
    // buffer region that is never read again; keeps vmcnt counts uniform).
    const int k1 = (t + 1 < NT ? t + 1 : t) << 6;
    const int k2 = (t + 2 < NT ? t + 2 : t) << 6;

    f16x8 Ar[4][2], Br[2][2];

    // -------- phase 1: quadrant (mq0, nq0) -- 12 ds_reads --------
#pragma unroll
    for (int i = 0; i < 4; i++)
#pragma unroll
      for (int ks = 0; ks < 2; ks++) Ar[i][ks] = rdA(Ab, i, ks);
#pragma unroll
    for (int j = 0; j < 2; j++)
#pragma unroll
      for (int ks = 0; ks < 2; ks++) Br[j][ks] = rdB(Bb, j, ks);
    stage(bi ^ 1, k1, 1);
    __builtin_amdgcn_s_barrier();
    asm volatile("s_waitcnt lgkmcnt(0)" ::: "memory");
    __builtin_amdgcn_s_setprio(1);
#pragma unroll
    for (int i = 0; i < 4; i++)
#pragma unroll
      for (int j = 0; j < 2; j++)
#pragma unroll
        for (int ks = 0; ks < 2; ks++)
          acc[i][j] = __builtin_amdgcn_mfma_f32_16x16x32_f16(
              Ar[i][ks], Br[j][ks], acc[i][j], 0, 0, 0);
    __builtin_amdgcn_s_setprio(0);
    __builtin_amdgcn_s_barrier();

    // -------- phase 2: quadrant (mq0, nq1) -- 4 ds_reads --------
#pragma unroll
    for (int j = 0; j < 2; j++)
#pragma unroll
      for (int ks = 0; ks < 2; ks++) Br[j][ks] = rdB(Bb, 2 + j, ks);
    stage(bi ^ 1, k1, 2);
    __builtin_amdgcn_s_barrier();
    asm volatile("s_waitcnt lgkmcnt(0)" ::: "memory");
    __builtin_amdgcn_s_setprio(1);
#pragma unroll
    for (int i = 0; i < 4; i++)
#pragma unroll
      for (int j = 0; j < 2; j++)
#pragma unroll
        for (int ks = 0; ks < 2; ks++)
          acc[i][2 + j] = __builtin_amdgcn_mfma_f32_16x16x32_f16(
              Ar[i][ks], Br[j][ks], acc[i][2 + j], 0, 0, 0);
    __builtin_amdgcn_s_setprio(0);
    __builtin_amdgcn_s_barrier();

    // -------- phase 3: quadrant (mq1, nq1) -- 8 ds_reads --------
#pragma unroll
    for (int i = 0; i < 4; i++)
#pragma unroll
      for (int ks = 0; ks < 2; ks++) Ar[i][ks] = rdA(Ab, 4 + i, ks);
    stage(bi ^ 1, k1, 3);
    __builtin_amdgcn_s_barrier();
    asm volatile("s_waitcnt lgkmcnt(0)" ::: "memory");
    __builtin_amdgcn_s_setprio(1);
#pragma unroll
    for (int i = 0; i < 4; i++)
#pragma unroll
      for (int j = 0; j < 2; j++)
#pragma unroll
        for (int ks = 0; ks < 2; ks++)
          acc[4 + i][2 + j] = __builtin_amdgcn_mfma_f32_16x16x32_f16(
              Ar[i][ks], Br[j][ks], acc[4 + i][2 + j], 0, 0, 0);
    __builtin_amdgcn_s_setprio(0);
    __builtin_amdgcn_s_barrier();

    // -------- phase 4: quadrant (mq1, nq0) -- 4 ds_reads (B re-read) ------
    // Stage targets buf[bi] A-lo; this phase only reads buf[bi] B region.
#pragma unroll
    for (int j = 0; j < 2; j++)
#pragma unroll
      for (int ks = 0; ks < 2; ks++) Br[j][ks] = rdB(Bb, j, ks);
    stage(bi, k2, 0);
    __builtin_amdgcn_s_barrier();
    asm volatile("s_waitcnt lgkmcnt(0)" ::: "memory");
    __builtin_amdgcn_s_setprio(1);
#pragma unroll
    for (int i = 0; i < 4; i++)
#pragma unroll
      for (int j = 0; j < 2; j++)
#pragma unroll
        for (int ks = 0; ks < 2; ks++)
          acc[4 + i][j] = __builtin_amdgcn_mfma_f32_16x16x32_f16(
              Ar[i][ks], Br[j][ks], acc[4 + i][j], 0, 0, 0);
    __builtin_amdgcn_s_setprio(0);
    // Counted wait: allow only this phase's 2 loads outstanding -> tile t+1
    // (h0 from (t-1).4, h1..h3 from t.1-3) is fully landed after barrier.
    asm volatile("s_waitcnt vmcnt(2)" ::: "memory");
    __builtin_amdgcn_s_barrier();
  }

  // Drain remaining DMA before LDS teardown / epilogue.
  asm volatile("s_waitcnt vmcnt(0)" ::: "memory");

  if constexpr (EPI == 0) {
    float* C = (float*)Cv;
#pragma unroll
    for (int i = 0; i < 8; i++)
#pragma unroll
      for (int r = 0; r < 4; r++) {
        float* crow = C + (size_t)(m0 + wm * 128 + i * 16 + quad * 4 + r) * N +
                      n0 + wn * 64 + lnm;
#pragma unroll
        for (int j = 0; j < 4; j++) crow[j * 16] = acc[i][j][r];
      }
  } else {
    // Fused RoPE + scale + f16 store. Pair (2i,2i+1) along cols: partner
    // value lives on the lnm^1 lane -> shfl_xor(.,1).
    // SCLQ = (1/sqrt(D)) * log2(e): flash computes exp2 instead of exp.
    f16* C = (f16*)Cv;
    const float SCLQ = 0.1275174280f;
#pragma unroll
    for (int i = 0; i < 8; i++)
#pragma unroll
      for (int r = 0; r < 4; r++) {
        const int m = m0 + wm * 128 + i * 16 + quad * 4 + r;
        const int t = m & (TT - 1);
#pragma unroll
        for (int j = 0; j < 4; j++) {
          const int col = n0 + wn * 64 + j * 16 + lnm;
          float v = acc[i][j][r];
          float u = __shfl_xor(v, 1, 64);
          const int fi = (col & (DD - 1)) >> 1;
          const float ct = cosb[t * (DD / 2) + fi];
          const float st2 = sinb[t * (DD / 2) + fi];
          const float o =
              (lnm & 1) ? (u * st2 + v * ct) : (v * ct - u * st2);
          C[(size_t)m * N + col] = (f16)(o * SCLQ);
        }
      }
  }
}

// ---------------------------------------------------------------------------
// MFMA NT GEMM (f16 in, fp32 out): C[m,n] = sum_k A[m*K+k] * B[n*K+k]
// 128x128 tile, BK=32 (m97 recipe). Kept for N<2048 shapes (kv/up-projs).
// ---------------------------------------------------------------------------
__global__ __launch_bounds__(256) void mla_gemm_mfma(
    const f16* __restrict__ A, const f16* __restrict__ B,
    float* __restrict__ C, int M, int N, int K) {
  __shared__ f16 As[128 * 32];
  __shared__ f16 Bs[128 * 32];

  const int tid = threadIdx.x;
  const int lane = tid & 63;
  const int w = tid >> 6;
  const int lnm = lane & 15, quad = lane >> 4;
  const int wm = w >> 1, wn = w & 1;
  const int m0 = blockIdx.y * 128;
  const int n0 = blockIdx.x * 128;

  const int srow = tid >> 2;
  const int skoff = (tid & 3) * 8;

  f32x4 acc[4][4] = {};

  for (int k0 = 0; k0 < K; k0 += 32) {
    const f16* ag = A + (size_t)(m0 + srow) * K + k0 + skoff;
    const f16* bg = B + (size_t)(n0 + srow) * K + k0 + skoff;
    async_load16(&As[(size_t)tid * 8], ag);
    async_load16(&As[(size_t)(256 + tid) * 8], ag + (size_t)64 * K);
    async_load16(&Bs[(size_t)tid * 8], bg);
    async_load16(&Bs[(size_t)(256 + tid) * 8], bg + (size_t)64 * K);
    __syncthreads();

    f16x8 af[4], bf[4];
#pragma unroll
    for (int i = 0; i < 4; i++)
      af[i] = *(const f16x8*)&As[(wm * 64 + i * 16 + lnm) * 32 + quad * 8];
#pragma unroll
    for (int j = 0; j < 4; j++)
      bf[j] = *(const f16x8*)&Bs[(wn * 64 + j * 16 + lnm) * 32 + quad * 8];
#pragma unroll
    for (int i = 0; i < 4; i++)
#pragma unroll
      for (int j = 0; j < 4; j++)
        acc[i][j] = __builtin_amdgcn_mfma_f32_16x16x32_f16(af[i], bf[j],
                                                           acc[i][j], 0, 0, 0);
    __syncthreads();
  }

#pragma unroll
  for (int i = 0; i < 4; i++)
#pragma unroll
    for (int r = 0; r < 4; r++) {
      float* crow = C + (size_t)(m0 + wm * 64 + i * 16 + quad * 4 + r) * N +
                    n0 + wn * 64 + lnm;
#pragma unroll
      for (int j = 0; j < 4; j++) crow[j * 16] = acc[i][j][r];
    }
}

// ---------------------------------------------------------------------------
// fp32 -> f16 convert (vectorized, n % 4 == 0)
// ---------------------------------------------------------------------------
__global__ __launch_bounds__(256) void mla_cvt_f16(
    const float4* __restrict__ in, f16* __restrict__ out, int n4) {
  int i = blockIdx.x * 256 + threadIdx.x;
  if (i >= n4) return;
  float4 v = in[i];
  f16x4 r = {(f16)v.x, (f16)v.y, (f16)v.z, (f16)v.w};
  *(f16x4*)(out + (size_t)i * 4) = r;
}

// ---------------------------------------------------------------------------
// Fused RoPE (interleaved pairs) + scale + fp32 -> f16 conversion (k path).
// ---------------------------------------------------------------------------
__global__ __launch_bounds__(256) void mla_rope_cvt(
    const float2* __restrict__ x, f16* __restrict__ o,
    const float* __restrict__ cosb, const float* __restrict__ sinb,
    int Hh, float scale, int total) {
  int idx = blockIdx.x * blockDim.x + threadIdx.x;
  if (idx >= total) return;
  const int Dh = DD / 2;
  int i = idx % Dh;
  int t = (idx / (Dh * Hh)) % TT;
  float c = cosb[t * Dh + i];
  float s = sinb[t * Dh + i];
  float2 v = x[idx];
  f16x2 r;
  r.x = (f16)((v.x * c - v.y * s) * scale);
  r.y = (f16)((v.x * s + v.y * c) * scale);
  *(f16x2*)(o + (size_t)idx * 2) = r;
}

// ---------------------------------------------------------------------------
// v fp32 [B,T,D] -> vt f16 [B,D,T]
// ---------------------------------------------------------------------------
__global__ __launch_bounds__(256) void mla_transpose_v(
    const float* __restrict__ v, f16* __restrict__ vt) {
  __shared__ float tl[32][33];
  const int b = blockIdx.z;
  const int t0 = blockIdx.x * 32;
  const int d0 = blockIdx.y * 32;
  const int tx = threadIdx.x & 31;
  const int ty = threadIdx.x >> 5;
#pragma unroll
  for (int k = 0; k < 4; k++)
    tl[ty + 8 * k][tx] = v[((size_t)(b * TT + t0 + ty + 8 * k)) * DD + d0 + tx];
  __syncthreads();
#pragma unroll
  for (int k = 0; k < 4; k++)
    vt[((size_t)(b * DD + d0 + ty + 8 * k)) * TT + t0 + tx] =
        (f16)tl[tx][ty + 8 * k];
}

// ---------------------------------------------------------------------------
// Block-cooperative MFMA flash attention v4.
// Changes vs v3: 512-thread blocks (8 waves x 32 q-rows = 256-row q-tile)
// sharing ONE double-buffered K/V LDS pair -> 16 waves/CU (2 blocks x 8)
// instead of 8: one wave's softmax VALU overlaps another's MFMA. Staging
// per thread halves; K/V FETCH per q-row halves. Softmax uses exp2 via
// __builtin_amdgcn_exp2f (v_exp_f32 computes 2^x natively; log2e folded
// into q scale by the q-GEMM epilogue) and a wave-uniform masked/unmasked
// branch split (non-diagonal tiles skip 32 cmp+cndmask).
// ---------------------------------------------------------------------------
__global__ __launch_bounds__(512, 2) void mla_flash2(
    const f16* __restrict__ qh, const f16* __restrict__ kh,
    const f16* __restrict__ vth, f16* __restrict__ y) {
  __shared__ f16 Ks[2][64 * 128];  // (s, ch16B): stored at ch' = ch ^ (s&15)
  __shared__ f16 Vs[2][128 * 64];  // (d, ch8f16): stored at ch' = ch ^ (d&7)

  const int tid = threadIdx.x;
  const int lane = tid & 63;
  const int w = tid >> 6;  // 0..7
  const int lnm = lane & 15, quad = lane >> 4;

  const int bid = blockIdx.x;
  const int qt = (TT / 256 - 1) - (bid >> 6);  // LPT: longest q-tiles first
  const int bh = bid & 63;
  const int b = bh >> 4, h = bh & 15;
  const int q0b = qt * 256;
  const int q0 = q0b + w * 32;  // this wave's 32 q-rows

  // Q B-frags (global, once per block)
  f16x8 qf[2][4];
#pragma unroll
  for (int qnb = 0; qnb < 2; qnb++) {
    const f16* qrow =
        qh + ((size_t)(b * TT + q0 + qnb * 16 + lnm) * HH + h) * DD;
#pragma unroll
    for (int c = 0; c < 4; c++)
      qf[qnb][c] = *(const f16x8*)(qrow + c * 32 + quad * 8);
  }

  f32x4 O[2][8] = {};
  float l_acc[2] = {0.f, 0.f};

  const int nst = (q0b + 256) / 64;  // 4*qt + 4
  const int wmax = q0 + 31;
  const f16* kbase = kh + (size_t)b * TT * DD;
  const f16* vbase = vth + (size_t)b * DD * TT;

  // Staging (512 threads, 2 issues each for K and V):
  // K slot = i*512+tid -> s = i*32+(tid>>4), stored ch' = tid&15,
  //   global ch = (tid&15) ^ ((tid>>4)&15).
  // V slot = i*512+tid -> d = i*64+(tid>>3), stored ch' = tid&7,
  //   global ch = (tid&7) ^ ((tid>>3)&7).
  const int ks_row = tid >> 4;
  const int ks_col = ((tid & 15) ^ ((tid >> 4) & 15)) * 8;
  const int vs_row = tid >> 3;
  const int vs_col = ((tid & 7) ^ ((tid >> 3) & 7)) * 8;

  auto stage = [&](int buf, int st) {
    const int s0 = st * 64;
#pragma unroll
    for (int i = 0; i < 2; i++)
      async_load16(&Ks[buf][(size_t)(i * 512 + tid) * 8],
                   kbase + (size_t)(s0 + i * 32 + ks_row) * DD + ks_col);
#pragma unroll
    for (int i = 0; i < 2; i++)
      async_load16(&Vs[buf][(size_t)(i * 512 + tid) * 8],
                   vbase + (size_t)(i * 64 + vs_row) * TT + s0 + vs_col);
  };

  stage(0, 0);
  __syncthreads();  // drains vmcnt(0): tile 0 landed

  for (int st = 0; st < nst; st++) {
    const int cur = st & 1;
    const int s0 = st * 64;
    // Issue next tile's DMA first; its latency hides under this tile's
    // compute, so the end-of-tile drain is cheap.
    if (st + 1 < nst) stage(cur ^ 1, st + 1);

    if (s0 <= wmax) {  // wave-uniform: skip fully-masked tiles
      const f16* Kc = Ks[cur];
      const f16* Vc = Vs[cur];

      // QK: S^T = K . Q^T
      f32x4 S[2][4] = {};
      __builtin_amdgcn_s_setprio(1);
#pragma unroll
      for (int sb = 0; sb < 4; sb++) {
        const int sl = sb * 16 + lnm;
#pragma unroll
        for (int c = 0; c < 4; c++) {
          f16x8 ka =
              *(const f16x8*)&Kc[sl * 128 + ((c * 4 + quad) ^ lnm) * 8];
          S[0][sb] = __builtin_amdgcn_mfma_f32_16x16x32_f16(ka, qf[0][c],
                                                            S[0][sb], 0, 0, 0);
          S[1][sb] = __builtin_amdgcn_mfma_f32_16x16x32_f16(ka, qf[1][c],
                                                            S[1][sb], 0, 0, 0);
        }
      }
      __builtin_amdgcn_s_setprio(0);

      // P = exp2(S) (+ causal mask on diagonal tiles), packed as K=32
      // A-frags: P8[qnb][c][e]: e<4 -> s=c*32+quad*4+e (sb=2c),
      //                         e>=4 -> s=c*32+16+quad*4+(e-4) (sb=2c+1).
      f16x8 P8[2][2];
      const bool domask = (s0 + 63 > q0);  // wave-uniform
      if (!domask) {
#pragma unroll
        for (int qnb = 0; qnb < 2; qnb++) {
          float lp = 0.f;
#pragma unroll
          for (int sb = 0; sb < 4; sb++)
#pragma unroll
            for (int j = 0; j < 4; j++) {
              float p = __builtin_amdgcn_exp2f(S[qnb][sb][j]);
              lp += p;
              P8[qnb][sb >> 1][(sb & 1) * 4 + j] = (f16)p;
            }
          l_acc[qnb] += lp;
        }
      } else {
#pragma unroll
        for (int qnb = 0; qnb < 2; qnb++) {
          const int m_abs = q0 + qnb * 16 + lnm;
          float lp = 0.f;
#pragma unroll
          for (int sb = 0; sb < 4; sb++) {
            const int srow = s0 + sb * 16 + quad * 4;
#pragma unroll
            for (int j = 0; j < 4; j++) {
              float p = __builtin_amdgcn_exp2f(S[qnb][sb][j]);
              if (srow + j > m_abs) p = 0.f;
              lp += p;
              P8[qnb][sb >> 1][(sb & 1) * 4 + j] = (f16)p;
            }
          }
          l_acc[qnb] += lp;
        }
      }

      // PV at K=32: V frag uses the SAME k->s permutation as P8.
      __builtin_amdgcn_s_setprio(1);
#pragma unroll
      for (int c = 0; c < 2; c++) {
        const int chlo = c * 4 + (quad >> 1);
        const int soff = (quad & 1) * 4;
#pragma unroll
        for (int db = 0; db < 8; db++) {
          const int d = db * 16 + lnm;
          const f16* vrow = &Vc[d * 64];
          f16x4 vlo = *(const f16x4*)&vrow[((chlo ^ (d & 7)) * 8) + soff];
          f16x4 vhi =
              *(const f16x4*)&vrow[(((chlo + 2) ^ (d & 7)) * 8) + soff];
          f16x8 vb;
#pragma unroll
          for (int j = 0; j < 4; j++) {
            vb[j] = vlo[j];
            vb[4 + j] = vhi[j];
          }
          O[0][db] = __builtin_amdgcn_mfma_f32_16x16x32_f16(P8[0][c], vb,
                                                            O[0][db], 0, 0, 0);
          O[1][db] = __builtin_amdgcn_mfma_f32_16x16x32_f16(P8[1][c], vb,
                                                            O[1][db], 0, 0, 0);
        }
      }
      __builtin_amdgcn_s_setprio(0);
    }
    __syncthreads();  // drains next-tile DMA (already landed) + buffer swap
  }

  // Row-sums across quads
#pragma unroll
  for (int qnb = 0; qnb < 2; qnb++) {
    float l = l_acc[qnb];
    l += __shfl_xor(l, 16, 64);
    l += __shfl_xor(l, 32, 64);
    l_acc[qnb] = l;
  }

  // Epilogue: y = O / l (f16)
#pragma unroll
  for (int qnb = 0; qnb < 2; qnb++) {
    float linv[4];
#pragma unroll
    for (int r = 0; r < 4; r++)
      linv[r] = 1.f / __shfl(l_acc[qnb], quad * 4 + r, 64);
#pragma unroll
    for (int db = 0; db < 8; db++)
#pragma unroll
      for (int r = 0; r < 4; r++) {
        size_t off =
            ((size_t)(b * TT + q0 + qnb * 16 + quad * 4 + r) * HH + h) * DD +
            db * 16 + lnm;
        y[off] = (f16)(O[qnb][db][r] * linv[r]);
      }
  }
}

// ---------------------------------------------------------------------------
extern "C" void kernel_launch(void* const* d_in, const int* in_sizes, int n_in,
                              void* d_out, int out_size, void* d_ws,
                              size_t ws_size, hipStream_t stream) {
  const float* x      = (const float*)d_in[0];
  const float* fcos   = (const float*)d_in[1];
  const float* fsin   = (const float*)d_in[2];
  const float* wq     = (const float*)d_in[3];
  const float* wkv_dn = (const float*)d_in[4];
  const float* wk_up  = (const float*)d_in[5];
  const float* wv_up  = (const float*)d_in[6];
  const float* wo     = (const float*)d_in[7];
  float* out = (float*)d_out;

  const int M = BB * TT;  // 8192

  // Workspace layout. q-GEMM writes qh (f16, roped) directly, so the old
  // fp32 q buffer is repurposed: [qh | yh] (each M*CC f16 = 32 MB).
  float* ws = (float*)d_ws;
  float* qbuf   = ws;                              // 64 MB slot: qh + yh
  float* kv     = qbuf + (size_t)M * CC;           // 4.2M f32 (16 MB)
  float* kk     = kv + (size_t)M * LL;             // 1M f32 (4 MB)
  float* vv     = kk + (size_t)M * DD;             // 1M f32 (4 MB)
  f16*   xh     = (f16*)(vv + (size_t)M * DD);     // 16.7M f16 (32 MB)
  f16*   wqh    = xh + (size_t)M * CC;             // 4.2M f16 (8 MB)
  f16*   wdownh = wqh + (size_t)CC * CC;           // 1M f16 (2 MB)
  f16*   wkuph  = wdownh + (size_t)LL * CC;        // 64K f16
  f16*   wvuph  = wkuph + (size_t)DD * LL;         // 64K f16
  f16*   woh    = wvuph + (size_t)DD * LL;         // 4.2M f16 (8 MB)
  f16*   kvh    = woh + (size_t)CC * CC;           // 4.2M f16 (8 MB)
  f16*   khb    = kvh + (size_t)M * LL;            // 1M f16 (2 MB)
  f16*   vth    = khb + (size_t)M * DD;            // 1M f16 (2 MB)
  f16*   qh     = (f16*)qbuf;                      // 32 MB
  f16*   yh     = qh + (size_t)M * CC;             // 32 MB

  dim3 blk(256);

  // fp32 -> f16 conversions
  mla_cvt_f16<<<(M * CC / 4 + 255) / 256, blk, 0, stream>>>(
      (const float4*)x, xh, M * CC / 4);
  mla_cvt_f16<<<(CC * CC / 4 + 255) / 256, blk, 0, stream>>>(
      (const float4*)wq, wqh, CC * CC / 4);
  mla_cvt_f16<<<(LL * CC / 4 + 255) / 256, blk, 0, stream>>>(
      (const float4*)wkv_dn, wdownh, LL * CC / 4);
  mla_cvt_f16<<<(DD * LL / 4 + 255) / 256, blk, 0, stream>>>(
      (const float4*)wk_up, wkuph, DD * LL / 4);
  mla_cvt_f16<<<(DD * LL / 4 + 255) / 256, blk, 0, stream>>>(
      (const float4*)wv_up, wvuph, DD * LL / 4);
  mla_cvt_f16<<<(CC * CC / 4 + 255) / 256, blk, 0, stream>>>(
      (const float4*)wo, woh, CC * CC / 4);

  // q = rope(x @ wq^T) (8-phase 256^2, fused epilogue -> f16 qh, exp2 scale)
  mla_gemm_256<1><<<dim3((M / 256) * (CC / 256)), dim3(512), 0, stream>>>(
      xh, wqh, qh, M, CC, CC, fcos, fsin);
  // kv = x @ wdown^T (128^2: N=512 -> 256 wgs)
  mla_gemm_mfma<<<dim3(LL / 128, M / 128), blk, 0, stream>>>(
      xh, wdownh, kv, M, LL, CC);

  // kv -> f16, then k/v up-projections
  mla_cvt_f16<<<(M * LL / 4 + 255) / 256, blk, 0, stream>>>(
      (const float4*)kv, kvh, M * LL / 4);
  mla_gemm_mfma<<<dim3(DD / 128, M / 128), blk, 0, stream>>>(
      kvh, wkuph, kk, M, DD, LL);
  mla_gemm_mfma<<<dim3(DD / 128, M / 128), blk, 0, stream>>>(
      kvh, wvuph, vv, M, DD, LL);

  // k RoPE + f16 conversion
  {
    int total_k = BB * TT * (DD / 2);
    mla_rope_cvt<<<(total_k + 255) / 256, blk, 0, stream>>>(
        (const float2*)kk, khb, fcos, fsin, 1, 1.0f, total_k);
  }

  // v -> vt (transposed f16)
  mla_transpose_v<<<dim3(TT / 32, DD / 32, BB), blk, 0, stream>>>(vv, vth);

  // Flash attention v4 -> yh (f16). 512 blocks x 512 threads, LPT order.
  mla_flash2<<<dim3(BB * HH * (TT / 256)), dim3(512), 0, stream>>>(
      qh, khb, vth, yh);

  // out = y @ wo^T (8-phase 256^2)
  mla_gemm_256<0><<<dim3((M / 256) * (CC / 256)), dim3(512), 0, stream>>>(
      yh, woh, out, M, CC, CC, nullptr, nullptr);
}

// Round 6
// 455.305 us; speedup vs baseline: 1.2651x; 1.0233x over previous
//
#include <hip/hip_runtime.h>
#include <hip/hip_bf16.h>
#include <cstddef>

// Problem constants
#define BB 4
#define TT 2048
#define CC 2048
#define HH 16
#define DD 128
#define LL 512

typedef _Float16 f16;
typedef f16 f16x2 __attribute__((ext_vector_type(2)));
typedef f16 f16x4 __attribute__((ext_vector_type(4)));
typedef f16 f16x8 __attribute__((ext_vector_type(8)));
typedef float f32x4 __attribute__((ext_vector_type(4)));

// ---------------------------------------------------------------------------
// async global->LDS, 16 B per lane (global_load_lds_dwordx4).
// LDS dest = wave-uniform base + lane*16 (fixed); global side is a per-lane
// gather -> swizzles go into the GLOBAL address, LDS stays lane-contiguous.
// ---------------------------------------------------------------------------
__device__ __forceinline__ void async_load16(void* lptr, const void* gptr) {
  __builtin_amdgcn_global_load_lds(
      (const __attribute__((address_space(1))) unsigned int*)gptr,
      (__attribute__((address_space(3))) unsigned int*)lptr, 16, 0, 0);
}

// ---------------------------------------------------------------------------
// 256x256 8-phase MFMA NT GEMM (f16 in): C[m,n] = sum_k A[m,k]B[n,k]
// m201-style template: BK=64, 8 waves (2M x 4N), 128 KiB double-buffered LDS,
// counted vmcnt (never 0 in main loop), per-phase barriers + setprio around
// the MFMA cluster, XOR chunk swizzle via pre-swizzled GLOBAL gather address.
// EPI=0: fp32 store. EPI=1: fused RoPE(interleaved)+scale+f16 store (q path;
// scale includes log2(e) -- flash uses exp2).
// ---------------------------------------------------------------------------
template <int EPI>
__global__ __launch_bounds__(512, 2) void mla_gemm_256(
    const f16* __restrict__ A, const f16* __restrict__ B,
    void* __restrict__ Cv, int M, int N, int K,
    const float* __restrict__ cosb, const float* __restrict__ sinb) {
  // [buf][0=A,1=B][256 rows][64 f16]; row r chunk ch (16B units) stored at
  // ch' = ch ^ (r&7)  (pre-swizzled on the global side).
  __shared__ __align__(16) f16 smem[2][2][256 * 64];

  const int tid = threadIdx.x;       // 0..511
  const int lane = tid & 63;
  const int w = tid >> 6;            // 0..7
  const int lnm = lane & 15, quad = lane >> 4;
  const int wm = w >> 2, wn = w & 3; // 2 x 4 wave grid; wave tile 128x64

  // Bijective XCD-aware block swizzle (m204 variant).
  const int nwg = gridDim.x;
  const int bid0 = blockIdx.x;
  const int q8 = nwg >> 3, r8 = nwg & 7;
  const int xcd = bid0 & 7, lid = bid0 >> 3;
  const int wg =
      (xcd < r8 ? xcd * (q8 + 1) : r8 * (q8 + 1) + (xcd - r8) * q8) + lid;
  const int ntc = N >> 8;
  const int m0 = (wg / ntc) * 256;
  const int n0 = (wg % ntc) * 256;

  // Staging geometry: issue j covers LDS slot idx=j*512+tid -> local row
  // r = j*64 + (tid>>3), stored chunk ch' = tid&7; global chunk
  // ch = ch' ^ (r&7) = (tid&7) ^ ((tid>>3)&7)  (j*64 is 0 mod 8).
  const int srow = tid >> 3;
  const int sch = (tid & 7) ^ ((tid >> 3) & 7);
  const f16* Ag = A + (size_t)(m0 + srow) * K + sch * 8;
  const f16* Bg = B + (size_t)(n0 + srow) * K + sch * 8;

  // half h: 0=A-lo 1=A-hi 2=B-lo 3=B-hi; each = 2 global_load_lds / thread
  auto stage = [&](int bi, int k0, int h) {
    const int mat = h >> 1;
    const int rb = (h & 1) * 128;
    const f16* g = (mat ? Bg : Ag) + (size_t)rb * K + k0;
    f16* l = &smem[bi][mat][rb * 64 + tid * 8];
    async_load16(l, g);
    async_load16(l + 4096, g + (size_t)64 * K);
  };

  const int rx8 = lnm & 7;  // (row & 7) for all fragment rows below
  auto rdA = [&](const f16* Ab, int i, int ks) -> f16x8 {
    return *(const f16x8*)&Ab[(wm * 128 + i * 16 + lnm) * 64 +
                              (((ks * 4 + quad) ^ rx8) * 8)];
  };
  auto rdB = [&](const f16* Bb, int j, int ks) -> f16x8 {
    return *(const f16x8*)&Bb[(wn * 64 + j * 16 + lnm) * 64 +
                              (((ks * 4 + quad) ^ rx8) * 8)];
  };

  f32x4 acc[8][4] = {};

  const int NT = K >> 6;

  // Prologue: tile0 fully + tile1 A-lo (the (t-1).4-equivalent stage).
  stage(0, 0, 0);
  stage(0, 0, 1);
  stage(0, 0, 2);
  stage(0, 0, 3);
  stage(1, 64, 0);
  asm volatile("s_waitcnt vmcnt(2)" ::: "memory");  // tile0 landed
  __builtin_amdgcn_s_barrier();

  for (int t = 0; t < NT; ++t) {
    const int bi = t & 1;
    const f16* Ab = smem[bi][0];
    const f16* Bb = smem[bi][1];
    // Clamped k-offsets for tail staging (writes valid-but-dead data into a
    // buffer region that is never read again; keeps vmcnt counts uniform).
    const int k1 = (t + 1 < NT ? t + 1 : t) << 6;
    const int k2 = (t + 2 < NT ? t + 2 : t) << 6;

    f16x8 Ar[4][2], Br[2][2];

    // -------- phase 1: quadrant (mq0, nq0) -- 12 ds_reads --------
#pragma unroll
    for (int i = 0; i < 4; i++)
#pragma unroll
      for (int ks = 0; ks < 2; ks++) Ar[i][ks] = rdA(Ab, i, ks);
#pragma unroll
    for (int j = 0; j < 2; j++)
#pragma unroll
      for (int ks = 0; ks < 2; ks++) Br[j][ks] = rdB(Bb, j, ks);
    stage(bi ^ 1, k1, 1);
    __builtin_amdgcn_s_barrier();
    asm volatile("s_waitcnt lgkmcnt(0)" ::: "memory");
    __builtin_amdgcn_s_setprio(1);
#pragma unroll
    for (int i = 0; i < 4; i++)
#pragma unroll
      for (int j = 0; j < 2; j++)
#pragma unroll
        for (int ks = 0; ks < 2; ks++)
          acc[i][j] = __builtin_amdgcn_mfma_f32_16x16x32_f16(
              Ar[i][ks], Br[j][ks], acc[i][j], 0, 0, 0);
    __builtin_amdgcn_s_setprio(0);
    __builtin_amdgcn_s_barrier();

    // -------- phase 2: quadrant (mq0, nq1) -- 4 ds_reads --------
#pragma unroll
    for (int j = 0; j < 2; j++)
#pragma unroll
      for (int ks = 0; ks < 2; ks++) Br[j][ks] = rdB(Bb, 2 + j, ks);
    stage(bi ^ 1, k1, 2);
    __builtin_amdgcn_s_barrier();
    asm volatile("s_waitcnt lgkmcnt(0)" ::: "memory");
    __builtin_amdgcn_s_setprio(1);
#pragma unroll
    for (int i = 0; i < 4; i++)
#pragma unroll
      for (int j = 0; j < 2; j++)
#pragma unroll
        for (int ks = 0; ks < 2; ks++)
          acc[i][2 + j] = __builtin_amdgcn_mfma_f32_16x16x32_f16(
              Ar[i][ks], Br[j][ks], acc[i][2 + j], 0, 0, 0);
    __builtin_amdgcn_s_setprio(0);
    __builtin_amdgcn_s_barrier();

    // -------- phase 3: quadrant (mq1, nq1) -- 8 ds_reads --------
#pragma unroll
    for (int i = 0; i < 4; i++)
#pragma unroll
      for (int ks = 0; ks < 2; ks++) Ar[i][ks] = rdA(Ab, 4 + i, ks);
    stage(bi ^ 1, k1, 3);
    __builtin_amdgcn_s_barrier();
    asm volatile("s_waitcnt lgkmcnt(0)" ::: "memory");
    __builtin_amdgcn_s_setprio(1);
#pragma unroll
    for (int i = 0; i < 4; i++)
#pragma unroll
      for (int j = 0; j < 2; j++)
#pragma unroll
        for (int ks = 0; ks < 2; ks++)
          acc[4 + i][2 + j] = __builtin_amdgcn_mfma_f32_16x16x32_f16(
              Ar[i][ks], Br[j][ks], acc[4 + i][2 + j], 0, 0, 0);
    __builtin_amdgcn_s_setprio(0);
    __builtin_amdgcn_s_barrier();

    // -------- phase 4: quadrant (mq1, nq0) -- 4 ds_reads (B re-read) ------
    // Stage targets buf[bi] A-lo; this phase only reads buf[bi] B region.
#pragma unroll
    for (int j = 0; j < 2; j++)
#pragma unroll
      for (int ks = 0; ks < 2; ks++) Br[j][ks] = rdB(Bb, j, ks);
    stage(bi, k2, 0);
    __builtin_amdgcn_s_barrier();
    asm volatile("s_waitcnt lgkmcnt(0)" ::: "memory");
    __builtin_amdgcn_s_setprio(1);
#pragma unroll
    for (int i = 0; i < 4; i++)
#pragma unroll
      for (int j = 0; j < 2; j++)
#pragma unroll
        for (int ks = 0; ks < 2; ks++)
          acc[4 + i][j] = __builtin_amdgcn_mfma_f32_16x16x32_f16(
              Ar[i][ks], Br[j][ks], acc[4 + i][j], 0, 0, 0);
    __builtin_amdgcn_s_setprio(0);
    // Counted wait: allow only this phase's 2 loads outstanding -> tile t+1
    // (h0 from (t-1).4, h1..h3 from t.1-3) is fully landed after barrier.
    asm volatile("s_waitcnt vmcnt(2)" ::: "memory");
    __builtin_amdgcn_s_barrier();
  }

  // Drain remaining DMA before LDS teardown / epilogue.
  asm volatile("s_waitcnt vmcnt(0)" ::: "memory");

  if constexpr (EPI == 0) {
    float* C = (float*)Cv;
#pragma unroll
    for (int i = 0; i < 8; i++)
#pragma unroll
      for (int r = 0; r < 4; r++) {
        float* crow = C + (size_t)(m0 + wm * 128 + i * 16 + quad * 4 + r) * N +
                      n0 + wn * 64 + lnm;
#pragma unroll
        for (int j = 0; j < 4; j++) crow[j * 16] = acc[i][j][r];
      }
  } else {
    // Fused RoPE + scale + f16 store. Pair (2i,2i+1) along cols: partner
    // value lives on the lnm^1 lane -> shfl_xor(.,1).
    // SCLQ = (1/sqrt(D)) * log2(e): flash computes exp2 instead of exp.
    f16* C = (f16*)Cv;
    const float SCLQ = 0.1275174280f;
#pragma unroll
    for (int i = 0; i < 8; i++)
#pragma unroll
      for (int r = 0; r < 4; r++) {
        const int m = m0 + wm * 128 + i * 16 + quad * 4 + r;
        const int t = m & (TT - 1);
#pragma unroll
        for (int j = 0; j < 4; j++) {
          const int col = n0 + wn * 64 + j * 16 + lnm;
          float v = acc[i][j][r];
          float u = __shfl_xor(v, 1, 64);
          const int fi = (col & (DD - 1)) >> 1;
          const float ct = cosb[t * (DD / 2) + fi];
          const float st2 = sinb[t * (DD / 2) + fi];
          const float o =
              (lnm & 1) ? (u * st2 + v * ct) : (v * ct - u * st2);
          C[(size_t)m * N + col] = (f16)(o * SCLQ);
        }
      }
  }
}

// ---------------------------------------------------------------------------
// MFMA NT GEMM (f16 in, fp32 out): C[m,n] = sum_k A[m*K+k] * B[n*K+k]
// 128x128 tile, BK=32 (m97 recipe). Kept for N<2048 shapes (kv/up-projs).
// ---------------------------------------------------------------------------
__global__ __launch_bounds__(256) void mla_gemm_mfma(
    const f16* __restrict__ A, const f16* __restrict__ B,
    float* __restrict__ C, int M, int N, int K) {
  __shared__ f16 As[128 * 32];
  __shared__ f16 Bs[128 * 32];

  const int tid = threadIdx.x;
  const int lane = tid & 63;
  const int w = tid >> 6;
  const int lnm = lane & 15, quad = lane >> 4;
  const int wm = w >> 1, wn = w & 1;
  const int m0 = blockIdx.y * 128;
  const int n0 = blockIdx.x * 128;

  const int srow = tid >> 2;
  const int skoff = (tid & 3) * 8;

  f32x4 acc[4][4] = {};

  for (int k0 = 0; k0 < K; k0 += 32) {
    const f16* ag = A + (size_t)(m0 + srow) * K + k0 + skoff;
    const f16* bg = B + (size_t)(n0 + srow) * K + k0 + skoff;
    async_load16(&As[(size_t)tid * 8], ag);
    async_load16(&As[(size_t)(256 + tid) * 8], ag + (size_t)64 * K);
    async_load16(&Bs[(size_t)tid * 8], bg);
    async_load16(&Bs[(size_t)(256 + tid) * 8], bg + (size_t)64 * K);
    __syncthreads();

    f16x8 af[4], bf[4];
#pragma unroll
    for (int i = 0; i < 4; i++)
      af[i] = *(const f16x8*)&As[(wm * 64 + i * 16 + lnm) * 32 + quad * 8];
#pragma unroll
    for (int j = 0; j < 4; j++)
      bf[j] = *(const f16x8*)&Bs[(wn * 64 + j * 16 + lnm) * 32 + quad * 8];
#pragma unroll
    for (int i = 0; i < 4; i++)
#pragma unroll
      for (int j = 0; j < 4; j++)
        acc[i][j] = __builtin_amdgcn_mfma_f32_16x16x32_f16(af[i], bf[j],
                                                           acc[i][j], 0, 0, 0);
    __syncthreads();
  }

#pragma unroll
  for (int i = 0; i < 4; i++)
#pragma unroll
    for (int r = 0; r < 4; r++) {
      float* crow = C + (size_t)(m0 + wm * 64 + i * 16 + quad * 4 + r) * N +
                    n0 + wn * 64 + lnm;
#pragma unroll
      for (int j = 0; j < 4; j++) crow[j * 16] = acc[i][j][r];
    }
}

// ---------------------------------------------------------------------------
// fp32 -> f16 convert (vectorized, n % 4 == 0)
// ---------------------------------------------------------------------------
__global__ __launch_bounds__(256) void mla_cvt_f16(
    const float4* __restrict__ in, f16* __restrict__ out, int n4) {
  int i = blockIdx.x * 256 + threadIdx.x;
  if (i >= n4) return;
  float4 v = in[i];
  f16x4 r = {(f16)v.x, (f16)v.y, (f16)v.z, (f16)v.w};
  *(f16x4*)(out + (size_t)i * 4) = r;
}

// ---------------------------------------------------------------------------
// Fused RoPE (interleaved pairs) + scale + fp32 -> f16 conversion (k path).
// Input rows have stride ld2 float2 (k may live in a wider fused kv buffer).
// ---------------------------------------------------------------------------
__global__ __launch_bounds__(256) void mla_rope_cvt(
    const float2* __restrict__ x, f16* __restrict__ o,
    const float* __restrict__ cosb, const float* __restrict__ sinb,
    int ld2, float scale, int total) {
  int idx = blockIdx.x * blockDim.x + threadIdx.x;
  if (idx >= total) return;
  const int Dh = DD / 2;  // 64
  int i = idx & (Dh - 1);
  int m = idx >> 6;
  int t = m & (TT - 1);
  float c = cosb[t * Dh + i];
  float s = sinb[t * Dh + i];
  float2 v = x[(size_t)m * ld2 + i];
  f16x2 r;
  r.x = (f16)((v.x * c - v.y * s) * scale);
  r.y = (f16)((v.x * s + v.y * c) * scale);
  *(f16x2*)(o + (size_t)idx * 2) = r;
}

// ---------------------------------------------------------------------------
// v fp32 [B,T,*ldv] (v at given base) -> vt f16 [B,D,T]
// ---------------------------------------------------------------------------
__global__ __launch_bounds__(256) void mla_transpose_v(
    const float* __restrict__ v, f16* __restrict__ vt, int ldv) {
  __shared__ float tl[32][33];
  const int b = blockIdx.z;
  const int t0 = blockIdx.x * 32;
  const int d0 = blockIdx.y * 32;
  const int tx = threadIdx.x & 31;
  const int ty = threadIdx.x >> 5;
#pragma unroll
  for (int k = 0; k < 4; k++)
    tl[ty + 8 * k][tx] =
        v[((size_t)(b * TT + t0 + ty + 8 * k)) * ldv + d0 + tx];
  __syncthreads();
#pragma unroll
  for (int k = 0; k < 4; k++)
    vt[((size_t)(b * DD + d0 + ty + 8 * k)) * TT + t0 + tx] =
        (f16)tl[tx][ty + 8 * k];
}

// ---------------------------------------------------------------------------
// Block-cooperative MFMA flash attention v5: one-tile software pipeline.
// At 2 waves/SIMD (unified VGPR+AGPR >128/wave) cross-wave overlap is weak,
// so overlap is created WITHIN the wave: S(t) persists across the iteration;
// each iteration runs softmax(t) -> QK(t+1) -> PV(t). QK(t+1) is independent
// of softmax(t)/PV(t), so the scheduler interleaves 64 MFMAs with the
// softmax VALU chain instead of stalling phase-by-phase.
// Staging stagger: K staged 2 tiles ahead into Ks[t&1], V staged 1 ahead
// into Vs[(t&1)^1]; all buffer write/read pairs are disjoint per iteration
// and separated by the per-tile barrier (audited per-buffer).
// ---------------------------------------------------------------------------
__global__ __launch_bounds__(512, 2) void mla_flash2(
    const f16* __restrict__ qh, const f16* __restrict__ kh,
    const f16* __restrict__ vth, f16* __restrict__ y) {
  __shared__ f16 Ks[2][64 * 128];  // (s, ch16B): stored at ch' = ch ^ (s&15)
  __shared__ f16 Vs[2][128 * 64];  // (d, ch8f16): stored at ch' = ch ^ (d&7)

  const int tid = threadIdx.x;
  const int lane = tid & 63;
  const int w = tid >> 6;  // 0..7
  const int lnm = lane & 15, quad = lane >> 4;

  const int bid = blockIdx.x;
  const int qt = (TT / 256 - 1) - (bid >> 6);  // LPT: longest q-tiles first
  const int bh = bid & 63;
  const int b = bh >> 4, h = bh & 15;
  const int q0b = qt * 256;
  const int q0 = q0b + w * 32;  // this wave's 32 q-rows

  // Q B-frags (global, once per block)
  f16x8 qf[2][4];
#pragma unroll
  for (int qnb = 0; qnb < 2; qnb++) {
    const f16* qrow =
        qh + ((size_t)(b * TT + q0 + qnb * 16 + lnm) * HH + h) * DD;
#pragma unroll
    for (int c = 0; c < 4; c++)
      qf[qnb][c] = *(const f16x8*)(qrow + c * 32 + quad * 8);
  }

  f32x4 O[2][8] = {};
  f32x4 S[2][4];  // pipelined QK result (tile t+1 during iteration t)
  float l_acc[2] = {0.f, 0.f};

  const int nst = (q0b + 256) / 64;  // 4*qt + 4
  const int wmax = q0 + 31;
  const f16* kbase = kh + (size_t)b * TT * DD;
  const f16* vbase = vth + (size_t)b * DD * TT;

  const int ks_row = tid >> 4;
  const int ks_col = ((tid & 15) ^ ((tid >> 4) & 15)) * 8;
  const int vs_row = tid >> 3;
  const int vs_col = ((tid & 7) ^ ((tid >> 3) & 7)) * 8;

  auto stageK = [&](int buf, int st) {
    const int s0 = st * 64;
#pragma unroll
    for (int i = 0; i < 2; i++)
      async_load16(&Ks[buf][(size_t)(i * 512 + tid) * 8],
                   kbase + (size_t)(s0 + i * 32 + ks_row) * DD + ks_col);
  };
  auto stageV = [&](int buf, int st) {
    const int s0 = st * 64;
#pragma unroll
    for (int i = 0; i < 2; i++)
      async_load16(&Vs[buf][(size_t)(i * 512 + tid) * 8],
                   vbase + (size_t)(i * 64 + vs_row) * TT + s0 + vs_col);
  };

  auto qk = [&](const f16* Kc) {
    const f32x4 z = {0.f, 0.f, 0.f, 0.f};
#pragma unroll
    for (int qnb = 0; qnb < 2; qnb++)
#pragma unroll
      for (int sb = 0; sb < 4; sb++) S[qnb][sb] = z;
#pragma unroll
    for (int sb = 0; sb < 4; sb++) {
      const int sl = sb * 16 + lnm;
#pragma unroll
      for (int c = 0; c < 4; c++) {
        f16x8 ka = *(const f16x8*)&Kc[sl * 128 + ((c * 4 + quad) ^ lnm) * 8];
        S[0][sb] = __builtin_amdgcn_mfma_f32_16x16x32_f16(ka, qf[0][c],
                                                          S[0][sb], 0, 0, 0);
        S[1][sb] = __builtin_amdgcn_mfma_f32_16x16x32_f16(ka, qf[1][c],
                                                          S[1][sb], 0, 0, 0);
      }
    }
  };

  // Prologue: tile0 K+V; then K1 in flight; S = QK(0).
  stageK(0, 0);
  stageV(0, 0);
  __syncthreads();  // tile0 landed
  stageK(1, 1 < nst ? 1 : 0);
  qk(Ks[0]);
  __syncthreads();  // all waves done reading Ks[0]; K1 landed

  for (int st = 0; st < nst; st++) {
    const int cur = st & 1, nxt = cur ^ 1;
    const int s0c = st * 64;
    // K(t+2) -> Ks[cur] (last read QK(t), prev iter); V(t+1) -> Vs[nxt]
    // (last read PV(t-1), prev iter). Both separated by prev barrier.
    stageK(cur, st + 2 < nst ? st + 2 : nst - 1);
    stageV(nxt, st + 1 < nst ? st + 1 : nst - 1);

    const bool act = (s0c <= wmax);  // wave-uniform
    f16x8 P8[2][2];
    if (act) {
      // softmax(t): P8 = exp2(S) (+causal mask), row-sums. Consumes S ->
      // registers free for QK(t+1) below.
      const bool domask = (s0c + 63 > q0);
#pragma unroll
      for (int qnb = 0; qnb < 2; qnb++) {
        const int m_abs = q0 + qnb * 16 + lnm;
        float lp = 0.f;
#pragma unroll
        for (int sb = 0; sb < 4; sb++) {
          const int srow = s0c + sb * 16 + quad * 4;
          float p[4];
#pragma unroll
          for (int j = 0; j < 4; j++) {
            float e = __builtin_amdgcn_exp2f(S[qnb][sb][j]);
            if (domask && (srow + j > m_abs)) e = 0.f;
            p[j] = e;
            lp += e;
          }
          f16x2* pp = (f16x2*)&P8[qnb][sb >> 1];
#if __has_builtin(__builtin_amdgcn_cvt_pkrtz)
          {
            auto h0 = __builtin_amdgcn_cvt_pkrtz(p[0], p[1]);
            auto h1 = __builtin_amdgcn_cvt_pkrtz(p[2], p[3]);
            pp[(sb & 1) * 2 + 0] = *(const f16x2*)&h0;
            pp[(sb & 1) * 2 + 1] = *(const f16x2*)&h1;
          }
#else
          {
            f16x2 h0 = {(f16)p[0], (f16)p[1]};
            f16x2 h1 = {(f16)p[2], (f16)p[3]};
            pp[(sb & 1) * 2 + 0] = h0;
            pp[(sb & 1) * 2 + 1] = h1;
          }
#endif
        }
        l_acc[qnb] += lp;
      }
    }

    __builtin_amdgcn_s_setprio(1);
    // QK(t+1) from Ks[nxt] -- independent of softmax(t)/PV(t): the
    // scheduler interleaves these MFMAs with the VALU chain above and the
    // PV MFMAs below.
    if ((st + 1) * 64 <= wmax) qk(Ks[nxt]);

    if (act) {
      // PV(t) at K=32 from Vs[cur]: V frag uses the SAME k->s permutation
      // as P8 (exact: MFMA sums over the shared k index).
      const f16* Vc = Vs[cur];
#pragma unroll
      for (int c = 0; c < 2; c++) {
        const int chlo = c * 4 + (quad >> 1);
        const int soff = (quad & 1) * 4;
#pragma unroll
        for (int db = 0; db < 8; db++) {
          const int d = db * 16 + lnm;
          const f16* vrow = &Vc[d * 64];
          f16x4 vlo = *(const f16x4*)&vrow[((chlo ^ (d & 7)) * 8) + soff];
          f16x4 vhi =
              *(const f16x4*)&vrow[(((chlo + 2) ^ (d & 7)) * 8) + soff];
          f16x8 vb;
#pragma unroll
          for (int j = 0; j < 4; j++) {
            vb[j] = vlo[j];
            vb[4 + j] = vhi[j];
          }
          O[0][db] = __builtin_amdgcn_mfma_f32_16x16x32_f16(P8[0][c], vb,
                                                            O[0][db], 0, 0, 0);
          O[1][db] = __builtin_amdgcn_mfma_f32_16x16x32_f16(P8[1][c], vb,
                                                            O[1][db], 0, 0, 0);
        }
      }
    }
    __builtin_amdgcn_s_setprio(0);
    __syncthreads();  // drains this iter's DMA + separates buffer reuse
  }

  // Row-sums across quads
#pragma unroll
  for (int qnb = 0; qnb < 2; qnb++) {
    float l = l_acc[qnb];
    l += __shfl_xor(l, 16, 64);
    l += __shfl_xor(l, 32, 64);
    l_acc[qnb] = l;
  }

  // Epilogue: y = O / l (f16)
#pragma unroll
  for (int qnb = 0; qnb < 2; qnb++) {
    float linv[4];
#pragma unroll
    for (int r = 0; r < 4; r++)
      linv[r] = 1.f / __shfl(l_acc[qnb], quad * 4 + r, 64);
#pragma unroll
    for (int db = 0; db < 8; db++)
#pragma unroll
      for (int r = 0; r < 4; r++) {
        size_t off =
            ((size_t)(b * TT + q0 + qnb * 16 + quad * 4 + r) * HH + h) * DD +
            db * 16 + lnm;
        y[off] = (f16)(O[qnb][db][r] * linv[r]);
      }
  }
}

// ---------------------------------------------------------------------------
extern "C" void kernel_launch(void* const* d_in, const int* in_sizes, int n_in,
                              void* d_out, int out_size, void* d_ws,
                              size_t ws_size, hipStream_t stream) {
  const float* x      = (const float*)d_in[0];
  const float* fcos   = (const float*)d_in[1];
  const float* fsin   = (const float*)d_in[2];
  const float* wq     = (const float*)d_in[3];
  const float* wkv_dn = (const float*)d_in[4];
  const float* wk_up  = (const float*)d_in[5];
  const float* wv_up  = (const float*)d_in[6];
  const float* wo     = (const float*)d_in[7];
  float* out = (float*)d_out;

  const int M = BB * TT;  // 8192

  // Workspace layout. q-GEMM writes qh (f16, roped) directly, so the old
  // fp32 q buffer is repurposed: [qh | yh] (each M*CC f16 = 32 MB).
  // kk+vv are adjacent -> fused as kkvv fp32 [M][256] (k cols 0-127,
  // v cols 128-255) written by ONE up-projection GEMM (N=256).
  float* ws = (float*)d_ws;
  float* qbuf   = ws;                              // 64 MB slot: qh + yh
  float* kv     = qbuf + (size_t)M * CC;           // 4.2M f32 (16 MB)
  float* kkvv   = kv + (size_t)M * LL;             // 2M f32 (8 MB)
  f16*   xh     = (f16*)(kkvv + (size_t)M * 256);  // 16.7M f16 (32 MB)
  f16*   wqh    = xh + (size_t)M * CC;             // 4.2M f16 (8 MB)
  f16*   wdownh = wqh + (size_t)CC * CC;           // 1M f16 (2 MB)
  f16*   wkvuph = wdownh + (size_t)LL * CC;        // 128K f16 (k rows 0-127,
                                                   //           v rows 128-255)
  f16*   woh    = wkvuph + (size_t)256 * LL;       // 4.2M f16 (8 MB)
  f16*   kvh    = woh + (size_t)CC * CC;           // 4.2M f16 (8 MB)
  f16*   khb    = kvh + (size_t)M * LL;            // 1M f16 (2 MB)
  f16*   vth    = khb + (size_t)M * DD;            // 1M f16 (2 MB)
  f16*   qh     = (f16*)qbuf;                      // 32 MB
  f16*   yh     = qh + (size_t)M * CC;             // 32 MB

  dim3 blk(256);

  // fp32 -> f16 conversions
  mla_cvt_f16<<<(M * CC / 4 + 255) / 256, blk, 0, stream>>>(
      (const float4*)x, xh, M * CC / 4);
  mla_cvt_f16<<<(CC * CC / 4 + 255) / 256, blk, 0, stream>>>(
      (const float4*)wq, wqh, CC * CC / 4);
  mla_cvt_f16<<<(LL * CC / 4 + 255) / 256, blk, 0, stream>>>(
      (const float4*)wkv_dn, wdownh, LL * CC / 4);
  mla_cvt_f16<<<(DD * LL / 4 + 255) / 256, blk, 0, stream>>>(
      (const float4*)wk_up, wkvuph, DD * LL / 4);
  mla_cvt_f16<<<(DD * LL / 4 + 255) / 256, blk, 0, stream>>>(
      (const float4*)wv_up, wkvuph + (size_t)DD * LL, DD * LL / 4);
  mla_cvt_f16<<<(CC * CC / 4 + 255) / 256, blk, 0, stream>>>(
      (const float4*)wo, woh, CC * CC / 4);

  // q = rope(x @ wq^T) (8-phase 256^2, fused epilogue -> f16 qh, exp2 scale)
  mla_gemm_256<1><<<dim3((M / 256) * (CC / 256)), dim3(512), 0, stream>>>(
      xh, wqh, qh, M, CC, CC, fcos, fsin);
  // kv = x @ wdown^T (128^2: N=512 -> 256 wgs)
  mla_gemm_mfma<<<dim3(LL / 128, M / 128), blk, 0, stream>>>(
      xh, wdownh, kv, M, LL, CC);

  // kv -> f16, then fused k|v up-projection (N=256, one dispatch)
  mla_cvt_f16<<<(M * LL / 4 + 255) / 256, blk, 0, stream>>>(
      (const float4*)kv, kvh, M * LL / 4);
  mla_gemm_mfma<<<dim3(256 / 128, M / 128), blk, 0, stream>>>(
      kvh, wkvuph, kkvv, M, 256, LL);

  // k RoPE + f16 conversion (k = kkvv cols 0-127, row stride 256 f32)
  {
    int total_k = BB * TT * (DD / 2);
    mla_rope_cvt<<<(total_k + 255) / 256, blk, 0, stream>>>(
        (const float2*)kkvv, khb, fcos, fsin, 128, 1.0f, total_k);
  }

  // v -> vt (transposed f16); v = kkvv cols 128-255, row stride 256 f32
  mla_transpose_v<<<dim3(TT / 32, DD / 32, BB), blk, 0, stream>>>(
      kkvv + 128, vth, 256);

  // Flash attention v5 -> yh (f16). 512 blocks x 512 threads, LPT order.
  mla_flash2<<<dim3(BB * HH * (TT / 256)), dim3(512), 0, stream>>>(
      qh, khb, vth, yh);

  // out = y @ wo^T (8-phase 256^2)
  mla_gemm_256<0><<<dim3((M / 256) * (CC / 256)), dim3(512), 0, stream>>>(
      yh, woh, out, M, CC, CC, nullptr, nullptr);
}

// Round 7
// 454.773 us; speedup vs baseline: 1.2666x; 1.0012x over previous
//
#include <hip/hip_runtime.h>
#include <hip/hip_bf16.h>
#include <cstddef>

// Problem constants
#define BB 4
#define TT 2048
#define CC 2048
#define HH 16
#define DD 128
#define LL 512

typedef _Float16 f16;
typedef f16 f16x2 __attribute__((ext_vector_type(2)));
typedef f16 f16x4 __attribute__((ext_vector_type(4)));
typedef f16 f16x8 __attribute__((ext_vector_type(8)));
typedef float f32x4 __attribute__((ext_vector_type(4)));

// ---------------------------------------------------------------------------
// async global->LDS, 16 B per lane (global_load_lds_dwordx4).
// ---------------------------------------------------------------------------
__device__ __forceinline__ void async_load16(void* lptr, const void* gptr) {
  __builtin_amdgcn_global_load_lds(
      (const __attribute__((address_space(1))) unsigned int*)gptr,
      (__attribute__((address_space(3))) unsigned int*)lptr, 16, 0, 0);
}

// ---------------------------------------------------------------------------
// 256x256 8-phase MFMA NT GEMM (f16 in): C[m,n] = sum_k A[m,k]B[n,k]
// m201-style template. EPI=0: fp32 store. EPI=1: fused RoPE+scale+f16 store
// (q path; scale includes log2(e) -- flash uses exp2).
// ---------------------------------------------------------------------------
template <int EPI>
__global__ __launch_bounds__(512, 2) void mla_gemm_256(
    const f16* __restrict__ A, const f16* __restrict__ B,
    void* __restrict__ Cv, int M, int N, int K,
    const float* __restrict__ cosb, const float* __restrict__ sinb) {
  __shared__ __align__(16) f16 smem[2][2][256 * 64];

  const int tid = threadIdx.x;       // 0..511
  const int lane = tid & 63;
  const int w = tid >> 6;            // 0..7
  const int lnm = lane & 15, quad = lane >> 4;
  const int wm = w >> 2, wn = w & 3; // 2 x 4 wave grid; wave tile 128x64

  // Bijective XCD-aware block swizzle (m204 variant).
  const int nwg = gridDim.x;
  const int bid0 = blockIdx.x;
  const int q8 = nwg >> 3, r8 = nwg & 7;
  const int xcd = bid0 & 7, lid = bid0 >> 3;
  const int wg =
      (xcd < r8 ? xcd * (q8 + 1) : r8 * (q8 + 1) + (xcd - r8) * q8) + lid;
  const int ntc = N >> 8;
  const int m0 = (wg / ntc) * 256;
  const int n0 = (wg % ntc) * 256;

  const int srow = tid >> 3;
  const int sch = (tid & 7) ^ ((tid >> 3) & 7);
  const f16* Ag = A + (size_t)(m0 + srow) * K + sch * 8;
  const f16* Bg = B + (size_t)(n0 + srow) * K + sch * 8;

  auto stage = [&](int bi, int k0, int h) {
    const int mat = h >> 1;
    const int rb = (h & 1) * 128;
    const f16* g = (mat ? Bg : Ag) + (size_t)rb * K + k0;
    f16* l = &smem[bi][mat][rb * 64 + tid * 8];
    async_load16(l, g);
    async_load16(l + 4096, g + (size_t)64 * K);
  };

  const int rx8 = lnm & 7;
  auto rdA = [&](const f16* Ab, int i, int ks) -> f16x8 {
    return *(const f16x8*)&Ab[(wm * 128 + i * 16 + lnm) * 64 +
                              (((ks * 4 + quad) ^ rx8) * 8)];
  };
  auto rdB = [&](const f16* Bb, int j, int ks) -> f16x8 {
    return *(const f16x8*)&Bb[(wn * 64 + j * 16 + lnm) * 64 +
                              (((ks * 4 + quad) ^ rx8) * 8)];
  };

  f32x4 acc[8][4] = {};

  const int NT = K >> 6;

  stage(0, 0, 0);
  stage(0, 0, 1);
  stage(0, 0, 2);
  stage(0, 0, 3);
  stage(1, 64, 0);
  asm volatile("s_waitcnt vmcnt(2)" ::: "memory");
  __builtin_amdgcn_s_barrier();

  for (int t = 0; t < NT; ++t) {
    const int bi = t & 1;
    const f16* Ab = smem[bi][0];
    const f16* Bb = smem[bi][1];
    const int k1 = (t + 1 < NT ? t + 1 : t) << 6;
    const int k2 = (t + 2 < NT ? t + 2 : t) << 6;

    f16x8 Ar[4][2], Br[2][2];

    // -------- phase 1: quadrant (mq0, nq0) --------
#pragma unroll
    for (int i = 0; i < 4; i++)
#pragma unroll
      for (int ks = 0; ks < 2; ks++) Ar[i][ks] = rdA(Ab, i, ks);
#pragma unroll
    for (int j = 0; j < 2; j++)
#pragma unroll
      for (int ks = 0; ks < 2; ks++) Br[j][ks] = rdB(Bb, j, ks);
    stage(bi ^ 1, k1, 1);
    __builtin_amdgcn_s_barrier();
    asm volatile("s_waitcnt lgkmcnt(0)" ::: "memory");
    __builtin_amdgcn_s_setprio(1);
#pragma unroll
    for (int i = 0; i < 4; i++)
#pragma unroll
      for (int j = 0; j < 2; j++)
#pragma unroll
        for (int ks = 0; ks < 2; ks++)
          acc[i][j] = __builtin_amdgcn_mfma_f32_16x16x32_f16(
              Ar[i][ks], Br[j][ks], acc[i][j], 0, 0, 0);
    __builtin_amdgcn_s_setprio(0);
    __builtin_amdgcn_s_barrier();

    // -------- phase 2: quadrant (mq0, nq1) --------
#pragma unroll
    for (int j = 0; j < 2; j++)
#pragma unroll
      for (int ks = 0; ks < 2; ks++) Br[j][ks] = rdB(Bb, 2 + j, ks);
    stage(bi ^ 1, k1, 2);
    __builtin_amdgcn_s_barrier();
    asm volatile("s_waitcnt lgkmcnt(0)" ::: "memory");
    __builtin_amdgcn_s_setprio(1);
#pragma unroll
    for (int i = 0; i < 4; i++)
#pragma unroll
      for (int j = 0; j < 2; j++)
#pragma unroll
        for (int ks = 0; ks < 2; ks++)
          acc[i][2 + j] = __builtin_amdgcn_mfma_f32_16x16x32_f16(
              Ar[i][ks], Br[j][ks], acc[i][2 + j], 0, 0, 0);
    __builtin_amdgcn_s_setprio(0);
    __builtin_amdgcn_s_barrier();

    // -------- phase 3: quadrant (mq1, nq1) --------
#pragma unroll
    for (int i = 0; i < 4; i++)
#pragma unroll
      for (int ks = 0; ks < 2; ks++) Ar[i][ks] = rdA(Ab, 4 + i, ks);
    stage(bi ^ 1, k1, 3);
    __builtin_amdgcn_s_barrier();
    asm volatile("s_waitcnt lgkmcnt(0)" ::: "memory");
    __builtin_amdgcn_s_setprio(1);
#pragma unroll
    for (int i = 0; i < 4; i++)
#pragma unroll
      for (int j = 0; j < 2; j++)
#pragma unroll
        for (int ks = 0; ks < 2; ks++)
          acc[4 + i][2 + j] = __builtin_amdgcn_mfma_f32_16x16x32_f16(
              Ar[i][ks], Br[j][ks], acc[4 + i][2 + j], 0, 0, 0);
    __builtin_amdgcn_s_setprio(0);
    __builtin_amdgcn_s_barrier();

    // -------- phase 4: quadrant (mq1, nq0) --------
#pragma unroll
    for (int j = 0; j < 2; j++)
#pragma unroll
      for (int ks = 0; ks < 2; ks++) Br[j][ks] = rdB(Bb, j, ks);
    stage(bi, k2, 0);
    __builtin_amdgcn_s_barrier();
    asm volatile("s_waitcnt lgkmcnt(0)" ::: "memory");
    __builtin_amdgcn_s_setprio(1);
#pragma unroll
    for (int i = 0; i < 4; i++)
#pragma unroll
      for (int j = 0; j < 2; j++)
#pragma unroll
        for (int ks = 0; ks < 2; ks++)
          acc[4 + i][j] = __builtin_amdgcn_mfma_f32_16x16x32_f16(
              Ar[i][ks], Br[j][ks], acc[4 + i][j], 0, 0, 0);
    __builtin_amdgcn_s_setprio(0);
    asm volatile("s_waitcnt vmcnt(2)" ::: "memory");
    __builtin_amdgcn_s_barrier();
  }

  asm volatile("s_waitcnt vmcnt(0)" ::: "memory");

  if constexpr (EPI == 0) {
    float* C = (float*)Cv;
#pragma unroll
    for (int i = 0; i < 8; i++)
#pragma unroll
      for (int r = 0; r < 4; r++) {
        float* crow = C + (size_t)(m0 + wm * 128 + i * 16 + quad * 4 + r) * N +
                      n0 + wn * 64 + lnm;
#pragma unroll
        for (int j = 0; j < 4; j++) crow[j * 16] = acc[i][j][r];
      }
  } else {
    // Fused RoPE + scale + f16 store. SCLQ = (1/sqrt(D)) * log2(e).
    f16* C = (f16*)Cv;
    const float SCLQ = 0.1275174280f;
#pragma unroll
    for (int i = 0; i < 8; i++)
#pragma unroll
      for (int r = 0; r < 4; r++) {
        const int m = m0 + wm * 128 + i * 16 + quad * 4 + r;
        const int t = m & (TT - 1);
#pragma unroll
        for (int j = 0; j < 4; j++) {
          const int col = n0 + wn * 64 + j * 16 + lnm;
          float v = acc[i][j][r];
          float u = __shfl_xor(v, 1, 64);
          const int fi = (col & (DD - 1)) >> 1;
          const float ct = cosb[t * (DD / 2) + fi];
          const float st2 = sinb[t * (DD / 2) + fi];
          const float o =
              (lnm & 1) ? (u * st2 + v * ct) : (v * ct - u * st2);
          C[(size_t)m * N + col] = (f16)(o * SCLQ);
        }
      }
  }
}

// ---------------------------------------------------------------------------
// MFMA NT GEMM 128x128 (m97 recipe). Kept for N<2048 shapes.
// ---------------------------------------------------------------------------
__global__ __launch_bounds__(256) void mla_gemm_mfma(
    const f16* __restrict__ A, const f16* __restrict__ B,
    float* __restrict__ C, int M, int N, int K) {
  __shared__ f16 As[128 * 32];
  __shared__ f16 Bs[128 * 32];

  const int tid = threadIdx.x;
  const int lane = tid & 63;
  const int w = tid >> 6;
  const int lnm = lane & 15, quad = lane >> 4;
  const int wm = w >> 1, wn = w & 1;
  const int m0 = blockIdx.y * 128;
  const int n0 = blockIdx.x * 128;

  const int srow = tid >> 2;
  const int skoff = (tid & 3) * 8;

  f32x4 acc[4][4] = {};

  for (int k0 = 0; k0 < K; k0 += 32) {
    const f16* ag = A + (size_t)(m0 + srow) * K + k0 + skoff;
    const f16* bg = B + (size_t)(n0 + srow) * K + k0 + skoff;
    async_load16(&As[(size_t)tid * 8], ag);
    async_load16(&As[(size_t)(256 + tid) * 8], ag + (size_t)64 * K);
    async_load16(&Bs[(size_t)tid * 8], bg);
    async_load16(&Bs[(size_t)(256 + tid) * 8], bg + (size_t)64 * K);
    __syncthreads();

    f16x8 af[4], bf[4];
#pragma unroll
    for (int i = 0; i < 4; i++)
      af[i] = *(const f16x8*)&As[(wm * 64 + i * 16 + lnm) * 32 + quad * 8];
#pragma unroll
    for (int j = 0; j < 4; j++)
      bf[j] = *(const f16x8*)&Bs[(wn * 64 + j * 16 + lnm) * 32 + quad * 8];
#pragma unroll
    for (int i = 0; i < 4; i++)
#pragma unroll
      for (int j = 0; j < 4; j++)
        acc[i][j] = __builtin_amdgcn_mfma_f32_16x16x32_f16(af[i], bf[j],
                                                           acc[i][j], 0, 0, 0);
    __syncthreads();
  }

#pragma unroll
  for (int i = 0; i < 4; i++)
#pragma unroll
    for (int r = 0; r < 4; r++) {
      float* crow = C + (size_t)(m0 + wm * 64 + i * 16 + quad * 4 + r) * N +
                    n0 + wn * 64 + lnm;
#pragma unroll
      for (int j = 0; j < 4; j++) crow[j * 16] = acc[i][j][r];
    }
}

// ---------------------------------------------------------------------------
// fp32 -> f16 convert (vectorized, n % 4 == 0)
// ---------------------------------------------------------------------------
__global__ __launch_bounds__(256) void mla_cvt_f16(
    const float4* __restrict__ in, f16* __restrict__ out, int n4) {
  int i = blockIdx.x * 256 + threadIdx.x;
  if (i >= n4) return;
  float4 v = in[i];
  f16x4 r = {(f16)v.x, (f16)v.y, (f16)v.z, (f16)v.w};
  *(f16x4*)(out + (size_t)i * 4) = r;
}

// ---------------------------------------------------------------------------
// k RoPE + f16 + FRAGMENT-READY store: khp[b][st][cq][s][e] = K[t][cq*8+e],
// t = st*64+s. Flash then stages K tiles with a LINEAR global_load_lds copy
// and reads A-fragments as single ds_read_b128 at immediate offsets.
// Input rows stride ld2 float2 (k lives in the fused kkvv buffer).
// ---------------------------------------------------------------------------
__global__ __launch_bounds__(256) void mla_rope_k(
    const float2* __restrict__ x, f16* __restrict__ khp,
    const float* __restrict__ cosb, const float* __restrict__ sinb,
    int ld2, int total) {
  int idx = blockIdx.x * blockDim.x + threadIdx.x;
  if (idx >= total) return;
  const int i = idx & 63;        // pair index (d = 2i, 2i+1)
  const int m = idx >> 6;
  const int t = m & (TT - 1);
  const int b = m >> 11;
  float c = cosb[t * 64 + i];
  float s = sinb[t * 64 + i];
  float2 v = x[(size_t)m * ld2 + i];
  f16x2 r;
  r.x = (f16)(v.x * c - v.y * s);
  r.y = (f16)(v.x * s + v.y * c);
  const int st = t >> 6, sl = t & 63;
  const int cq = i >> 2, e = (i & 3) * 2;
  size_t off = (((size_t)(b * 32 + st) * 16 + cq) * 64 + sl) * 8 + e;
  *(f16x2*)(khp + off) = r;
}

// ---------------------------------------------------------------------------
// v fp32 [rows m, stride ldv, cols 0..127] -> FRAGMENT-READY f16
// vtp[b][st][cq2][d][e] = V[st*64 + sv(cq2,e)][d],
// sv = (cq2>>2)*32 + (cq2&3)*4 + (e>=4)*16 + (e&3)  (== flash P8 k->s map).
// Flash stages V tiles linearly and reads B-fragments as single b128.
// ---------------------------------------------------------------------------
__global__ __launch_bounds__(256) void mla_fragv(
    const float* __restrict__ v, f16* __restrict__ vtp, int ldv) {
  __shared__ f16 tl[64][128];
  const int b = blockIdx.z;
  const int st = blockIdx.x;
  const int t = threadIdx.x;

  // Load 64x128 fp32 -> f16 LDS tile (coalesced float4 reads).
  const int dl = (t & 31) * 4;
#pragma unroll
  for (int r = 0; r < 8; r++) {
    const int s = r * 8 + (t >> 5);
    float4 val = *(const float4*)&v[((size_t)(b * TT + st * 64 + s)) * ldv + dl];
    f16x4 h = {(f16)val.x, (f16)val.y, (f16)val.z, (f16)val.w};
    *(f16x4*)&tl[s][dl] = h;
  }
  __syncthreads();

  // Emit 1024 fragment chunks of 16B (4 per thread).
  f16* outb = vtp + (size_t)(b * 32 + st) * 8192;
#pragma unroll
  for (int k = 0; k < 4; k++) {
    const int cd = k * 256 + t;
    const int cq2 = cd >> 7, d = cd & 127;
    const int c = cq2 >> 2, quad = cq2 & 3;
    f16x8 o;
#pragma unroll
    for (int e = 0; e < 8; e++) {
      const int s = c * 32 + quad * 4 + ((e >> 2) << 4) + (e & 3);
      o[e] = tl[s][d];
    }
    *(f16x8*)&outb[(size_t)cd * 8] = o;
  }
}

// ---------------------------------------------------------------------------
// Block-cooperative MFMA flash attention v6: fragment-ready LDS layouts.
// K tile [cq][s][e] and V tile [cq2][d][e] arrive in MFMA-fragment order:
// every A/B fragment is ONE ds_read_b128 at lane_base + immediate offset
// (zero per-read address VALU, no two-chunk concat). Staging is a linear
// global_load_lds copy, double-buffered, staged one tile ahead.
// Softmax: exp2 (log2e folded into q scale), wave-uniform mask split.
// ---------------------------------------------------------------------------
__global__ __launch_bounds__(512, 2) void mla_flash2(
    const f16* __restrict__ qh, const f16* __restrict__ khp,
    const f16* __restrict__ vtp, f16* __restrict__ y) {
  __shared__ __align__(16) f16 Ks[2][8192];  // [cq 0..15][s 0..63][e 0..7]
  __shared__ __align__(16) f16 Vs[2][8192];  // [cq2 0..7][d 0..127][e 0..7]

  const int tid = threadIdx.x;
  const int lane = tid & 63;
  const int w = tid >> 6;  // 0..7
  const int lnm = lane & 15, quad = lane >> 4;

  const int bid = blockIdx.x;
  const int qt = (TT / 256 - 1) - (bid >> 6);  // LPT: longest q-tiles first
  const int bh = bid & 63;
  const int b = bh >> 4, h = bh & 15;
  const int q0b = qt * 256;
  const int q0 = q0b + w * 32;  // this wave's 32 q-rows

  // Q B-frags (global, once per block)
  f16x8 qf[2][4];
#pragma unroll
  for (int qnb = 0; qnb < 2; qnb++) {
    const f16* qrow =
        qh + ((size_t)(b * TT + q0 + qnb * 16 + lnm) * HH + h) * DD;
#pragma unroll
    for (int c = 0; c < 4; c++)
      qf[qnb][c] = *(const f16x8*)(qrow + c * 32 + quad * 8);
  }

  f32x4 O[2][8] = {};
  float l_acc[2] = {0.f, 0.f};

  const int nst = (q0b + 256) / 64;  // 4*qt + 4
  const int wmax = q0 + 31;
  const f16* kpb = khp + (size_t)b * 32 * 8192;  // per-b tile array
  const f16* vpb = vtp + (size_t)b * 32 * 8192;

  auto stageK = [&](int buf, int st) {
    const f16* g = kpb + (size_t)st * 8192 + (size_t)tid * 8;
    async_load16(&Ks[buf][(size_t)tid * 8], g);
    async_load16(&Ks[buf][(size_t)(512 + tid) * 8], g + 4096);
  };
  auto stageV = [&](int buf, int st) {
    const f16* g = vpb + (size_t)st * 8192 + (size_t)tid * 8;
    async_load16(&Vs[buf][(size_t)tid * 8], g);
    async_load16(&Vs[buf][(size_t)(512 + tid) * 8], g + 4096);
  };

  // Per-lane fragment base offsets (f16 units).
  const int kbo = quad * 512 + lnm * 8;   // + c*2048 + sb*128
  const int vbo = quad * 1024 + lnm * 8;  // + c*4096 + db*128

  stageK(0, 0);
  stageV(0, 0);
  __syncthreads();  // tile 0 landed

  for (int st = 0; st < nst; st++) {
    const int cur = st & 1;
    const int s0 = st * 64;
    if (st + 1 < nst) {  // stage next tile; latency hides under compute
      stageK(cur ^ 1, st + 1);
      stageV(cur ^ 1, st + 1);
    }

    if (s0 <= wmax) {  // wave-uniform: skip fully-masked tiles
      const f16* kl = &Ks[cur][kbo];
      const f16* vl = &Vs[cur][vbo];

      // QK: S^T = K . Q^T -- 16 b128 reads, imm offsets
      f32x4 S[2][4] = {};
      __builtin_amdgcn_s_setprio(1);
#pragma unroll
      for (int sb = 0; sb < 4; sb++)
#pragma unroll
        for (int c = 0; c < 4; c++) {
          f16x8 ka = *(const f16x8*)&kl[c * 2048 + sb * 128];
          S[0][sb] = __builtin_amdgcn_mfma_f32_16x16x32_f16(ka, qf[0][c],
                                                            S[0][sb], 0, 0, 0);
          S[1][sb] = __builtin_amdgcn_mfma_f32_16x16x32_f16(ka, qf[1][c],
                                                            S[1][sb], 0, 0, 0);
        }
      __builtin_amdgcn_s_setprio(0);

      // P = exp2(S) (+ causal mask on diagonal tiles), packed as K=32
      // A-frags: P8[qnb][c][e], s = c*32 + quad*4 + (e>=4)*16 + (e&3).
      f16x8 P8[2][2];
      const bool domask = (s0 + 63 > q0);  // wave-uniform
      if (!domask) {
#pragma unroll
        for (int qnb = 0; qnb < 2; qnb++) {
          float lp = 0.f;
#pragma unroll
          for (int sb = 0; sb < 4; sb++)
#pragma unroll
            for (int j = 0; j < 4; j++) {
              float p = __builtin_amdgcn_exp2f(S[qnb][sb][j]);
              lp += p;
              P8[qnb][sb >> 1][(sb & 1) * 4 + j] = (f16)p;
            }
          l_acc[qnb] += lp;
        }
      } else {
#pragma unroll
        for (int qnb = 0; qnb < 2; qnb++) {
          const int m_abs = q0 + qnb * 16 + lnm;
          float lp = 0.f;
#pragma unroll
          for (int sb = 0; sb < 4; sb++) {
            const int srow = s0 + sb * 16 + quad * 4;
#pragma unroll
            for (int j = 0; j < 4; j++) {
              float p = __builtin_amdgcn_exp2f(S[qnb][sb][j]);
              if (srow + j > m_abs) p = 0.f;
              lp += p;
              P8[qnb][sb >> 1][(sb & 1) * 4 + j] = (f16)p;
            }
          }
          l_acc[qnb] += lp;
        }
      }

      // PV at K=32 -- 16 b128 reads, imm offsets; V frag shares P8's k->s map.
      __builtin_amdgcn_s_setprio(1);
#pragma unroll
      for (int c = 0; c < 2; c++)
#pragma unroll
        for (int db = 0; db < 8; db++) {
          f16x8 vb = *(const f16x8*)&vl[c * 4096 + db * 128];
          O[0][db] = __builtin_amdgcn_mfma_f32_16x16x32_f16(P8[0][c], vb,
                                                            O[0][db], 0, 0, 0);
          O[1][db] = __builtin_amdgcn_mfma_f32_16x16x32_f16(P8[1][c], vb,
                                                            O[1][db], 0, 0, 0);
        }
      __builtin_amdgcn_s_setprio(0);
    }
    __syncthreads();  // drains next-tile DMA + separates buffer reuse
  }

  // Row-sums across quads
#pragma unroll
  for (int qnb = 0; qnb < 2; qnb++) {
    float l = l_acc[qnb];
    l += __shfl_xor(l, 16, 64);
    l += __shfl_xor(l, 32, 64);
    l_acc[qnb] = l;
  }

  // Epilogue: y = O / l (f16)
#pragma unroll
  for (int qnb = 0; qnb < 2; qnb++) {
    float linv[4];
#pragma unroll
    for (int r = 0; r < 4; r++)
      linv[r] = 1.f / __shfl(l_acc[qnb], quad * 4 + r, 64);
#pragma unroll
    for (int db = 0; db < 8; db++)
#pragma unroll
      for (int r = 0; r < 4; r++) {
        size_t off =
            ((size_t)(b * TT + q0 + qnb * 16 + quad * 4 + r) * HH + h) * DD +
            db * 16 + lnm;
        y[off] = (f16)(O[qnb][db][r] * linv[r]);
      }
  }
}

// ---------------------------------------------------------------------------
extern "C" void kernel_launch(void* const* d_in, const int* in_sizes, int n_in,
                              void* d_out, int out_size, void* d_ws,
                              size_t ws_size, hipStream_t stream) {
  const float* x      = (const float*)d_in[0];
  const float* fcos   = (const float*)d_in[1];
  const float* fsin   = (const float*)d_in[2];
  const float* wq     = (const float*)d_in[3];
  const float* wkv_dn = (const float*)d_in[4];
  const float* wk_up  = (const float*)d_in[5];
  const float* wv_up  = (const float*)d_in[6];
  const float* wo     = (const float*)d_in[7];
  float* out = (float*)d_out;

  const int M = BB * TT;  // 8192

  // Workspace layout (as round 6; khb/vth now hold fragment-ready layouts).
  float* ws = (float*)d_ws;
  float* qbuf   = ws;                              // 64 MB slot: qh + yh
  float* kv     = qbuf + (size_t)M * CC;           // 16 MB
  float* kkvv   = kv + (size_t)M * LL;             // 8 MB  [M][256] k|v
  f16*   xh     = (f16*)(kkvv + (size_t)M * 256);  // 32 MB
  f16*   wqh    = xh + (size_t)M * CC;             // 8 MB
  f16*   wdownh = wqh + (size_t)CC * CC;           // 2 MB
  f16*   wkvuph = wdownh + (size_t)LL * CC;        // 128K f16
  f16*   woh    = wkvuph + (size_t)256 * LL;       // 8 MB
  f16*   kvh    = woh + (size_t)CC * CC;           // 8 MB
  f16*   khp    = kvh + (size_t)M * LL;            // 2 MB (fragment K)
  f16*   vtp    = khp + (size_t)M * DD;            // 2 MB (fragment V)
  f16*   qh     = (f16*)qbuf;                      // 32 MB
  f16*   yh     = qh + (size_t)M * CC;             // 32 MB

  dim3 blk(256);

  // fp32 -> f16 conversions
  mla_cvt_f16<<<(M * CC / 4 + 255) / 256, blk, 0, stream>>>(
      (const float4*)x, xh, M * CC / 4);
  mla_cvt_f16<<<(CC * CC / 4 + 255) / 256, blk, 0, stream>>>(
      (const float4*)wq, wqh, CC * CC / 4);
  mla_cvt_f16<<<(LL * CC / 4 + 255) / 256, blk, 0, stream>>>(
      (const float4*)wkv_dn, wdownh, LL * CC / 4);
  mla_cvt_f16<<<(DD * LL / 4 + 255) / 256, blk, 0, stream>>>(
      (const float4*)wk_up, wkvuph, DD * LL / 4);
  mla_cvt_f16<<<(DD * LL / 4 + 255) / 256, blk, 0, stream>>>(
      (const float4*)wv_up, wkvuph + (size_t)DD * LL, DD * LL / 4);
  mla_cvt_f16<<<(CC * CC / 4 + 255) / 256, blk, 0, stream>>>(
      (const float4*)wo, woh, CC * CC / 4);

  // q = rope(x @ wq^T) (8-phase 256^2, fused epilogue -> f16 qh, exp2 scale)
  mla_gemm_256<1><<<dim3((M / 256) * (CC / 256)), dim3(512), 0, stream>>>(
      xh, wqh, qh, M, CC, CC, fcos, fsin);
  // kv = x @ wdown^T (128^2: N=512 -> 256 wgs)
  mla_gemm_mfma<<<dim3(LL / 128, M / 128), blk, 0, stream>>>(
      xh, wdownh, kv, M, LL, CC);

  // kv -> f16, then fused k|v up-projection (N=256, one dispatch)
  mla_cvt_f16<<<(M * LL / 4 + 255) / 256, blk, 0, stream>>>(
      (const float4*)kv, kvh, M * LL / 4);
  mla_gemm_mfma<<<dim3(256 / 128, M / 128), blk, 0, stream>>>(
      kvh, wkvuph, kkvv, M, 256, LL);

  // k RoPE -> fragment-ready khp (k = kkvv cols 0-127, row stride 256 f32)
  {
    int total_k = BB * TT * (DD / 2);
    mla_rope_k<<<(total_k + 255) / 256, blk, 0, stream>>>(
        (const float2*)kkvv, khp, fcos, fsin, 128, total_k);
  }

  // v -> fragment-ready vtp (v = kkvv cols 128-255, row stride 256 f32)
  mla_fragv<<<dim3(TT / 64, 1, BB), blk, 0, stream>>>(kkvv + 128, vtp, 256);

  // Flash attention v6 -> yh (f16). 512 blocks x 512 threads, LPT order.
  mla_flash2<<<dim3(BB * HH * (TT / 256)), dim3(512), 0, stream>>>(
      qh, khp, vtp, yh);

  // out = y @ wo^T (8-phase 256^2)
  mla_gemm_256<0><<<dim3((M / 256) * (CC / 256)), dim3(512), 0, stream>>>(
      yh, woh, out, M, CC, CC, nullptr, nullptr);
}

// Round 8
// 432.088 us; speedup vs baseline: 1.3330x; 1.0525x over previous
//
#include <hip/hip_runtime.h>
#include <hip/hip_bf16.h>
#include <cstddef>

// Problem constants
#define BB 4
#define TT 2048
#define CC 2048
#define HH 16
#define DD 128
#define LL 512

typedef _Float16 f16;
typedef f16 f16x2 __attribute__((ext_vector_type(2)));
typedef f16 f16x4 __attribute__((ext_vector_type(4)));
typedef f16 f16x8 __attribute__((ext_vector_type(8)));
typedef float f32x4 __attribute__((ext_vector_type(4)));

// ---------------------------------------------------------------------------
// async global->LDS, 16 B per lane (global_load_lds_dwordx4).
// ---------------------------------------------------------------------------
__device__ __forceinline__ void async_load16(void* lptr, const void* gptr) {
  __builtin_amdgcn_global_load_lds(
      (const __attribute__((address_space(1))) unsigned int*)gptr,
      (__attribute__((address_space(3))) unsigned int*)lptr, 16, 0, 0);
}

// ---------------------------------------------------------------------------
// 256x256 8-phase MFMA NT GEMM (f16 in): C[m,n] = sum_k A[m,k]B[n,k]
// m201-style template. EPI=0: fp32 store. EPI=1: fused RoPE+scale+f16 store
// (q path; scale includes log2(e) -- flash uses exp2).
// ---------------------------------------------------------------------------
template <int EPI>
__global__ __launch_bounds__(512, 2) void mla_gemm_256(
    const f16* __restrict__ A, const f16* __restrict__ B,
    void* __restrict__ Cv, int M, int N, int K,
    const float* __restrict__ cosb, const float* __restrict__ sinb) {
  __shared__ __align__(16) f16 smem[2][2][256 * 64];

  const int tid = threadIdx.x;       // 0..511
  const int lane = tid & 63;
  const int w = tid >> 6;            // 0..7
  const int lnm = lane & 15, quad = lane >> 4;
  const int wm = w >> 2, wn = w & 3; // 2 x 4 wave grid; wave tile 128x64

  // Bijective XCD-aware block swizzle (m204 variant).
  const int nwg = gridDim.x;
  const int bid0 = blockIdx.x;
  const int q8 = nwg >> 3, r8 = nwg & 7;
  const int xcd = bid0 & 7, lid = bid0 >> 3;
  const int wg =
      (xcd < r8 ? xcd * (q8 + 1) : r8 * (q8 + 1) + (xcd - r8) * q8) + lid;
  const int ntc = N >> 8;
  const int m0 = (wg / ntc) * 256;
  const int n0 = (wg % ntc) * 256;

  const int srow = tid >> 3;
  const int sch = (tid & 7) ^ ((tid >> 3) & 7);
  const f16* Ag = A + (size_t)(m0 + srow) * K + sch * 8;
  const f16* Bg = B + (size_t)(n0 + srow) * K + sch * 8;

  auto stage = [&](int bi, int k0, int h) {
    const int mat = h >> 1;
    const int rb = (h & 1) * 128;
    const f16* g = (mat ? Bg : Ag) + (size_t)rb * K + k0;
    f16* l = &smem[bi][mat][rb * 64 + tid * 8];
    async_load16(l, g);
    async_load16(l + 4096, g + (size_t)64 * K);
  };

  const int rx8 = lnm & 7;
  auto rdA = [&](const f16* Ab, int i, int ks) -> f16x8 {
    return *(const f16x8*)&Ab[(wm * 128 + i * 16 + lnm) * 64 +
                              (((ks * 4 + quad) ^ rx8) * 8)];
  };
  auto rdB = [&](const f16* Bb, int j, int ks) -> f16x8 {
    return *(const f16x8*)&Bb[(wn * 64 + j * 16 + lnm) * 64 +
                              (((ks * 4 + quad) ^ rx8) * 8)];
  };

  f32x4 acc[8][4] = {};

  const int NT = K >> 6;

  stage(0, 0, 0);
  stage(0, 0, 1);
  stage(0, 0, 2);
  stage(0, 0, 3);
  stage(1, 64, 0);
  asm volatile("s_waitcnt vmcnt(2)" ::: "memory");
  __builtin_amdgcn_s_barrier();

  for (int t = 0; t < NT; ++t) {
    const int bi = t & 1;
    const f16* Ab = smem[bi][0];
    const f16* Bb = smem[bi][1];
    const int k1 = (t + 1 < NT ? t + 1 : t) << 6;
    const int k2 = (t + 2 < NT ? t + 2 : t) << 6;

    f16x8 Ar[4][2], Br[2][2];

    // -------- phase 1: quadrant (mq0, nq0) --------
#pragma unroll
    for (int i = 0; i < 4; i++)
#pragma unroll
      for (int ks = 0; ks < 2; ks++) Ar[i][ks] = rdA(Ab, i, ks);
#pragma unroll
    for (int j = 0; j < 2; j++)
#pragma unroll
      for (int ks = 0; ks < 2; ks++) Br[j][ks] = rdB(Bb, j, ks);
    stage(bi ^ 1, k1, 1);
    __builtin_amdgcn_s_barrier();
    asm volatile("s_waitcnt lgkmcnt(0)" ::: "memory");
    __builtin_amdgcn_s_setprio(1);
#pragma unroll
    for (int i = 0; i < 4; i++)
#pragma unroll
      for (int j = 0; j < 2; j++)
#pragma unroll
        for (int ks = 0; ks < 2; ks++)
          acc[i][j] = __builtin_amdgcn_mfma_f32_16x16x32_f16(
              Ar[i][ks], Br[j][ks], acc[i][j], 0, 0, 0);
    __builtin_amdgcn_s_setprio(0);
    __builtin_amdgcn_s_barrier();

    // -------- phase 2: quadrant (mq0, nq1) --------
#pragma unroll
    for (int j = 0; j < 2; j++)
#pragma unroll
      for (int ks = 0; ks < 2; ks++) Br[j][ks] = rdB(Bb, 2 + j, ks);
    stage(bi ^ 1, k1, 2);
    __builtin_amdgcn_s_barrier();
    asm volatile("s_waitcnt lgkmcnt(0)" ::: "memory");
    __builtin_amdgcn_s_setprio(1);
#pragma unroll
    for (int i = 0; i < 4; i++)
#pragma unroll
      for (int j = 0; j < 2; j++)
#pragma unroll
        for (int ks = 0; ks < 2; ks++)
          acc[i][2 + j] = __builtin_amdgcn_mfma_f32_16x16x32_f16(
              Ar[i][ks], Br[j][ks], acc[i][2 + j], 0, 0, 0);
    __builtin_amdgcn_s_setprio(0);
    __builtin_amdgcn_s_barrier();

    // -------- phase 3: quadrant (mq1, nq1) --------
#pragma unroll
    for (int i = 0; i < 4; i++)
#pragma unroll
      for (int ks = 0; ks < 2; ks++) Ar[i][ks] = rdA(Ab, 4 + i, ks);
    stage(bi ^ 1, k1, 3);
    __builtin_amdgcn_s_barrier();
    asm volatile("s_waitcnt lgkmcnt(0)" ::: "memory");
    __builtin_amdgcn_s_setprio(1);
#pragma unroll
    for (int i = 0; i < 4; i++)
#pragma unroll
      for (int j = 0; j < 2; j++)
#pragma unroll
        for (int ks = 0; ks < 2; ks++)
          acc[4 + i][2 + j] = __builtin_amdgcn_mfma_f32_16x16x32_f16(
              Ar[i][ks], Br[j][ks], acc[4 + i][2 + j], 0, 0, 0);
    __builtin_amdgcn_s_setprio(0);
    __builtin_amdgcn_s_barrier();

    // -------- phase 4: quadrant (mq1, nq0) --------
#pragma unroll
    for (int j = 0; j < 2; j++)
#pragma unroll
      for (int ks = 0; ks < 2; ks++) Br[j][ks] = rdB(Bb, j, ks);
    stage(bi, k2, 0);
    __builtin_amdgcn_s_barrier();
    asm volatile("s_waitcnt lgkmcnt(0)" ::: "memory");
    __builtin_amdgcn_s_setprio(1);
#pragma unroll
    for (int i = 0; i < 4; i++)
#pragma unroll
      for (int j = 0; j < 2; j++)
#pragma unroll
        for (int ks = 0; ks < 2; ks++)
          acc[4 + i][j] = __builtin_amdgcn_mfma_f32_16x16x32_f16(
              Ar[i][ks], Br[j][ks], acc[4 + i][j], 0, 0, 0);
    __builtin_amdgcn_s_setprio(0);
    asm volatile("s_waitcnt vmcnt(2)" ::: "memory");
    __builtin_amdgcn_s_barrier();
  }

  asm volatile("s_waitcnt vmcnt(0)" ::: "memory");

  if constexpr (EPI == 0) {
    float* C = (float*)Cv;
#pragma unroll
    for (int i = 0; i < 8; i++)
#pragma unroll
      for (int r = 0; r < 4; r++) {
        float* crow = C + (size_t)(m0 + wm * 128 + i * 16 + quad * 4 + r) * N +
                      n0 + wn * 64 + lnm;
#pragma unroll
        for (int j = 0; j < 4; j++) crow[j * 16] = acc[i][j][r];
      }
  } else {
    // Fused RoPE + scale + f16 store. SCLQ = (1/sqrt(D)) * log2(e).
    f16* C = (f16*)Cv;
    const float SCLQ = 0.1275174280f;
#pragma unroll
    for (int i = 0; i < 8; i++)
#pragma unroll
      for (int r = 0; r < 4; r++) {
        const int m = m0 + wm * 128 + i * 16 + quad * 4 + r;
        const int t = m & (TT - 1);
#pragma unroll
        for (int j = 0; j < 4; j++) {
          const int col = n0 + wn * 64 + j * 16 + lnm;
          float v = acc[i][j][r];
          float u = __shfl_xor(v, 1, 64);
          const int fi = (col & (DD - 1)) >> 1;
          const float ct = cosb[t * (DD / 2) + fi];
          const float st2 = sinb[t * (DD / 2) + fi];
          const float o =
              (lnm & 1) ? (u * st2 + v * ct) : (v * ct - u * st2);
          C[(size_t)m * N + col] = (f16)(o * SCLQ);
        }
      }
  }
}

// ---------------------------------------------------------------------------
// MFMA NT GEMM 128x128 (m97 recipe), f16 OUTPUT (down-projection: the fp32
// intermediate + separate cvt dispatch are deleted; same rounding).
// ---------------------------------------------------------------------------
__global__ __launch_bounds__(256) void mla_gemm_mfma_h(
    const f16* __restrict__ A, const f16* __restrict__ B,
    f16* __restrict__ C, int M, int N, int K) {
  __shared__ f16 As[128 * 32];
  __shared__ f16 Bs[128 * 32];

  const int tid = threadIdx.x;
  const int lane = tid & 63;
  const int w = tid >> 6;
  const int lnm = lane & 15, quad = lane >> 4;
  const int wm = w >> 1, wn = w & 1;
  const int m0 = blockIdx.y * 128;
  const int n0 = blockIdx.x * 128;

  const int srow = tid >> 2;
  const int skoff = (tid & 3) * 8;

  f32x4 acc[4][4] = {};

  for (int k0 = 0; k0 < K; k0 += 32) {
    const f16* ag = A + (size_t)(m0 + srow) * K + k0 + skoff;
    const f16* bg = B + (size_t)(n0 + srow) * K + k0 + skoff;
    async_load16(&As[(size_t)tid * 8], ag);
    async_load16(&As[(size_t)(256 + tid) * 8], ag + (size_t)64 * K);
    async_load16(&Bs[(size_t)tid * 8], bg);
    async_load16(&Bs[(size_t)(256 + tid) * 8], bg + (size_t)64 * K);
    __syncthreads();

    f16x8 af[4], bf[4];
#pragma unroll
    for (int i = 0; i < 4; i++)
      af[i] = *(const f16x8*)&As[(wm * 64 + i * 16 + lnm) * 32 + quad * 8];
#pragma unroll
    for (int j = 0; j < 4; j++)
      bf[j] = *(const f16x8*)&Bs[(wn * 64 + j * 16 + lnm) * 32 + quad * 8];
#pragma unroll
    for (int i = 0; i < 4; i++)
#pragma unroll
      for (int j = 0; j < 4; j++)
        acc[i][j] = __builtin_amdgcn_mfma_f32_16x16x32_f16(af[i], bf[j],
                                                           acc[i][j], 0, 0, 0);
    __syncthreads();
  }

#pragma unroll
  for (int i = 0; i < 4; i++)
#pragma unroll
    for (int r = 0; r < 4; r++) {
      f16* crow = C + (size_t)(m0 + wm * 64 + i * 16 + quad * 4 + r) * N +
                  n0 + wn * 64 + lnm;
#pragma unroll
      for (int j = 0; j < 4; j++) crow[j * 16] = (f16)acc[i][j][r];
    }
}

// ---------------------------------------------------------------------------
// Up-projection GEMM (M=8192, N=256, K=512) with FUSED epilogues:
//   n0 == 0   (k-half): RoPE (interleaved pairs) + fragment-K scatter -> khp
//   n0 == 128 (v-half): fragment-V scatter (inverse sigma map)        -> vtp
// Replaces up-GEMM + rope_k + fragv and the kkvv fp32 round-trip.
// ---------------------------------------------------------------------------
__global__ __launch_bounds__(256) void mla_gemm_upkv(
    const f16* __restrict__ A, const f16* __restrict__ B,
    f16* __restrict__ khp, f16* __restrict__ vtp,
    const float* __restrict__ cosb, const float* __restrict__ sinb) {
  const int NN = 256, KK = 512;
  __shared__ f16 As[128 * 32];
  __shared__ f16 Bs[128 * 32];

  const int tid = threadIdx.x;
  const int lane = tid & 63;
  const int w = tid >> 6;
  const int lnm = lane & 15, quad = lane >> 4;
  const int wm = w >> 1, wn = w & 1;
  const int m0 = blockIdx.y * 128;
  const int n0 = blockIdx.x * 128;

  const int srow = tid >> 2;
  const int skoff = (tid & 3) * 8;

  f32x4 acc[4][4] = {};

  for (int k0 = 0; k0 < KK; k0 += 32) {
    const f16* ag = A + (size_t)(m0 + srow) * KK + k0 + skoff;
    const f16* bg = B + (size_t)(n0 + srow) * KK + k0 + skoff;
    async_load16(&As[(size_t)tid * 8], ag);
    async_load16(&As[(size_t)(256 + tid) * 8], ag + (size_t)64 * KK);
    async_load16(&Bs[(size_t)tid * 8], bg);
    async_load16(&Bs[(size_t)(256 + tid) * 8], bg + (size_t)64 * KK);
    __syncthreads();

    f16x8 af[4], bf[4];
#pragma unroll
    for (int i = 0; i < 4; i++)
      af[i] = *(const f16x8*)&As[(wm * 64 + i * 16 + lnm) * 32 + quad * 8];
#pragma unroll
    for (int j = 0; j < 4; j++)
      bf[j] = *(const f16x8*)&Bs[(wn * 64 + j * 16 + lnm) * 32 + quad * 8];
#pragma unroll
    for (int i = 0; i < 4; i++)
#pragma unroll
      for (int j = 0; j < 4; j++)
        acc[i][j] = __builtin_amdgcn_mfma_f32_16x16x32_f16(af[i], bf[j],
                                                           acc[i][j], 0, 0, 0);
    __syncthreads();
  }

  const bool isv = (n0 != 0);  // block-uniform
#pragma unroll
  for (int i = 0; i < 4; i++)
#pragma unroll
    for (int r = 0; r < 4; r++) {
      const int m = m0 + wm * 64 + i * 16 + quad * 4 + r;
      const int b = m >> 11, t = m & (TT - 1);
      const int st = t >> 6, s = t & 63;
      if (!isv) {
        // k-half: RoPE pairs (n even/odd adjacent = lnm^1 lanes), then
        // khp[b][st][cq=n>>3][s][e=n&7].
        f16* tb = khp + (size_t)(b * 32 + st) * 8192;
#pragma unroll
        for (int j = 0; j < 4; j++) {
          const int n = wn * 64 + j * 16 + lnm;  // 0..127
          float v = acc[i][j][r];
          float u = __shfl_xor(v, 1, 64);
          const int fi = n >> 1;
          const float ct = cosb[t * 64 + fi];
          const float st2 = sinb[t * 64 + fi];
          const float o = (lnm & 1) ? (u * st2 + v * ct) : (v * ct - u * st2);
          tb[(n >> 3) * 512 + s * 8 + (n & 7)] = (f16)o;
        }
      } else {
        // v-half: vtp[b][st][cq2][d][e] with sigma(cq2,e)=s inverse map.
        const int cq2 = ((s >> 5) << 2) | ((s >> 2) & 3);
        const int e = (((s >> 4) & 1) << 2) | (s & 3);
        f16* tb = vtp + (size_t)(b * 32 + st) * 8192 + cq2 * 1024 + e;
#pragma unroll
        for (int j = 0; j < 4; j++) {
          const int d = wn * 64 + j * 16 + lnm;  // 0..127
          tb[d * 8] = (f16)acc[i][j][r];
        }
      }
    }
}

// ---------------------------------------------------------------------------
// ONE fp32->f16 conversion kernel for all six inputs. The six destinations
// are CONTIGUOUS in workspace (xh | wqh | wdownh | wkvuph(k|v) | woh), so
// this is a single contiguous f16 store stream; source picked by range.
// ---------------------------------------------------------------------------
#define CVT_C0 ((size_t)BB * TT * CC)            // x
#define CVT_C1 (CVT_C0 + (size_t)CC * CC)        // wq
#define CVT_C2 (CVT_C1 + (size_t)LL * CC)        // wkv_down
#define CVT_C3 (CVT_C2 + (size_t)DD * LL)        // wk_up
#define CVT_C4 (CVT_C3 + (size_t)DD * LL)        // wv_up
#define CVT_C5 (CVT_C4 + (size_t)CC * CC)        // wo
__global__ __launch_bounds__(256) void mla_cvt_all(
    const float* __restrict__ x, const float* __restrict__ wq,
    const float* __restrict__ wdn, const float* __restrict__ wku,
    const float* __restrict__ wvu, const float* __restrict__ wo,
    f16* __restrict__ dst) {
  size_t i4 = (size_t)blockIdx.x * 256 + threadIdx.x;
  if (i4 >= CVT_C5 / 4) return;
  size_t e = i4 * 4;
  const float* src;
  size_t off;
  if (e < CVT_C0) { src = x; off = e; }
  else if (e < CVT_C1) { src = wq; off = e - CVT_C0; }
  else if (e < CVT_C2) { src = wdn; off = e - CVT_C1; }
  else if (e < CVT_C3) { src = wku; off = e - CVT_C2; }
  else if (e < CVT_C4) { src = wvu; off = e - CVT_C3; }
  else { src = wo; off = e - CVT_C4; }
  float4 v = *(const float4*)&src[off];
  f16x4 r = {(f16)v.x, (f16)v.y, (f16)v.z, (f16)v.w};
  *(f16x4*)(dst + e) = r;
}

// ---------------------------------------------------------------------------
// Block-cooperative MFMA flash attention v8: fragment-ready LDS layouts
// (R7) + one-tile software pipeline. S(t) persists across the iteration:
// each iteration runs softmax(t) -> QK(t+1) -> PV(t); QK(t+1) is 16
// imm-offset b128 reads + 16 MFMA, independent of softmax/PV -> scheduler
// fills the softmax dependency chain. Buffers: iteration t writes
// Ks[cur]/Vs[nxt] (DMA), reads Ks[nxt]/Vs[cur]; one barrier per tile.
// ---------------------------------------------------------------------------
__global__ __launch_bounds__(512, 2) void mla_flash2(
    const f16* __restrict__ qh, const f16* __restrict__ khp,
    const f16* __restrict__ vtp, f16* __restrict__ y) {
  __shared__ __align__(16) f16 Ks[2][8192];  // [cq 0..15][s 0..63][e 0..7]
  __shared__ __align__(16) f16 Vs[2][8192];  // [cq2 0..7][d 0..127][e 0..7]

  const int tid = threadIdx.x;
  const int lane = tid & 63;
  const int w = tid >> 6;  // 0..7
  const int lnm = lane & 15, quad = lane >> 4;

  const int bid = blockIdx.x;
  const int qt = (TT / 256 - 1) - (bid >> 6);  // LPT: longest q-tiles first
  const int bh = bid & 63;
  const int b = bh >> 4, h = bh & 15;
  const int q0b = qt * 256;
  const int q0 = q0b + w * 32;  // this wave's 32 q-rows

  // Q B-frags (global, once per block)
  f16x8 qf[2][4];
#pragma unroll
  for (int qnb = 0; qnb < 2; qnb++) {
    const f16* qrow =
        qh + ((size_t)(b * TT + q0 + qnb * 16 + lnm) * HH + h) * DD;
#pragma unroll
    for (int c = 0; c < 4; c++)
      qf[qnb][c] = *(const f16x8*)(qrow + c * 32 + quad * 8);
  }

  f32x4 O[2][8] = {};
  f32x4 S[2][4];  // pipelined QK result: holds tile t during iteration t
  float l_acc[2] = {0.f, 0.f};

  const int nst = (q0b + 256) / 64;  // 4*qt + 4
  const int wmax = q0 + 31;
  const f16* kpb = khp + (size_t)b * 32 * 8192;
  const f16* vpb = vtp + (size_t)b * 32 * 8192;

  auto stageK = [&](int buf, int st) {
    const f16* g = kpb + (size_t)st * 8192 + (size_t)tid * 8;
    async_load16(&Ks[buf][(size_t)tid * 8], g);
    async_load16(&Ks[buf][(size_t)(512 + tid) * 8], g + 4096);
  };
  auto stageV = [&](int buf, int st) {
    const f16* g = vpb + (size_t)st * 8192 + (size_t)tid * 8;
    async_load16(&Vs[buf][(size_t)tid * 8], g);
    async_load16(&Vs[buf][(size_t)(512 + tid) * 8], g + 4096);
  };

  // Per-lane fragment base offsets (f16 units).
  const int kbo = quad * 512 + lnm * 8;   // + c*2048 + sb*128
  const int vbo = quad * 1024 + lnm * 8;  // + c*4096 + db*128

  auto qk = [&](const f16* Kbuf) {
    const f16* kl = Kbuf + kbo;
    const f32x4 z = {0.f, 0.f, 0.f, 0.f};
#pragma unroll
    for (int qnb = 0; qnb < 2; qnb++)
#pragma unroll
      for (int sb = 0; sb < 4; sb++) S[qnb][sb] = z;
#pragma unroll
    for (int sb = 0; sb < 4; sb++)
#pragma unroll
      for (int c = 0; c < 4; c++) {
        f16x8 ka = *(const f16x8*)&kl[c * 2048 + sb * 128];
        S[0][sb] = __builtin_amdgcn_mfma_f32_16x16x32_f16(ka, qf[0][c],
                                                          S[0][sb], 0, 0, 0);
        S[1][sb] = __builtin_amdgcn_mfma_f32_16x16x32_f16(ka, qf[1][c],
                                                          S[1][sb], 0, 0, 0);
      }
  };

  // Prologue: tile0 K+V staged; K(1) in flight; S = QK(0).
  stageK(0, 0);
  stageV(0, 0);
  __syncthreads();  // tile0 landed
  stageK(1, 1);     // nst >= 4 always
  qk(Ks[0]);
  __syncthreads();  // all waves done reading Ks[0]; K(1) landed

  for (int st = 0; st < nst; st++) {
    const int cur = st & 1, nxt = cur ^ 1;
    const int s0 = st * 64;
    // K(t+2) -> Ks[cur] (all waves consumed it for QK(t) before last
    // barrier); V(t+1) -> Vs[nxt] (consumed by PV(t-1)). Clamped tail
    // stages write data that is never read (QK guard below).
    stageK(cur, st + 2 < nst ? st + 2 : nst - 1);
    stageV(nxt, st + 1 < nst ? st + 1 : nst - 1);

    const bool act = (s0 <= wmax);  // wave-uniform
    f16x8 P8[2][2];
    if (act) {
      // softmax(t): P8 = exp2(S) (+causal mask), row-sums.
      const bool domask = (s0 + 63 > q0);
      if (!domask) {
#pragma unroll
        for (int qnb = 0; qnb < 2; qnb++) {
          float lp = 0.f;
#pragma unroll
          for (int sb = 0; sb < 4; sb++)
#pragma unroll
            for (int j = 0; j < 4; j++) {
              float p = __builtin_amdgcn_exp2f(S[qnb][sb][j]);
              lp += p;
              P8[qnb][sb >> 1][(sb & 1) * 4 + j] = (f16)p;
            }
          l_acc[qnb] += lp;
        }
      } else {
#pragma unroll
        for (int qnb = 0; qnb < 2; qnb++) {
          const int m_abs = q0 + qnb * 16 + lnm;
          float lp = 0.f;
#pragma unroll
          for (int sb = 0; sb < 4; sb++) {
            const int srow = s0 + sb * 16 + quad * 4;
#pragma unroll
            for (int j = 0; j < 4; j++) {
              float p = __builtin_amdgcn_exp2f(S[qnb][sb][j]);
              if (srow + j > m_abs) p = 0.f;
              lp += p;
              P8[qnb][sb >> 1][(sb & 1) * 4 + j] = (f16)p;
            }
          }
          l_acc[qnb] += lp;
        }
      }
    }

    __builtin_amdgcn_s_setprio(1);
    // QK(t+1) from Ks[nxt] -- independent of softmax(t)/PV(t).
    if ((st + 1) * 64 <= wmax) qk(Ks[nxt]);

    if (act) {
      // PV(t) from Vs[cur]: 16 imm-offset b128; V frag shares P8's k->s map.
      const f16* vl = &Vs[cur][vbo];
#pragma unroll
      for (int c = 0; c < 2; c++)
#pragma unroll
        for (int db = 0; db < 8; db++) {
          f16x8 vb = *(const f16x8*)&vl[c * 4096 + db * 128];
          O[0][db] = __builtin_amdgcn_mfma_f32_16x16x32_f16(P8[0][c], vb,
                                                            O[0][db], 0, 0, 0);
          O[1][db] = __builtin_amdgcn_mfma_f32_16x16x32_f16(P8[1][c], vb,
                                                            O[1][db], 0, 0, 0);
        }
    }
    __builtin_amdgcn_s_setprio(0);
    __syncthreads();  // drains this iter's DMA + separates buffer reuse
  }

  // Row-sums across quads
#pragma unroll
  for (int qnb = 0; qnb < 2; qnb++) {
    float l = l_acc[qnb];
    l += __shfl_xor(l, 16, 64);
    l += __shfl_xor(l, 32, 64);
    l_acc[qnb] = l;
  }

  // Epilogue: y = O / l (f16)
#pragma unroll
  for (int qnb = 0; qnb < 2; qnb++) {
    float linv[4];
#pragma unroll
    for (int r = 0; r < 4; r++)
      linv[r] = 1.f / __shfl(l_acc[qnb], quad * 4 + r, 64);
#pragma unroll
    for (int db = 0; db < 8; db++)
#pragma unroll
      for (int r = 0; r < 4; r++) {
        size_t off =
            ((size_t)(b * TT + q0 + qnb * 16 + quad * 4 + r) * HH + h) * DD +
            db * 16 + lnm;
        y[off] = (f16)(O[qnb][db][r] * linv[r]);
      }
  }
}

// ---------------------------------------------------------------------------
extern "C" void kernel_launch(void* const* d_in, const int* in_sizes, int n_in,
                              void* d_out, int out_size, void* d_ws,
                              size_t ws_size, hipStream_t stream) {
  const float* x      = (const float*)d_in[0];
  const float* fcos   = (const float*)d_in[1];
  const float* fsin   = (const float*)d_in[2];
  const float* wq     = (const float*)d_in[3];
  const float* wkv_dn = (const float*)d_in[4];
  const float* wk_up  = (const float*)d_in[5];
  const float* wv_up  = (const float*)d_in[6];
  const float* wo     = (const float*)d_in[7];
  float* out = (float*)d_out;

  const int M = BB * TT;  // 8192

  // Workspace layout. f16 conversion destinations MUST stay contiguous in
  // the order xh|wqh|wdownh|wkvuph|woh (mla_cvt_all single-stream store).
  float* ws = (float*)d_ws;
  float* qbuf   = ws;                              // 64 MB slot: qh + yh
  f16*   xh     = (f16*)(qbuf + (size_t)M * CC);   // 32 MB
  f16*   wqh    = xh + (size_t)M * CC;             // 8 MB
  f16*   wdownh = wqh + (size_t)CC * CC;           // 2 MB
  f16*   wkvuph = wdownh + (size_t)LL * CC;        // 256 KB (k rows | v rows)
  f16*   woh    = wkvuph + (size_t)256 * LL;       // 8 MB
  f16*   kvh    = woh + (size_t)CC * CC;           // 8 MB (down-proj, f16)
  f16*   khp    = kvh + (size_t)M * LL;            // 2 MB (fragment K)
  f16*   vtp    = khp + (size_t)M * DD;            // 2 MB (fragment V)
  f16*   qh     = (f16*)qbuf;                      // 32 MB
  f16*   yh     = qh + (size_t)M * CC;             // 32 MB

  // 1) all fp32 -> f16 conversions in one dispatch
  {
    size_t total4 = CVT_C5 / 4;
    mla_cvt_all<<<(unsigned)((total4 + 255) / 256), dim3(256), 0, stream>>>(
        x, wq, wkv_dn, wk_up, wv_up, wo, xh);
  }

  // 2) q = rope(x @ wq^T) (8-phase 256^2, fused epilogue -> f16 qh)
  mla_gemm_256<1><<<dim3((M / 256) * (CC / 256)), dim3(512), 0, stream>>>(
      xh, wqh, qh, M, CC, CC, fcos, fsin);

  // 3) kvh = (x @ wdown^T) as f16 directly (128^2, N=512 -> 256 wgs)
  mla_gemm_mfma_h<<<dim3(LL / 128, M / 128), dim3(256), 0, stream>>>(
      xh, wdownh, kvh, M, LL, CC);

  // 4) fused up-projection: k-half -> rope -> fragment khp;
  //    v-half -> fragment vtp (one dispatch, no fp32 round-trip)
  mla_gemm_upkv<<<dim3(2, M / 128), dim3(256), 0, stream>>>(
      kvh, wkvuph, khp, vtp, fcos, fsin);

  // 5) flash attention v8 -> yh (f16). 512 blocks x 512 threads, LPT order.
  mla_flash2<<<dim3(BB * HH * (TT / 256)), dim3(512), 0, stream>>>(
      qh, khp, vtp, yh);

  // 6) out = y @ wo^T (8-phase 256^2)
  mla_gemm_256<0><<<dim3((M / 256) * (CC / 256)), dim3(512), 0, stream>>>(
      yh, woh, out, M, CC, CC, nullptr, nullptr);
}

// Round 9
// 417.307 us; speedup vs baseline: 1.3803x; 1.0354x over previous
//
#include <hip/hip_runtime.h>
#include <hip/hip_bf16.h>
#include <cstddef>

// Problem constants
#define BB 4
#define TT 2048
#define CC 2048
#define HH 16
#define DD 128
#define LL 512

typedef _Float16 f16;
typedef f16 f16x2 __attribute__((ext_vector_type(2)));
typedef f16 f16x4 __attribute__((ext_vector_type(4)));
typedef f16 f16x8 __attribute__((ext_vector_type(8)));
typedef float f32x4 __attribute__((ext_vector_type(4)));

// ---------------------------------------------------------------------------
// async global->LDS, 16 B per lane (global_load_lds_dwordx4).
// ---------------------------------------------------------------------------
__device__ __forceinline__ void async_load16(void* lptr, const void* gptr) {
  __builtin_amdgcn_global_load_lds(
      (const __attribute__((address_space(1))) unsigned int*)gptr,
      (__attribute__((address_space(3))) unsigned int*)lptr, 16, 0, 0);
}

// ---------------------------------------------------------------------------
// 256x256 8-phase MFMA NT GEMM (f16 in): C[m,n] = sum_k A[m,k]B[n,k]
// m201-style template. EPI=0: fp32 store. EPI=1: fused RoPE+scale+f16 store
// (q path; scale includes log2(e) -- flash uses exp2).
// ---------------------------------------------------------------------------
template <int EPI>
__global__ __launch_bounds__(512, 2) void mla_gemm_256(
    const f16* __restrict__ A, const f16* __restrict__ B,
    void* __restrict__ Cv, int M, int N, int K,
    const float* __restrict__ cosb, const float* __restrict__ sinb) {
  __shared__ __align__(16) f16 smem[2][2][256 * 64];

  const int tid = threadIdx.x;       // 0..511
  const int lane = tid & 63;
  const int w = tid >> 6;            // 0..7
  const int lnm = lane & 15, quad = lane >> 4;
  const int wm = w >> 2, wn = w & 3; // 2 x 4 wave grid; wave tile 128x64

  // Bijective XCD-aware block swizzle (m204 variant).
  const int nwg = gridDim.x;
  const int bid0 = blockIdx.x;
  const int q8 = nwg >> 3, r8 = nwg & 7;
  const int xcd = bid0 & 7, lid = bid0 >> 3;
  const int wg =
      (xcd < r8 ? xcd * (q8 + 1) : r8 * (q8 + 1) + (xcd - r8) * q8) + lid;
  const int ntc = N >> 8;
  const int m0 = (wg / ntc) * 256;
  const int n0 = (wg % ntc) * 256;

  const int srow = tid >> 3;
  const int sch = (tid & 7) ^ ((tid >> 3) & 7);
  const f16* Ag = A + (size_t)(m0 + srow) * K + sch * 8;
  const f16* Bg = B + (size_t)(n0 + srow) * K + sch * 8;

  auto stage = [&](int bi, int k0, int h) {
    const int mat = h >> 1;
    const int rb = (h & 1) * 128;
    const f16* g = (mat ? Bg : Ag) + (size_t)rb * K + k0;
    f16* l = &smem[bi][mat][rb * 64 + tid * 8];
    async_load16(l, g);
    async_load16(l + 4096, g + (size_t)64 * K);
  };

  const int rx8 = lnm & 7;
  auto rdA = [&](const f16* Ab, int i, int ks) -> f16x8 {
    return *(const f16x8*)&Ab[(wm * 128 + i * 16 + lnm) * 64 +
                              (((ks * 4 + quad) ^ rx8) * 8)];
  };
  auto rdB = [&](const f16* Bb, int j, int ks) -> f16x8 {
    return *(const f16x8*)&Bb[(wn * 64 + j * 16 + lnm) * 64 +
                              (((ks * 4 + quad) ^ rx8) * 8)];
  };

  f32x4 acc[8][4] = {};

  const int NT = K >> 6;

  stage(0, 0, 0);
  stage(0, 0, 1);
  stage(0, 0, 2);
  stage(0, 0, 3);
  stage(1, 64, 0);
  asm volatile("s_waitcnt vmcnt(2)" ::: "memory");
  __builtin_amdgcn_s_barrier();

  for (int t = 0; t < NT; ++t) {
    const int bi = t & 1;
    const f16* Ab = smem[bi][0];
    const f16* Bb = smem[bi][1];
    const int k1 = (t + 1 < NT ? t + 1 : t) << 6;
    const int k2 = (t + 2 < NT ? t + 2 : t) << 6;

    f16x8 Ar[4][2], Br[2][2];

    // -------- phase 1: quadrant (mq0, nq0) --------
#pragma unroll
    for (int i = 0; i < 4; i++)
#pragma unroll
      for (int ks = 0; ks < 2; ks++) Ar[i][ks] = rdA(Ab, i, ks);
#pragma unroll
    for (int j = 0; j < 2; j++)
#pragma unroll
      for (int ks = 0; ks < 2; ks++) Br[j][ks] = rdB(Bb, j, ks);
    stage(bi ^ 1, k1, 1);
    __builtin_amdgcn_s_barrier();
    asm volatile("s_waitcnt lgkmcnt(0)" ::: "memory");
    __builtin_amdgcn_s_setprio(1);
#pragma unroll
    for (int i = 0; i < 4; i++)
#pragma unroll
      for (int j = 0; j < 2; j++)
#pragma unroll
        for (int ks = 0; ks < 2; ks++)
          acc[i][j] = __builtin_amdgcn_mfma_f32_16x16x32_f16(
              Ar[i][ks], Br[j][ks], acc[i][j], 0, 0, 0);
    __builtin_amdgcn_s_setprio(0);
    __builtin_amdgcn_s_barrier();

    // -------- phase 2: quadrant (mq0, nq1) --------
#pragma unroll
    for (int j = 0; j < 2; j++)
#pragma unroll
      for (int ks = 0; ks < 2; ks++) Br[j][ks] = rdB(Bb, 2 + j, ks);
    stage(bi ^ 1, k1, 2);
    __builtin_amdgcn_s_barrier();
    asm volatile("s_waitcnt lgkmcnt(0)" ::: "memory");
    __builtin_amdgcn_s_setprio(1);
#pragma unroll
    for (int i = 0; i < 4; i++)
#pragma unroll
      for (int j = 0; j < 2; j++)
#pragma unroll
        for (int ks = 0; ks < 2; ks++)
          acc[i][2 + j] = __builtin_amdgcn_mfma_f32_16x16x32_f16(
              Ar[i][ks], Br[j][ks], acc[i][2 + j], 0, 0, 0);
    __builtin_amdgcn_s_setprio(0);
    __builtin_amdgcn_s_barrier();

    // -------- phase 3: quadrant (mq1, nq1) --------
#pragma unroll
    for (int i = 0; i < 4; i++)
#pragma unroll
      for (int ks = 0; ks < 2; ks++) Ar[i][ks] = rdA(Ab, 4 + i, ks);
    stage(bi ^ 1, k1, 3);
    __builtin_amdgcn_s_barrier();
    asm volatile("s_waitcnt lgkmcnt(0)" ::: "memory");
    __builtin_amdgcn_s_setprio(1);
#pragma unroll
    for (int i = 0; i < 4; i++)
#pragma unroll
      for (int j = 0; j < 2; j++)
#pragma unroll
        for (int ks = 0; ks < 2; ks++)
          acc[4 + i][2 + j] = __builtin_amdgcn_mfma_f32_16x16x32_f16(
              Ar[i][ks], Br[j][ks], acc[4 + i][2 + j], 0, 0, 0);
    __builtin_amdgcn_s_setprio(0);
    __builtin_amdgcn_s_barrier();

    // -------- phase 4: quadrant (mq1, nq0) --------
#pragma unroll
    for (int j = 0; j < 2; j++)
#pragma unroll
      for (int ks = 0; ks < 2; ks++) Br[j][ks] = rdB(Bb, j, ks);
    stage(bi, k2, 0);
    __builtin_amdgcn_s_barrier();
    asm volatile("s_waitcnt lgkmcnt(0)" ::: "memory");
    __builtin_amdgcn_s_setprio(1);
#pragma unroll
    for (int i = 0; i < 4; i++)
#pragma unroll
      for (int j = 0; j < 2; j++)
#pragma unroll
        for (int ks = 0; ks < 2; ks++)
          acc[4 + i][j] = __builtin_amdgcn_mfma_f32_16x16x32_f16(
              Ar[i][ks], Br[j][ks], acc[4 + i][j], 0, 0, 0);
    __builtin_amdgcn_s_setprio(0);
    asm volatile("s_waitcnt vmcnt(2)" ::: "memory");
    __builtin_amdgcn_s_barrier();
  }

  asm volatile("s_waitcnt vmcnt(0)" ::: "memory");

  if constexpr (EPI == 0) {
    float* C = (float*)Cv;
#pragma unroll
    for (int i = 0; i < 8; i++)
#pragma unroll
      for (int r = 0; r < 4; r++) {
        float* crow = C + (size_t)(m0 + wm * 128 + i * 16 + quad * 4 + r) * N +
                      n0 + wn * 64 + lnm;
#pragma unroll
        for (int j = 0; j < 4; j++) crow[j * 16] = acc[i][j][r];
      }
  } else {
    // Fused RoPE + scale + f16 store. SCLQ = (1/sqrt(D)) * log2(e).
    f16* C = (f16*)Cv;
    const float SCLQ = 0.1275174280f;
#pragma unroll
    for (int i = 0; i < 8; i++)
#pragma unroll
      for (int r = 0; r < 4; r++) {
        const int m = m0 + wm * 128 + i * 16 + quad * 4 + r;
        const int t = m & (TT - 1);
#pragma unroll
        for (int j = 0; j < 4; j++) {
          const int col = n0 + wn * 64 + j * 16 + lnm;
          float v = acc[i][j][r];
          float u = __shfl_xor(v, 1, 64);
          const int fi = (col & (DD - 1)) >> 1;
          const float ct = cosb[t * (DD / 2) + fi];
          const float st2 = sinb[t * (DD / 2) + fi];
          const float o =
              (lnm & 1) ? (u * st2 + v * ct) : (v * ct - u * st2);
          C[(size_t)m * N + col] = (f16)(o * SCLQ);
        }
      }
  }
}

// ---------------------------------------------------------------------------
// MFMA NT GEMM 128x128 (m97 recipe), f16 OUTPUT (down-projection).
// ---------------------------------------------------------------------------
__global__ __launch_bounds__(256) void mla_gemm_mfma_h(
    const f16* __restrict__ A, const f16* __restrict__ B,
    f16* __restrict__ C, int M, int N, int K) {
  __shared__ f16 As[128 * 32];
  __shared__ f16 Bs[128 * 32];

  const int tid = threadIdx.x;
  const int lane = tid & 63;
  const int w = tid >> 6;
  const int lnm = lane & 15, quad = lane >> 4;
  const int wm = w >> 1, wn = w & 1;
  const int m0 = blockIdx.y * 128;
  const int n0 = blockIdx.x * 128;

  const int srow = tid >> 2;
  const int skoff = (tid & 3) * 8;

  f32x4 acc[4][4] = {};

  for (int k0 = 0; k0 < K; k0 += 32) {
    const f16* ag = A + (size_t)(m0 + srow) * K + k0 + skoff;
    const f16* bg = B + (size_t)(n0 + srow) * K + k0 + skoff;
    async_load16(&As[(size_t)tid * 8], ag);
    async_load16(&As[(size_t)(256 + tid) * 8], ag + (size_t)64 * K);
    async_load16(&Bs[(size_t)tid * 8], bg);
    async_load16(&Bs[(size_t)(256 + tid) * 8], bg + (size_t)64 * K);
    __syncthreads();

    f16x8 af[4], bf[4];
#pragma unroll
    for (int i = 0; i < 4; i++)
      af[i] = *(const f16x8*)&As[(wm * 64 + i * 16 + lnm) * 32 + quad * 8];
#pragma unroll
    for (int j = 0; j < 4; j++)
      bf[j] = *(const f16x8*)&Bs[(wn * 64 + j * 16 + lnm) * 32 + quad * 8];
#pragma unroll
    for (int i = 0; i < 4; i++)
#pragma unroll
      for (int j = 0; j < 4; j++)
        acc[i][j] = __builtin_amdgcn_mfma_f32_16x16x32_f16(af[i], bf[j],
                                                           acc[i][j], 0, 0, 0);
    __syncthreads();
  }

#pragma unroll
  for (int i = 0; i < 4; i++)
#pragma unroll
    for (int r = 0; r < 4; r++) {
      f16* crow = C + (size_t)(m0 + wm * 64 + i * 16 + quad * 4 + r) * N +
                  n0 + wn * 64 + lnm;
#pragma unroll
      for (int j = 0; j < 4; j++) crow[j * 16] = (f16)acc[i][j][r];
    }
}

// ---------------------------------------------------------------------------
// Up-projection GEMM (M=8192, N=256, K=512) with FUSED epilogues:
//   n0 == 0   (k-half): RoPE (interleaved pairs) + fragment-K scatter -> khp
//   n0 == 128 (v-half): fragment-V scatter (inverse sigma map)        -> vtp
// ---------------------------------------------------------------------------
__global__ __launch_bounds__(256) void mla_gemm_upkv(
    const f16* __restrict__ A, const f16* __restrict__ B,
    f16* __restrict__ khp, f16* __restrict__ vtp,
    const float* __restrict__ cosb, const float* __restrict__ sinb) {
  const int NN = 256, KK = 512;
  (void)NN;
  __shared__ f16 As[128 * 32];
  __shared__ f16 Bs[128 * 32];

  const int tid = threadIdx.x;
  const int lane = tid & 63;
  const int w = tid >> 6;
  const int lnm = lane & 15, quad = lane >> 4;
  const int wm = w >> 1, wn = w & 1;
  const int m0 = blockIdx.y * 128;
  const int n0 = blockIdx.x * 128;

  const int srow = tid >> 2;
  const int skoff = (tid & 3) * 8;

  f32x4 acc[4][4] = {};

  for (int k0 = 0; k0 < KK; k0 += 32) {
    const f16* ag = A + (size_t)(m0 + srow) * KK + k0 + skoff;
    const f16* bg = B + (size_t)(n0 + srow) * KK + k0 + skoff;
    async_load16(&As[(size_t)tid * 8], ag);
    async_load16(&As[(size_t)(256 + tid) * 8], ag + (size_t)64 * KK);
    async_load16(&Bs[(size_t)tid * 8], bg);
    async_load16(&Bs[(size_t)(256 + tid) * 8], bg + (size_t)64 * KK);
    __syncthreads();

    f16x8 af[4], bf[4];
#pragma unroll
    for (int i = 0; i < 4; i++)
      af[i] = *(const f16x8*)&As[(wm * 64 + i * 16 + lnm) * 32 + quad * 8];
#pragma unroll
    for (int j = 0; j < 4; j++)
      bf[j] = *(const f16x8*)&Bs[(wn * 64 + j * 16 + lnm) * 32 + quad * 8];
#pragma unroll
    for (int i = 0; i < 4; i++)
#pragma unroll
      for (int j = 0; j < 4; j++)
        acc[i][j] = __builtin_amdgcn_mfma_f32_16x16x32_f16(af[i], bf[j],
                                                           acc[i][j], 0, 0, 0);
    __syncthreads();
  }

  const bool isv = (n0 != 0);  // block-uniform
#pragma unroll
  for (int i = 0; i < 4; i++)
#pragma unroll
    for (int r = 0; r < 4; r++) {
      const int m = m0 + wm * 64 + i * 16 + quad * 4 + r;
      const int b = m >> 11, t = m & (TT - 1);
      const int st = t >> 6, s = t & 63;
      if (!isv) {
        // k-half: RoPE pairs, then khp[b][st][cq=n>>3][s][e=n&7].
        f16* tb = khp + (size_t)(b * 32 + st) * 8192;
#pragma unroll
        for (int j = 0; j < 4; j++) {
          const int n = wn * 64 + j * 16 + lnm;  // 0..127
          float v = acc[i][j][r];
          float u = __shfl_xor(v, 1, 64);
          const int fi = n >> 1;
          const float ct = cosb[t * 64 + fi];
          const float st2 = sinb[t * 64 + fi];
          const float o = (lnm & 1) ? (u * st2 + v * ct) : (v * ct - u * st2);
          tb[(n >> 3) * 512 + s * 8 + (n & 7)] = (f16)o;
        }
      } else {
        // v-half: vtp[b][st][cq2][d][e] with sigma(cq2,e)=s inverse map.
        const int cq2 = ((s >> 5) << 2) | ((s >> 2) & 3);
        const int e = (((s >> 4) & 1) << 2) | (s & 3);
        f16* tb = vtp + (size_t)(b * 32 + st) * 8192 + cq2 * 1024 + e;
#pragma unroll
        for (int j = 0; j < 4; j++) {
          const int d = wn * 64 + j * 16 + lnm;  // 0..127
          tb[d * 8] = (f16)acc[i][j][r];
        }
      }
    }
}

// ---------------------------------------------------------------------------
// ONE fp32->f16 conversion kernel for all six inputs (contiguous dsts).
// ---------------------------------------------------------------------------
#define CVT_C0 ((size_t)BB * TT * CC)            // x
#define CVT_C1 (CVT_C0 + (size_t)CC * CC)        // wq
#define CVT_C2 (CVT_C1 + (size_t)LL * CC)        // wkv_down
#define CVT_C3 (CVT_C2 + (size_t)DD * LL)        // wk_up
#define CVT_C4 (CVT_C3 + (size_t)DD * LL)        // wv_up
#define CVT_C5 (CVT_C4 + (size_t)CC * CC)        // wo
__global__ __launch_bounds__(256) void mla_cvt_all(
    const float* __restrict__ x, const float* __restrict__ wq,
    const float* __restrict__ wdn, const float* __restrict__ wku,
    const float* __restrict__ wvu, const float* __restrict__ wo,
    f16* __restrict__ dst) {
  size_t i4 = (size_t)blockIdx.x * 256 + threadIdx.x;
  if (i4 >= CVT_C5 / 4) return;
  size_t e = i4 * 4;
  const float* src;
  size_t off;
  if (e < CVT_C0) { src = x; off = e; }
  else if (e < CVT_C1) { src = wq; off = e - CVT_C0; }
  else if (e < CVT_C2) { src = wdn; off = e - CVT_C1; }
  else if (e < CVT_C3) { src = wku; off = e - CVT_C2; }
  else if (e < CVT_C4) { src = wvu; off = e - CVT_C3; }
  else { src = wo; off = e - CVT_C4; }
  float4 v = *(const float4*)&src[off];
  f16x4 r = {(f16)v.x, (f16)v.y, (f16)v.z, (f16)v.w};
  *(f16x4*)(dst + e) = r;
}

// ---------------------------------------------------------------------------
// Block-cooperative MFMA flash attention v9: OCCUPANCY re-shape.
// R8's 512-thread block used 164 unified regs/wave (100 VGPR + 64 AGPR) ->
// only 1 block/CU (2 waves/SIMD): no pipe above ~35%. v9: 256-thread blocks
// (4 waves x 32 q-rows = 128-row q-tile), LDS cut to 48 KB (K double-buffer,
// V single-buffer + 2nd barrier) -> 3 blocks/CU by LDS, launch_bounds(256,3)
// allows ~170 regs so the 148-reg body fits spill-free -> 12 waves/CU.
// Three independent blocks per CU overlap softmax(VALU) / MFMA / staging.
// Barrier schedule per tile t:
//   stageK(t+1) -> QK(t)+softmax(t) -> sync[drain: V(t),K(t+1) landed]
//   -> PV(t) -> sync[Vs reads done] -> stageV(t+1)
// V(t+1) DMA covered by next tile's QK+softmax; all barriers wave-uniform.
// ---------------------------------------------------------------------------
__global__ __launch_bounds__(256, 3) void mla_flash2(
    const f16* __restrict__ qh, const f16* __restrict__ khp,
    const f16* __restrict__ vtp, f16* __restrict__ y) {
  __shared__ __align__(16) f16 Ks[2][8192];  // [cq 0..15][s 0..63][e 0..7]
  __shared__ __align__(16) f16 Vs[8192];     // [cq2 0..7][d 0..127][e 0..7]

  const int tid = threadIdx.x;
  const int lane = tid & 63;
  const int w = tid >> 6;  // 0..3
  const int lnm = lane & 15, quad = lane >> 4;

  const int bid = blockIdx.x;
  const int qt = (TT / 128 - 1) - (bid >> 6);  // 15..0, LPT order
  const int bh = bid & 63;
  const int b = bh >> 4, h = bh & 15;
  const int q0b = qt * 128;
  const int q0 = q0b + w * 32;  // this wave's 32 q-rows

  // Q B-frags (global, once per block)
  f16x8 qf[2][4];
#pragma unroll
  for (int qnb = 0; qnb < 2; qnb++) {
    const f16* qrow =
        qh + ((size_t)(b * TT + q0 + qnb * 16 + lnm) * HH + h) * DD;
#pragma unroll
    for (int c = 0; c < 4; c++)
      qf[qnb][c] = *(const f16x8*)(qrow + c * 32 + quad * 8);
  }

  f32x4 O[2][8] = {};
  float l_acc[2] = {0.f, 0.f};

  const int nst = (q0b + 128) / 64;  // 2*qt + 2
  const int wmax = q0 + 31;
  const f16* kpb = khp + (size_t)b * 32 * 8192;
  const f16* vpb = vtp + (size_t)b * 32 * 8192;

  auto stageK = [&](int buf, int st) {
    const f16* g = kpb + (size_t)st * 8192 + (size_t)tid * 8;
#pragma unroll
    for (int i = 0; i < 4; i++)
      async_load16(&Ks[buf][(size_t)(i * 256 + tid) * 8], g + i * 2048);
  };
  auto stageV = [&](int st) {
    const f16* g = vpb + (size_t)st * 8192 + (size_t)tid * 8;
#pragma unroll
    for (int i = 0; i < 4; i++)
      async_load16(&Vs[(size_t)(i * 256 + tid) * 8], g + i * 2048);
  };

  // Per-lane fragment base offsets (f16 units).
  const int kbo = quad * 512 + lnm * 8;   // + c*2048 + sb*128
  const int vbo = quad * 1024 + lnm * 8;  // + c*4096 + db*128

  stageK(0, 0);
  stageV(0);
  __syncthreads();  // tile 0 (K and V) landed

  for (int st = 0; st < nst; st++) {
    const int cur = st & 1;
    const int s0 = st * 64;
    if (st + 1 < nst) stageK(cur ^ 1, st + 1);  // uniform

    const bool act = (s0 <= wmax);  // wave-uniform (no barriers inside)
    f16x8 P8[2][2];
    if (act) {
      // QK: S^T = K . Q^T -- 16 imm-offset b128 reads
      const f16* kl = &Ks[cur][kbo];
      f32x4 S[2][4] = {};
      __builtin_amdgcn_s_setprio(1);
#pragma unroll
      for (int sb = 0; sb < 4; sb++)
#pragma unroll
        for (int c = 0; c < 4; c++) {
          f16x8 ka = *(const f16x8*)&kl[c * 2048 + sb * 128];
          S[0][sb] = __builtin_amdgcn_mfma_f32_16x16x32_f16(ka, qf[0][c],
                                                            S[0][sb], 0, 0, 0);
          S[1][sb] = __builtin_amdgcn_mfma_f32_16x16x32_f16(ka, qf[1][c],
                                                            S[1][sb], 0, 0, 0);
        }
      __builtin_amdgcn_s_setprio(0);

      // softmax: P8 = exp2(S) (+causal mask on diagonal tiles), row-sums.
      const bool domask = (s0 + 63 > q0);
      if (!domask) {
#pragma unroll
        for (int qnb = 0; qnb < 2; qnb++) {
          float lp = 0.f;
#pragma unroll
          for (int sb = 0; sb < 4; sb++)
#pragma unroll
            for (int j = 0; j < 4; j++) {
              float p = __builtin_amdgcn_exp2f(S[qnb][sb][j]);
              lp += p;
              P8[qnb][sb >> 1][(sb & 1) * 4 + j] = (f16)p;
            }
          l_acc[qnb] += lp;
        }
      } else {
#pragma unroll
        for (int qnb = 0; qnb < 2; qnb++) {
          const int m_abs = q0 + qnb * 16 + lnm;
          float lp = 0.f;
#pragma unroll
          for (int sb = 0; sb < 4; sb++) {
            const int srow = s0 + sb * 16 + quad * 4;
#pragma unroll
            for (int j = 0; j < 4; j++) {
              float p = __builtin_amdgcn_exp2f(S[qnb][sb][j]);
              if (srow + j > m_abs) p = 0.f;
              lp += p;
              P8[qnb][sb >> 1][(sb & 1) * 4 + j] = (f16)p;
            }
          }
          l_acc[qnb] += lp;
        }
      }
    }

    __syncthreads();  // drains V(t) + K(t+1) DMA (per-wave vmcnt + barrier)

    if (act) {
      // PV: 16 imm-offset b128 reads; V frag shares P8's k->s map.
      const f16* vl = &Vs[vbo];
      __builtin_amdgcn_s_setprio(1);
#pragma unroll
      for (int c = 0; c < 2; c++)
#pragma unroll
        for (int db = 0; db < 8; db++) {
          f16x8 vb = *(const f16x8*)&vl[c * 4096 + db * 128];
          O[0][db] = __builtin_amdgcn_mfma_f32_16x16x32_f16(P8[0][c], vb,
                                                            O[0][db], 0, 0, 0);
          O[1][db] = __builtin_amdgcn_mfma_f32_16x16x32_f16(P8[1][c], vb,
                                                            O[1][db], 0, 0, 0);
        }
      __builtin_amdgcn_s_setprio(0);
    }

    __syncthreads();  // all waves done reading Vs
    if (st + 1 < nst) stageV(st + 1);  // overwrite Vs; lands by next drain
  }

  // Row-sums across quads
#pragma unroll
  for (int qnb = 0; qnb < 2; qnb++) {
    float l = l_acc[qnb];
    l += __shfl_xor(l, 16, 64);
    l += __shfl_xor(l, 32, 64);
    l_acc[qnb] = l;
  }

  // Epilogue: y = O / l (f16)
#pragma unroll
  for (int qnb = 0; qnb < 2; qnb++) {
    float linv[4];
#pragma unroll
    for (int r = 0; r < 4; r++)
      linv[r] = 1.f / __shfl(l_acc[qnb], quad * 4 + r, 64);
#pragma unroll
    for (int db = 0; db < 8; db++)
#pragma unroll
      for (int r = 0; r < 4; r++) {
        size_t off =
            ((size_t)(b * TT + q0 + qnb * 16 + quad * 4 + r) * HH + h) * DD +
            db * 16 + lnm;
        y[off] = (f16)(O[qnb][db][r] * linv[r]);
      }
  }
}

// ---------------------------------------------------------------------------
extern "C" void kernel_launch(void* const* d_in, const int* in_sizes, int n_in,
                              void* d_out, int out_size, void* d_ws,
                              size_t ws_size, hipStream_t stream) {
  const float* x      = (const float*)d_in[0];
  const float* fcos   = (const float*)d_in[1];
  const float* fsin   = (const float*)d_in[2];
  const float* wq     = (const float*)d_in[3];
  const float* wkv_dn = (const float*)d_in[4];
  const float* wk_up  = (const float*)d_in[5];
  const float* wv_up  = (const float*)d_in[6];
  const float* wo     = (const float*)d_in[7];
  float* out = (float*)d_out;

  const int M = BB * TT;  // 8192

  // Workspace layout. f16 conversion destinations MUST stay contiguous in
  // the order xh|wqh|wdownh|wkvuph|woh (mla_cvt_all single-stream store).
  float* ws = (float*)d_ws;
  float* qbuf   = ws;                              // 64 MB slot: qh + yh
  f16*   xh     = (f16*)(qbuf + (size_t)M * CC);   // 32 MB
  f16*   wqh    = xh + (size_t)M * CC;             // 8 MB
  f16*   wdownh = wqh + (size_t)CC * CC;           // 2 MB
  f16*   wkvuph = wdownh + (size_t)LL * CC;        // 256 KB (k rows | v rows)
  f16*   woh    = wkvuph + (size_t)256 * LL;       // 8 MB
  f16*   kvh    = woh + (size_t)CC * CC;           // 8 MB (down-proj, f16)
  f16*   khp    = kvh + (size_t)M * LL;            // 2 MB (fragment K)
  f16*   vtp    = khp + (size_t)M * DD;            // 2 MB (fragment V)
  f16*   qh     = (f16*)qbuf;                      // 32 MB
  f16*   yh     = qh + (size_t)M * CC;             // 32 MB

  // 1) all fp32 -> f16 conversions in one dispatch
  {
    size_t total4 = CVT_C5 / 4;
    mla_cvt_all<<<(unsigned)((total4 + 255) / 256), dim3(256), 0, stream>>>(
        x, wq, wkv_dn, wk_up, wv_up, wo, xh);
  }

  // 2) q = rope(x @ wq^T) (8-phase 256^2, fused epilogue -> f16 qh)
  mla_gemm_256<1><<<dim3((M / 256) * (CC / 256)), dim3(512), 0, stream>>>(
      xh, wqh, qh, M, CC, CC, fcos, fsin);

  // 3) kvh = (x @ wdown^T) as f16 directly (128^2, N=512 -> 256 wgs)
  mla_gemm_mfma_h<<<dim3(LL / 128, M / 128), dim3(256), 0, stream>>>(
      xh, wdownh, kvh, M, LL, CC);

  // 4) fused up-projection: k-half -> rope -> fragment khp;
  //    v-half -> fragment vtp (one dispatch, no fp32 round-trip)
  mla_gemm_upkv<<<dim3(2, M / 128), dim3(256), 0, stream>>>(
      kvh, wkvuph, khp, vtp, fcos, fsin);

  // 5) flash attention v9 -> yh (f16). 1024 blocks x 256 threads, LPT.
  mla_flash2<<<dim3(BB * HH * (TT / 128)), dim3(256), 0, stream>>>(
      qh, khp, vtp, yh);

  // 6) out = y @ wo^T (8-phase 256^2)
  mla_gemm_256<0><<<dim3((M / 256) * (CC / 256)), dim3(512), 0, stream>>>(
      yh, woh, out, M, CC, CC, nullptr, nullptr);
}